// Round 6
// baseline (1024.230 us; speedup 1.0000x reference)
//
#include <hip/hip_runtime.h>
#include <hip/hip_bf16.h>
#include <math.h>

typedef __hip_bfloat16 bf16;
#define DEV static __device__ __forceinline__
DEV float b2f(bf16 x){ return __bfloat162float(x); }
DEV bf16  f2b(float x){ return __float2bfloat16(x); }
DEV float blo(unsigned int w){ return __uint_as_float(w<<16); }
DEV float bhi(unsigned int w){ return __uint_as_float(w&0xffff0000u); }
DEV float ldin(const void* p, long i, int f){
  return f ? ((const float*)p)[i] : b2f(((const bf16*)p)[i]);
}

// problem dims
#define PP 25088            // t*h*w = 8*56*56

// ws layout (float units)
#define X1o    0L           // 2*64*25088
#define POOLo  3211264L     // 2*588*64   [b][m][c]
#define XW1o   3286528L     // 2*588*64   [b][m][c]
#define WXo    3361792L     // 2*13*125*64
#define WXTo   3569792L     // 2*125*64*16 (o padded 13->16, o inner)
#define WIXo   3825792L     // 2*64*49    [b][c][kk]
#define ATTo   3832064L     // 2*13*25088 (post-sigmoid)
#define KERNo  4484352L     // 2*49*25088
#define XW3o   6942976L     // 2*16*12*3136
#define STATo  8147200L     // sums(1024) + scale/shift(1024)
#define FLAGo  8149248L     // dtype flag (int), 16 floats reserved
#define WFo    8149264L     // converted f32 weights (118016)
#define WATTFo 8267280L     // W_att as f32 (955500, pad 955504)
#define WINVFo 9222784L     // W_inv as f32 (28812, pad 28816)
#define BF16o  9251600L     // bf16 region starts here (float idx)
#define PARTo  KERNo        // k_att partials (2,609,152 f) alias KERN+XW3 head;
                            // consumed by k_sig BEFORE k_kern/k_rr write those regions
// wf sub-offsets
#define oWCT   0            // [ci][co] 64x64
#define oBCT   4096
#define oWWSI  4160         // [co][ci] (untransposed)
#define oBWSI  8256
#define oWRR   8320         // [(ci*27+tap)*16+co]
#define oBINV  35968
#define oWP1   36032        // [ci][co] 256x256
#define oWP2   101568       // [ci][co] 256x64
#define oBP2   117952
// bf16 sub-offsets (bf16 element units)
#define bXCT   0L           // 3211264
#define bXWSI  3211264L     // 4816896
#define bXATT  8028160L     // 12845056
#define bY1    20873216L    // 12845056
#define bINV   20873216L    // alias: y1 dead after k_bn1
#define bXATT1 33718272L    // 12845056

// ---- input dtype probe: even uint16s of an f32 buffer are mantissa garbage ----
__global__ void k_detect(const unsigned short* raw, int* flag){
  int t = threadIdx.x;                       // 64 lanes
  unsigned short u = raw[2*t];               // low half of f32 word t (if f32)
  int e = (u>>7)&0xFF;
  int hit = (e >= 137);                      // |bf16| >= 1024 or inf/nan: impossible for N(0,1) bf16
  unsigned long long m = __ballot(hit);
  if(t==0) flag[0] = (__popcll(m) >= 8) ? 1 : 0;   // 1 = inputs are f32
}

// ---- canonicalize inputs ----
__global__ void k_c2b(const void* src, bf16* dst, int n, const int* flag){
  int i = blockIdx.x*256+threadIdx.x; if(i>=n) return;
  int f = flag[0];
  dst[i] = f ? f2b(((const float*)src)[i]) : ((const bf16*)src)[i];
}
__global__ void k_c2f(const void* src, float* dst, int n, const int* flag){
  int i = blockIdx.x*256+threadIdx.x; if(i>=n) return;
  dst[i] = ldin(src, i, flag[0]);
}

// ---- weight convert (+transpose to put out-channel innermost) ----
__global__ void k_cvt(const void* Wct,const void* bct,const void* Wwsi,const void* bwsi,
                      const void* Wrr,const void* binv,const void* Wp1,const void* Wp2,
                      const void* bp2,float* wf,const int* flag){
  int i = blockIdx.x*256 + threadIdx.x;
  int f = flag[0];
  if (i < 4096){ int co=i>>6, ci=i&63; wf[oWCT + ci*64+co] = ldin(Wct,i,f); }
  else if (i < 4160){ wf[i] = ldin(bct,i-4096,f); }
  else if (i < 8256){ wf[i] = ldin(Wwsi,i-4160,f); }
  else if (i < 8320){ wf[i] = ldin(bwsi,i-8256,f); }
  else if (i < 35968){ int l=i-8320; int co=l/1728, r=l%1728, ci=r/27, tp=r%27;
                       wf[oWRR + (ci*27+tp)*16+co] = ldin(Wrr,l,f); }
  else if (i < 36017){ wf[oBINV + (i-35968)] = ldin(binv,i-35968,f); }
  else if (i < 36032){ }
  else if (i < 101568){ int l=i-36032; int co=l>>8, ci=l&255; wf[oWP1 + ci*256+co] = ldin(Wp1,l,f); }
  else if (i < 117952){ int l=i-101568; int o=l>>8, ci=l&255; wf[oWP2 + ci*64+o] = ldin(Wp2,l,f); }
  else if (i < 118016){ int l=i-117952; if(l<64) wf[oBP2 + l] = ldin(bp2,l,f); }
}

// ---- adaptive pool of raw x_WSI (pool commutes with 1x1 conv) ----
__global__ void k_pool(const bf16* xwsi, float* pool){
  int i = blockIdx.x*256+threadIdx.x;            // 75264 = 2*588*64
  int c = i&63; int m=(i>>6)%588; int b=i/37632;
  int d=m/49, r=m%49, ii=r/7, jj=r%7;
  const bf16* src = xwsi + ((size_t)(b*64+c)*12 + d)*3136 + (ii*8)*56 + jj*8;
  float s=0;
  for(int u=0;u<8;u++) for(int v=0;v<8;v++) s += b2f(src[u*56+v]);
  pool[i] = s*(1.f/64.f);
}

// ---- xw1 = W_wsi * pooled + b ; layout [b][m][c] ----
__global__ void k_xw1(const float* pool, const float* wf, float* xw1){
  int i = blockIdx.x*256+threadIdx.x;
  int c = i&63; int m=(i>>6)%588; int b=i/37632;
  const float* p = pool + (b*588+m)*64;
  const float* w = wf + oWWSI + c*64;
  float s = wf[oBWSI + c];
  for(int ci=0;ci<64;ci++) s += w[ci]*p[ci];
  xw1[i]=s;
}

// ---- Wx[b,o,tap,c] = sum_m W_att[o,m,tap] * xw1[b,c,m] ----
__global__ void k_Wx(const float* Wattf, const float* xw1, float* Wx){
  int i = blockIdx.x*256+threadIdx.x; if(i>=208000) return;
  int c=i&63; int r=i>>6; int tap=r%125; int o=(r/125)%13; int b=r/1625;
  const float* wa = Wattf + (size_t)o*588*125 + tap;
  const float* xp = xw1 + b*588*64 + c;
  float s=0;
  for(int m=0;m<588;m++) s += wa[(size_t)m*125] * xp[m*64];
  Wx[i]=s;
}
__global__ void k_WxT(const float* Wx, float* WxT){
  int i = blockIdx.x*256+threadIdx.x; if(i>=256000) return;
  int o=i&15; int c=(i>>4)&63; int tap=(i>>10)%125; int b=i/128000;
  WxT[i] = (o<13) ? Wx[((b*13+o)*125+tap)*64+c] : 0.f;
}

// ---- Winvx[b][c][kk] = sum_m W_inv[kk,m] * xw1[b,c,m] ----
__global__ void k_Winvx(const float* Winvf, const float* xw1, float* Wix){
  int i = blockIdx.x*256+threadIdx.x; if(i>=6272) return;
  int kk=i%49; int c=(i/49)&63; int b=i/3136;
  const float* xp = xw1 + b*588*64 + c;
  float s=0;
  for(int m=0;m<588;m++) s += Winvf[kk*588+m] * xp[m*64];
  Wix[i]=s;
}

// ---- x1 = W_ct * x_CT + b (f32) ----
__global__ void k_x1(const bf16* xct, const float* wf, float* x1){
  int p = blockIdx.x*256+threadIdx.x;
  int co0 = blockIdx.y*16; int b = blockIdx.z;
  float acc[16];
  #pragma unroll
  for(int o=0;o<16;o++) acc[o]=wf[oBCT+co0+o];
  const bf16* xp = xct + (size_t)b*64*PP + p;
  for(int ci=0;ci<64;ci++){
    float xv = b2f(xp[(size_t)ci*PP]);
    const float* w = wf + oWCT + ci*64 + co0;
    #pragma unroll
    for(int o=0;o<16;o++) acc[o] += w[o]*xv;
  }
  float* out = x1 + ((size_t)b*64+co0)*PP + p;
  #pragma unroll
  for(int o=0;o<16;o++) out[(size_t)o*PP]=acc[o];
}

// ---- Att partial: each block reduces a 16-channel slice; 4x blocks for occupancy ----
// part[cg][b][o][p] ; bank-conflict-free LDS (row stride 24 -> 2-way only)
__global__ __launch_bounds__(256) void k_att(const float* x1, const float* WxT, float* part){
  __shared__ float xt[16][20][24];
  int tid=threadIdx.x;
  int bx=blockIdx.x, t=blockIdx.y;
  int b=blockIdx.z>>2, cg=blockIdx.z&3;
  int y0=(bx>>2)*16, x0=(bx&3)*16;
  int ty=tid>>4, tx=tid&15;
  int c0=cg*16;
  float acc[13];
  #pragma unroll
  for(int o=0;o<13;o++) acc[o]=0;
  for(int dt=0;dt<5;dt++){
    int ti=t+dt-2; if(ti<0||ti>=8) continue;
    __syncthreads();
    for(int e=tid;e<6400;e+=256){
      int c=e/400, rm=e%400, yy=rm/20, xx=rm%20;
      int gy=y0+yy-2, gx=x0+xx-2;
      float v=0;
      if(gy>=0&&gy<56&&gx>=0&&gx<56)
        v = x1[((size_t)(b*64+c0+c)*8+ti)*3136 + gy*56+gx];
      xt[c][yy][xx]=v;
    }
    __syncthreads();
    const float* wb = WxT + ((size_t)(b*125 + dt*25)*64 + c0)*16;
    for(int c=0;c<16;c++){
      for(int dy=0;dy<5;dy++){
        #pragma unroll
        for(int dx=0;dx<5;dx++){
          float xv = xt[c][ty+dy][tx+dx];
          const float* wp = wb + ((dy*5+dx)*64 + c)*16;
          #pragma unroll
          for(int o=0;o<13;o++) acc[o] += wp[o]*xv;
        }
      }
    }
  }
  int gy=y0+ty, gx=x0+tx;
  if(gy<56&&gx<56){
    size_t p=(size_t)t*3136+gy*56+gx;
    #pragma unroll
    for(int o=0;o<13;o++)
      part[(((size_t)cg*2+b)*13+o)*PP+p] = acc[o];
  }
}

// ---- att = sigmoid(sum_cg part) ----
__global__ void k_sig(const float* part, float* att){
  int i=blockIdx.x*256+threadIdx.x; if(i>=652288) return;
  int p=i%PP; int r=i/PP; int o=r%13; int b=r/13;
  float s=0;
  #pragma unroll
  for(int cg=0;cg<4;cg++) s += part[(((size_t)cg*2+b)*13+o)*PP+p];
  att[i] = 1.f/(1.f+__expf(-s));
}

// ---- kern49 = Winvx * x1 + b_inv ----
__global__ void k_kern(const float* x1, const float* Wix, const float* wf, float* kern){
  int p = blockIdx.x*256+threadIdx.x; int b=blockIdx.y;
  float acc[49];
  #pragma unroll
  for(int kk=0;kk<49;kk++) acc[kk]=wf[oBINV+kk];
  const float* xp = x1 + (size_t)b*64*PP + p;
  for(int c=0;c<64;c++){
    float xv = xp[(size_t)c*PP];
    const float* w = Wix + (b*64+c)*49;
    #pragma unroll
    for(int kk=0;kk<49;kk++) acc[kk]+=w[kk]*xv;
  }
  float* out = kern + (size_t)b*49*PP + p;
  #pragma unroll
  for(int kk=0;kk<49;kk++) out[(size_t)kk*PP]=acc[kk];
}

// ---- xw3 = conv3x3x3(x_WSI, W_rr, pad=1) ----
// 8x14 tile, 512 threads = 4 og-groups x (8y x 16x); each thread owns 4 of 16 outputs.
// og is wave-uniform (tid>>7), so weight reads stay s_load; 8 waves/block -> ~21 waves/CU.
__global__ __launch_bounds__(512) void k_rr(const bf16* xwsi, const float* wf, float* xw3){
  __shared__ float xt[16][10][16];    // row stride 16: 2-way conflicts max (free)
  int tid=threadIdx.x; int bx=blockIdx.x, d=blockIdx.y, b=blockIdx.z;
  int y0=(bx>>2)*8, x0=(bx&3)*14;     // 7 row-tiles x 4 col-tiles
  int og=tid>>7;                      // 4 output groups of 4
  int sp=tid&127, py=sp>>4, tx=sp&15; // 8 rows x 16 cols (tx<14 active in compute)
  float acc[4];
  #pragma unroll
  for(int j=0;j<4;j++) acc[j]=0;
  for(int dz=0;dz<3;dz++){
    int di=d+dz-1; if(di<0||di>=12) continue;   // block-uniform: barrier-safe
    for(int c0=0;c0<64;c0+=16){
      __syncthreads();
      #pragma unroll
      for(int k=0;k<5;k++){                     // 16ch*10*16 = 2560 / 512
        int e=tid+k*512;
        int c=e/160, rm=e-c*160, yy=rm>>4, xx=rm&15;
        int gy=y0+yy-1, gx=x0+xx-1;
        float v=0;
        if(gy>=0&&gy<56&&gx>=0&&gx<56)
          v=b2f(xwsi[((size_t)(b*64+c0+c)*12+di)*3136+gy*56+gx]);
        xt[c][yy][xx]=v;
      }
      __syncthreads();
      if(tx<14){
        for(int c=0;c<16;c++){
          // preload this channel's 9x4 weights (wave-uniform -> SGPR)
          float wreg[9][4];
          #pragma unroll
          for(int tp=0;tp<9;tp++){
            const float* w = wf + oWRR + ((c0+c)*27 + dz*9+tp)*16 + og*4;
            #pragma unroll
            for(int j=0;j<4;j++) wreg[tp][j]=w[j];
          }
          #pragma unroll
          for(int dy=0;dy<3;dy++){
            #pragma unroll
            for(int dx=0;dx<3;dx++){
              float xv=xt[c][py+dy][tx+dx];
              #pragma unroll
              for(int j=0;j<4;j++) acc[j]+=wreg[dy*3+dx][j]*xv;
            }
          }
        }
      }
    }
  }
  if(tx<14){
    float* out = xw3 + ((size_t)b*16*12 + d)*3136 + (y0+py)*56 + x0+tx;
    #pragma unroll
    for(int j=0;j<4;j++) out[(size_t)(og*4+j)*12*3136]=acc[j];
  }
}

// ---- x_Att = x_FS * (1 + Att_FS)  (bf16) ----
__global__ void k_xatt(const bf16* xct, const float* xw3, const float* att, bf16* xatt){
  size_t i=(size_t)blockIdx.x*256+threadIdx.x;   // 12,845,056
  int p=(int)(i%PP); int ch=(int)((i/PP)&255); int b=(int)(i/((size_t)PP*256));
  int s=p%3136;
  float v;
  if(ch<64){
    v = b2f(xct[((size_t)b*64+ch)*PP+p]) * (1.f+att[(size_t)b*13*PP+p]);
  } else {
    int q=ch-64;
    v = xw3[((size_t)(b*16+q/12)*12 + q%12)*3136 + s] * (1.f+att[((size_t)b*13+1+q/16)*PP+p]);
  }
  xatt[i]=f2b(v);
}

// ---- y1 = W_p1 * x_Att  (b_p1 cancels in batchnorm) ----
__global__ void k_p1(const bf16* xatt, const float* wf, bf16* y1){
  int p=blockIdx.x*256+threadIdx.x;
  int co0=blockIdx.y*16; int b=blockIdx.z;
  float acc[16];
  #pragma unroll
  for(int o=0;o<16;o++) acc[o]=0;
  const bf16* xp = xatt + (size_t)b*256*PP + p;
  for(int ci=0;ci<256;ci++){
    float xv=b2f(xp[(size_t)ci*PP]);
    const float* w = wf + oWP1 + ci*256 + co0;
    #pragma unroll
    for(int o=0;o<16;o++) acc[o]+=w[o]*xv;
  }
  bf16* out = y1 + ((size_t)b*256+co0)*PP + p;
  #pragma unroll
  for(int o=0;o<16;o++) out[(size_t)o*PP]=f2b(acc[o]);
}

// ---- per-channel sum / sumsq ----
__global__ void k_stats(const bf16* src, float* sum, float* sq){
  __shared__ float rs[256], rq[256];
  int tid=threadIdx.x;
  int chunk=blockIdx.x, ch=blockIdx.y, b=blockIdx.z;
  const bf16* p = src + ((size_t)b*256+ch)*PP + chunk*3136;
  float s=0,q=0;
  for(int i=tid;i<3136;i+=256){ float v=b2f(p[i]); s+=v; q+=v*v; }
  rs[tid]=s; rq[tid]=q; __syncthreads();
  for(int st=128;st>0;st>>=1){ if(tid<st){rs[tid]+=rs[tid+st]; rq[tid]+=rq[tid+st];} __syncthreads(); }
  if(tid==0){ atomicAdd(&sum[ch],rs[0]); atomicAdd(&sq[ch],rq[0]); }
}
__global__ void k_finstat(const float* sum, const float* sq, const void* g, const void* be,
                          const int* flag, float* sc, float* sh){
  int ch=threadIdx.x;
  int f=flag[0];
  float m = sum[ch]*(1.f/50176.f);
  float v = sq[ch]*(1.f/50176.f) - m*m;
  float s = ldin(g,ch,f) * rsqrtf(v+1e-5f);
  sc[ch]=s; sh[ch]=ldin(be,ch,f) - m*s;
}

// ---- xatt1 = relu(bn1(y1)), stored transposed [b][p][ch] for involution ----
__global__ void k_bn1(const bf16* y1, const float* sc, const float* sh, bf16* xatt1){
  __shared__ unsigned short tl[64][258];
  int tid=threadIdx.x; int p0=blockIdx.x*64; int b=blockIdx.y;
  for(int k=0;k<64;k++){
    int idx=k*256+tid; int ch=idx>>6, pp=idx&63;
    float v=b2f(y1[((size_t)b*256+ch)*PP + p0+pp]);
    v = v*sc[ch]+sh[ch]; v = v>0?v:0;
    bf16 h=f2b(v); tl[pp][ch]=*(unsigned short*)&h;
  }
  __syncthreads();
  for(int k=0;k<64;k++){
    unsigned short u=tl[k][tid];
    xatt1[((size_t)b*PP + p0+k)*256 + tid] = *(bf16*)&u;
  }
}

// ---- involution: out[C,p] = sum_{i,j} kern[i,j,p] * xatt1[C, shifted] ----
__global__ __launch_bounds__(64) void k_inv(const bf16* xatt1, const float* kern, bf16* inv){
  __shared__ __align__(16) unsigned short xt[196*72];   // rows padded 64->72 (bank spread)
  int tid=threadIdx.x;
  int bx=blockIdx.x, by=blockIdx.y, bz=blockIdx.z;
  int t=bz&7, b=bz>>3;
  int y0=(bx/7)*8, x0=(bx%7)*8, c0=by*64;
  int ty=tid>>3, tx=tid&7;
  for(int e=tid;e<1568;e+=64){
    int row=e>>3, seg=e&7;
    int yy=row/14, xx=row%14;
    int gy=y0+yy-3, gx=x0+xx-3;
    uint4 v={0,0,0,0};
    if(gy>=0&&gy<56&&gx>=0&&gx<56)
      v = *(const uint4*)&xatt1[((size_t)b*PP + t*3136 + gy*56+gx)*256 + c0 + seg*8];
    *(uint4*)&xt[row*72+seg*8]=v;
  }
  float kr[49];
  size_t px=(size_t)t*3136 + (y0+ty)*56 + x0+tx;
  #pragma unroll
  for(int kk=0;kk<49;kk++) kr[kk]=kern[((size_t)b*49+kk)*PP+px];
  __syncthreads();
  for(int sub=0;sub<8;sub++){
    float acc[8];
    #pragma unroll
    for(int e=0;e<8;e++) acc[e]=0;
    for(int i=0;i<7;i++){
      #pragma unroll
      for(int j=0;j<7;j++){
        uint4 u = *(const uint4*)&xt[((ty+i)*14+tx+j)*72 + sub*8];
        float kv = kr[i*7+j];
        acc[0]+=kv*blo(u.x); acc[1]+=kv*bhi(u.x);
        acc[2]+=kv*blo(u.y); acc[3]+=kv*bhi(u.y);
        acc[4]+=kv*blo(u.z); acc[5]+=kv*bhi(u.z);
        acc[6]+=kv*blo(u.w); acc[7]+=kv*bhi(u.w);
      }
    }
    #pragma unroll
    for(int e=0;e<8;e++)
      inv[((size_t)b*256+c0+sub*8+e)*PP+px]=f2b(acc[e]);
  }
}

// ---- out = W_p2 * (bn2(inv) + x_Att) + b_p2  (f32 output) ----
__global__ void k_final(const bf16* inv, const bf16* xatt, const float* wf,
                        const float* sc2, const float* sh2, float* out){
  int p=blockIdx.x*256+threadIdx.x; int o0=blockIdx.y*16; int b=blockIdx.z;
  float acc[16];
  #pragma unroll
  for(int o=0;o<16;o++) acc[o]=wf[oBP2+o0+o];
  const bf16* ip = inv + (size_t)b*256*PP + p;
  const bf16* xp = xatt + (size_t)b*256*PP + p;
  for(int ci=0;ci<256;ci++){
    float v = b2f(ip[(size_t)ci*PP])*sc2[ci]+sh2[ci] + b2f(xp[(size_t)ci*PP]);
    const float* w = wf + oWP2 + ci*64 + o0;
    #pragma unroll
    for(int o=0;o<16;o++) acc[o]+=w[o]*v;
  }
  float* op = out + ((size_t)b*64+o0)*PP + p;
  #pragma unroll
  for(int o=0;o<16;o++) op[(size_t)o*PP]=acc[o];
}

extern "C" void kernel_launch(void* const* d_in, const int* in_sizes, int n_in,
                              void* d_out, int out_size, void* d_ws, size_t ws_size,
                              hipStream_t stream){
  const void* xct_r =d_in[0];
  const void* xwsi_r=d_in[1];
  const void* Wct =d_in[2];
  const void* bct =d_in[3];
  const void* Wwsi=d_in[4];
  const void* bwsi=d_in[5];
  const void* Watt=d_in[6];
  const void* Winv=d_in[7];
  const void* binv=d_in[8];
  const void* Wrr =d_in[9];
  const void* g1  =d_in[10];
  const void* be1 =d_in[11];
  const void* g2  =d_in[12];
  const void* be2 =d_in[13];
  const void* Wp1 =d_in[14];
  const void* Wp2 =d_in[16];
  const void* bp2 =d_in[17];
  float* ws=(float*)d_ws;
  float* x1=ws+X1o; float* pool=ws+POOLo; float* xw1=ws+XW1o;
  float* Wx=ws+WXo; float* WxT=ws+WXTo; float* Wix=ws+WIXo;
  float* att=ws+ATTo; float* kern=ws+KERNo; float* xw3=ws+XW3o;
  float* part=ws+PARTo;
  float* stat=ws+STATo; float* wf=ws+WFo;
  float* Wattf=ws+WATTFo; float* Winvf=ws+WINVFo;
  int* flag=(int*)(ws+FLAGo);
  bf16* bfb=(bf16*)(ws+BF16o);
  bf16* xctb=bfb+bXCT; bf16* xwsib=bfb+bXWSI;
  bf16* xatt=bfb+bXATT; bf16* y1=bfb+bY1; bf16* invb=bfb+bINV; bf16* xatt1=bfb+bXATT1;
  float* sum1=stat; float* sq1=stat+256; float* sum2=stat+512; float* sq2=stat+768;
  float* sc1=stat+1024; float* sh1=stat+1280; float* sc2=stat+1536; float* sh2=stat+1792;

  hipMemsetAsync(stat,0,4096,stream);
  k_detect<<<1,64,0,stream>>>((const unsigned short*)xct_r,flag);
  k_c2b   <<<12544,256,0,stream>>>(xct_r,xctb,3211264,flag);
  k_c2b   <<<18816,256,0,stream>>>(xwsi_r,xwsib,4816896,flag);
  k_c2f   <<<3733,256,0,stream>>>(Watt,Wattf,955500,flag);
  k_c2f   <<<113,256,0,stream>>>(Winv,Winvf,28812,flag);
  k_cvt   <<<461,256,0,stream>>>(Wct,bct,Wwsi,bwsi,Wrr,binv,Wp1,Wp2,bp2,wf,flag);
  k_pool  <<<294,256,0,stream>>>(xwsib,pool);
  k_xw1   <<<294,256,0,stream>>>(pool,wf,xw1);
  k_Wx    <<<813,256,0,stream>>>(Wattf,xw1,Wx);
  k_WxT   <<<1000,256,0,stream>>>(Wx,WxT);
  k_Winvx <<<25,256,0,stream>>>(Winvf,xw1,Wix);
  k_x1    <<<dim3(98,4,2),256,0,stream>>>(xctb,wf,x1);
  k_att   <<<dim3(16,8,8),256,0,stream>>>(x1,WxT,part);     // 1024 blocks, 4/CU
  k_sig   <<<2548,256,0,stream>>>(part,att);                // consumes part before k_kern/k_rr reuse it
  k_kern  <<<dim3(98,2),256,0,stream>>>(x1,Wix,wf,kern);
  k_rr    <<<dim3(28,12,2),512,0,stream>>>(xwsib,wf,xw3);   // 672 blocks, 8 waves each
  k_xatt  <<<50176,256,0,stream>>>(xctb,xw3,att,xatt);
  k_p1    <<<dim3(98,16,2),256,0,stream>>>(xatt,wf,y1);
  k_stats <<<dim3(8,256,2),256,0,stream>>>(y1,sum1,sq1);
  k_finstat<<<1,256,0,stream>>>(sum1,sq1,g1,be1,flag,sc1,sh1);
  k_bn1   <<<dim3(392,2),256,0,stream>>>(y1,sc1,sh1,xatt1);
  k_inv   <<<dim3(49,4,16),64,0,stream>>>(xatt1,kern,invb);
  k_stats <<<dim3(8,256,2),256,0,stream>>>(invb,sum2,sq2);
  k_finstat<<<1,256,0,stream>>>(sum2,sq2,g2,be2,flag,sc2,sh2);
  k_final <<<dim3(98,4,2),256,0,stream>>>(invb,xatt,wf,sc2,sh2,(float*)d_out);
}

// Round 7
// 819.596 us; speedup vs baseline: 1.2497x; 1.2497x over previous
//
#include <hip/hip_runtime.h>
#include <hip/hip_bf16.h>
#include <math.h>

typedef __hip_bfloat16 bf16;
#define DEV static __device__ __forceinline__
DEV float b2f(bf16 x){ return __bfloat162float(x); }
DEV bf16  f2b(float x){ return __float2bfloat16(x); }
DEV float blo(unsigned int w){ return __uint_as_float(w<<16); }
DEV float bhi(unsigned int w){ return __uint_as_float(w&0xffff0000u); }
DEV float ldin(const void* p, long i, int f){
  return f ? ((const float*)p)[i] : b2f(((const bf16*)p)[i]);
}

// problem dims
#define PP 25088            // t*h*w = 8*56*56

// ws layout (float units)
#define X1o    0L           // 2*64*25088
#define POOLo  3211264L     // 2*588*64   [b][m][c]
#define XW1o   3286528L     // 2*588*64   [b][m][c]
#define WXo    3361792L     // 2*13*125*64
#define WXTo   3569792L     // 2*125*64*16 (o padded 13->16, o inner)
#define WIXo   3825792L     // 2*64*49    [b][c][kk]
#define ATTo   3832064L     // 2*13*25088 (post-sigmoid)
#define KERNo  4484352L     // 2*49*25088
#define XW3o   6942976L     // xw3 partials: 2half*2b*16co*12d*3136 bf16
#define STATo  8147200L     // sums(1024) + scale/shift(1024)
#define FLAGo  8149248L     // dtype flag (int), 16 floats reserved
#define WFo    8149264L     // converted f32 weights (118016)
#define WATTFo 8267280L     // W_att as f32 (955500, pad 955504)
#define WINVFo 9222784L     // W_inv as f32 (28812, pad 28816)
#define BF16o  9251600L     // bf16 region starts here (float idx)
#define PARTo  KERNo        // k_att bf16 partials (16 slabs x 13 x PP bf16 = 5.22M bf16);
                            // spans KERN+XW3 head; consumed by k_sig BEFORE k_kern/k_rr write
// wf sub-offsets
#define oWCT   0            // [ci][co] 64x64
#define oBCT   4096
#define oWWSI  4160         // [co][ci] (untransposed)
#define oBWSI  8256
#define oWRR   8320         // [(ci*27+tap)*16+co]
#define oBINV  35968
#define oWP1   36032        // [ci][co] 256x256
#define oWP2   101568       // [ci][co] 256x64
#define oBP2   117952
// bf16 sub-offsets (bf16 element units)
#define bXCT   0L           // 3211264
#define bXWSI  3211264L     // 4816896
#define bXATT  8028160L     // 12845056
#define bY1    20873216L    // 12845056
#define bINV   20873216L    // alias: y1 dead after k_bn1
#define bXATT1 33718272L    // 12845056

// ---- input dtype probe: even uint16s of an f32 buffer are mantissa garbage ----
__global__ void k_detect(const unsigned short* raw, int* flag){
  int t = threadIdx.x;                       // 64 lanes
  unsigned short u = raw[2*t];               // low half of f32 word t (if f32)
  int e = (u>>7)&0xFF;
  int hit = (e >= 137);                      // impossible for N(0,1) bf16
  unsigned long long m = __ballot(hit);
  if(t==0) flag[0] = (__popcll(m) >= 8) ? 1 : 0;   // 1 = inputs are f32
}

// ---- canonicalize inputs ----
__global__ void k_c2b(const void* src, bf16* dst, int n, const int* flag){
  int i = blockIdx.x*256+threadIdx.x; if(i>=n) return;
  int f = flag[0];
  dst[i] = f ? f2b(((const float*)src)[i]) : ((const bf16*)src)[i];
}
__global__ void k_c2f(const void* src, float* dst, int n, const int* flag){
  int i = blockIdx.x*256+threadIdx.x; if(i>=n) return;
  dst[i] = ldin(src, i, flag[0]);
}

// ---- weight convert (+transpose to put out-channel innermost) ----
__global__ void k_cvt(const void* Wct,const void* bct,const void* Wwsi,const void* bwsi,
                      const void* Wrr,const void* binv,const void* Wp1,const void* Wp2,
                      const void* bp2,float* wf,const int* flag){
  int i = blockIdx.x*256 + threadIdx.x;
  int f = flag[0];
  if (i < 4096){ int co=i>>6, ci=i&63; wf[oWCT + ci*64+co] = ldin(Wct,i,f); }
  else if (i < 4160){ wf[i] = ldin(bct,i-4096,f); }
  else if (i < 8256){ wf[i] = ldin(Wwsi,i-4160,f); }
  else if (i < 8320){ wf[i] = ldin(bwsi,i-8256,f); }
  else if (i < 35968){ int l=i-8320; int co=l/1728, r=l%1728, ci=r/27, tp=r%27;
                       wf[oWRR + (ci*27+tp)*16+co] = ldin(Wrr,l,f); }
  else if (i < 36017){ wf[oBINV + (i-35968)] = ldin(binv,i-35968,f); }
  else if (i < 36032){ }
  else if (i < 101568){ int l=i-36032; int co=l>>8, ci=l&255; wf[oWP1 + ci*256+co] = ldin(Wp1,l,f); }
  else if (i < 117952){ int l=i-101568; int o=l>>8, ci=l&255; wf[oWP2 + ci*64+o] = ldin(Wp2,l,f); }
  else if (i < 118016){ int l=i-117952; if(l<64) wf[oBP2 + l] = ldin(bp2,l,f); }
}

// ---- adaptive pool of raw x_WSI (pool commutes with 1x1 conv) ----
__global__ void k_pool(const bf16* xwsi, float* pool){
  int i = blockIdx.x*256+threadIdx.x;            // 75264 = 2*588*64
  int c = i&63; int m=(i>>6)%588; int b=i/37632;
  int d=m/49, r=m%49, ii=r/7, jj=r%7;
  const bf16* src = xwsi + ((size_t)(b*64+c)*12 + d)*3136 + (ii*8)*56 + jj*8;
  float s=0;
  for(int u=0;u<8;u++) for(int v=0;v<8;v++) s += b2f(src[u*56+v]);
  pool[i] = s*(1.f/64.f);
}

// ---- xw1 = W_wsi * pooled + b ; layout [b][m][c] ----
__global__ void k_xw1(const float* pool, const float* wf, float* xw1){
  int i = blockIdx.x*256+threadIdx.x;
  int c = i&63; int m=(i>>6)%588; int b=i/37632;
  const float* p = pool + (b*588+m)*64;
  const float* w = wf + oWWSI + c*64;
  float s = wf[oBWSI + c];
  for(int ci=0;ci<64;ci++) s += w[ci]*p[ci];
  xw1[i]=s;
}

// ---- Wx[b,o,tap,c] = sum_m W_att[o,m,tap] * xw1[b,c,m] ----
__global__ void k_Wx(const float* Wattf, const float* xw1, float* Wx){
  int i = blockIdx.x*256+threadIdx.x; if(i>=208000) return;
  int c=i&63; int r=i>>6; int tap=r%125; int o=(r/125)%13; int b=r/1625;
  const float* wa = Wattf + (size_t)o*588*125 + tap;
  const float* xp = xw1 + b*588*64 + c;
  float s=0;
  for(int m=0;m<588;m++) s += wa[(size_t)m*125] * xp[m*64];
  Wx[i]=s;
}
__global__ void k_WxT(const float* Wx, float* WxT){
  int i = blockIdx.x*256+threadIdx.x; if(i>=256000) return;
  int o=i&15; int c=(i>>4)&63; int tap=(i>>10)%125; int b=i/128000;
  WxT[i] = (o<13) ? Wx[((b*13+o)*125+tap)*64+c] : 0.f;
}

// ---- Winvx[b][c][kk] = sum_m W_inv[kk,m] * xw1[b,c,m] ----
__global__ void k_Winvx(const float* Winvf, const float* xw1, float* Wix){
  int i = blockIdx.x*256+threadIdx.x; if(i>=6272) return;
  int kk=i%49; int c=(i/49)&63; int b=i/3136;
  const float* xp = xw1 + b*588*64 + c;
  float s=0;
  for(int m=0;m<588;m++) s += Winvf[kk*588+m] * xp[m*64];
  Wix[i]=s;
}

// ---- x1 = W_ct * x_CT + b (f32) ----
__global__ void k_x1(const bf16* xct, const float* wf, float* x1){
  int p = blockIdx.x*256+threadIdx.x;
  int co0 = blockIdx.y*16; int b = blockIdx.z;
  float acc[16];
  #pragma unroll
  for(int o=0;o<16;o++) acc[o]=wf[oBCT+co0+o];
  const bf16* xp = xct + (size_t)b*64*PP + p;
  for(int ci=0;ci<64;ci++){
    float xv = b2f(xp[(size_t)ci*PP]);
    const float* w = wf + oWCT + ci*64 + co0;
    #pragma unroll
    for(int o=0;o<16;o++) acc[o] += w[o]*xv;
  }
  float* out = x1 + ((size_t)b*64+co0)*PP + p;
  #pragma unroll
  for(int o=0;o<16;o++) out[(size_t)o*PP]=acc[o];
}

// ---- Att partial: 8-way ci split (8 ch each) for full occupancy; bf16 partials ----
__global__ __launch_bounds__(256) void k_att(const float* x1, const float* WxT, bf16* part){
  __shared__ float xt[8][20][24];
  int tid=threadIdx.x;
  int bx=blockIdx.x, t=blockIdx.y;
  int b=blockIdx.z>>3, cg=blockIdx.z&7;
  int y0=(bx>>2)*16, x0=(bx&3)*16;
  int ty=tid>>4, tx=tid&15;
  int c0=cg*8;
  float acc[13];
  #pragma unroll
  for(int o=0;o<13;o++) acc[o]=0;
  for(int dt=0;dt<5;dt++){
    int ti=t+dt-2; if(ti<0||ti>=8) continue;
    __syncthreads();
    for(int e=tid;e<3200;e+=256){
      int c=e/400, rm=e-c*400, yy=rm/20, xx=rm-yy*20;
      int gy=y0+yy-2, gx=x0+xx-2;
      float v=0;
      if(gy>=0&&gy<56&&gx>=0&&gx<56)
        v = x1[((size_t)(b*64+c0+c)*8+ti)*3136 + gy*56+gx];
      xt[c][yy][xx]=v;
    }
    __syncthreads();
    const float* wb = WxT + ((size_t)(b*125 + dt*25)*64 + c0)*16;
    for(int c=0;c<8;c++){
      for(int dy=0;dy<5;dy++){
        #pragma unroll
        for(int dx=0;dx<5;dx++){
          float xv = xt[c][ty+dy][tx+dx];
          const float* wp = wb + ((dy*5+dx)*64 + c)*16;
          #pragma unroll
          for(int o=0;o<13;o++) acc[o] += wp[o]*xv;
        }
      }
    }
  }
  int gy=y0+ty, gx=x0+tx;
  if(gy<56&&gx<56){
    size_t p=(size_t)t*3136+gy*56+gx;
    #pragma unroll
    for(int o=0;o<13;o++)
      part[(((size_t)cg*2+b)*13+o)*PP+p] = f2b(acc[o]);
  }
}

// ---- att = sigmoid(sum_cg part)  (division-free grid) ----
__global__ void k_sig(const bf16* part, float* att){
  int p=blockIdx.x*256+threadIdx.x; int o=blockIdx.y; int b=blockIdx.z;
  float s=0;
  #pragma unroll
  for(int cg=0;cg<8;cg++) s += b2f(part[(((size_t)cg*2+b)*13+o)*PP+p]);
  att[((size_t)b*13+o)*PP+p] = 1.f/(1.f+__expf(-s));
}

// ---- kern49 = Winvx * x1 + b_inv ----
__global__ void k_kern(const float* x1, const float* Wix, const float* wf, float* kern){
  int p = blockIdx.x*256+threadIdx.x; int b=blockIdx.y;
  float acc[49];
  #pragma unroll
  for(int kk=0;kk<49;kk++) acc[kk]=wf[oBINV+kk];
  const float* xp = x1 + (size_t)b*64*PP + p;
  for(int c=0;c<64;c++){
    float xv = xp[(size_t)c*PP];
    const float* w = Wix + (b*64+c)*49;
    #pragma unroll
    for(int kk=0;kk<49;kk++) acc[kk]+=w[kk]*xv;
  }
  float* out = kern + (size_t)b*49*PP + p;
  #pragma unroll
  for(int kk=0;kk<49;kk++) out[(size_t)kk*PP]=acc[kk];
}

// ---- xw3 = conv3x3x3(x_WSI, W_rr, pad=1) : ci-half split, bf16 partials ----
// 8x14 tile, 128 threads; weights stay block-uniform (s_load); shift-only staging.
__global__ __launch_bounds__(128) void k_rr(const bf16* xwsi, const float* wf, bf16* xw3p){
  __shared__ float xt[16][10][16];
  int tid=threadIdx.x; int bx=blockIdx.x, d=blockIdx.y;
  int b=blockIdx.z>>1, half=blockIdx.z&1;
  int y0=(bx>>2)*8, x0=(bx&3)*14;
  int py=tid>>4, tx=tid&15;
  float acc[16];
  #pragma unroll
  for(int o=0;o<16;o++) acc[o]=0;
  for(int dz=0;dz<3;dz++){
    int di=d+dz-1; if(di<0||di>=12) continue;   // block-uniform: barrier-safe
    for(int c0h=0;c0h<2;c0h++){
      int c0 = half*32 + c0h*16;
      __syncthreads();
      #pragma unroll
      for(int c=0;c<16;c++){                    // shift-only staging, 16 indep loads
        const bf16* src = xwsi + ((size_t)(b*64+c0+c)*12+di)*3136;
        int gy=y0+py-1, gx=x0+tx-1;
        float v=0;
        if(gy>=0&&gy<56&&gx>=0&&gx<56) v=b2f(src[gy*56+gx]);
        xt[c][py][tx]=v;
        if(tid<32){
          int yy2=8+py; int gy2=y0+yy2-1;
          float v2=0;
          if(gy2>=0&&gy2<56&&gx>=0&&gx<56) v2=b2f(src[gy2*56+gx]);
          xt[c][yy2][tx]=v2;
        }
      }
      __syncthreads();
      if(tx<14){
        for(int c=0;c<16;c++){
          #pragma unroll
          for(int dy=0;dy<3;dy++){
            #pragma unroll
            for(int dx=0;dx<3;dx++){
              float xv=xt[c][py+dy][tx+dx];
              const float* w = wf + oWRR + ((c0+c)*27 + dz*9+dy*3+dx)*16;
              #pragma unroll
              for(int o=0;o<16;o++) acc[o]+=w[o]*xv;
            }
          }
        }
      }
    }
  }
  if(tx<14){
    bf16* out = xw3p + (((size_t)(half*2+b)*16)*12 + d)*3136 + (y0+py)*56 + x0+tx;
    #pragma unroll
    for(int o=0;o<16;o++) out[(size_t)o*12*3136]=f2b(acc[o]);
  }
}

// ---- x_Att = x_FS * (1 + Att_FS)  (division-free grid; sums xw3 halves) ----
__global__ void k_xatt(const bf16* xct, const bf16* xw3p, const float* att, bf16* xatt){
  int p=blockIdx.x*256+threadIdx.x; int ch=blockIdx.y; int b=blockIdx.z;
  float v;
  if(ch<64){
    v = b2f(xct[((size_t)b*64+ch)*PP+p]) * (1.f+att[(size_t)b*13*PP+p]);
  } else {
    int q=ch-64; int co=q/12, dd=q-co*12;       // block-uniform
    int s=p%3136;
    size_t i0=(((size_t)(0+b)*16+co)*12+dd)*3136+s;
    size_t i1=(((size_t)(2+b)*16+co)*12+dd)*3136+s;
    v = (b2f(xw3p[i0])+b2f(xw3p[i1])) * (1.f+att[((size_t)b*13+1+q/16)*PP+p]);
  }
  xatt[((size_t)b*256+ch)*PP+p]=f2b(v);
}

// ---- y1 = W_p1 * x_Att  (b_p1 cancels in batchnorm) ----
__global__ void k_p1(const bf16* xatt, const float* wf, bf16* y1){
  int p=blockIdx.x*256+threadIdx.x;
  int co0=blockIdx.y*16; int b=blockIdx.z;
  float acc[16];
  #pragma unroll
  for(int o=0;o<16;o++) acc[o]=0;
  const bf16* xp = xatt + (size_t)b*256*PP + p;
  for(int ci=0;ci<256;ci++){
    float xv=b2f(xp[(size_t)ci*PP]);
    const float* w = wf + oWP1 + ci*256 + co0;
    #pragma unroll
    for(int o=0;o<16;o++) acc[o]+=w[o]*xv;
  }
  bf16* out = y1 + ((size_t)b*256+co0)*PP + p;
  #pragma unroll
  for(int o=0;o<16;o++) out[(size_t)o*PP]=f2b(acc[o]);
}

// ---- per-channel sum / sumsq ----
__global__ void k_stats(const bf16* src, float* sum, float* sq){
  __shared__ float rs[256], rq[256];
  int tid=threadIdx.x;
  int chunk=blockIdx.x, ch=blockIdx.y, b=blockIdx.z;
  const bf16* p = src + ((size_t)b*256+ch)*PP + chunk*3136;
  float s=0,q=0;
  for(int i=tid;i<3136;i+=256){ float v=b2f(p[i]); s+=v; q+=v*v; }
  rs[tid]=s; rq[tid]=q; __syncthreads();
  for(int st=128;st>0;st>>=1){ if(tid<st){rs[tid]+=rs[tid+st]; rq[tid]+=rq[tid+st];} __syncthreads(); }
  if(tid==0){ atomicAdd(&sum[ch],rs[0]); atomicAdd(&sq[ch],rq[0]); }
}
__global__ void k_finstat(const float* sum, const float* sq, const void* g, const void* be,
                          const int* flag, float* sc, float* sh){
  int ch=threadIdx.x;
  int f=flag[0];
  float m = sum[ch]*(1.f/50176.f);
  float v = sq[ch]*(1.f/50176.f) - m*m;
  float s = ldin(g,ch,f) * rsqrtf(v+1e-5f);
  sc[ch]=s; sh[ch]=ldin(be,ch,f) - m*s;
}

// ---- xatt1 = relu(bn1(y1)), stored transposed [b][p][ch] for involution ----
__global__ void k_bn1(const bf16* y1, const float* sc, const float* sh, bf16* xatt1){
  __shared__ unsigned short tl[64][258];
  int tid=threadIdx.x; int p0=blockIdx.x*64; int b=blockIdx.y;
  for(int k=0;k<64;k++){
    int idx=k*256+tid; int ch=idx>>6, pp=idx&63;
    float v=b2f(y1[((size_t)b*256+ch)*PP + p0+pp]);
    v = v*sc[ch]+sh[ch]; v = v>0?v:0;
    bf16 h=f2b(v); tl[pp][ch]=*(unsigned short*)&h;
  }
  __syncthreads();
  for(int k=0;k<64;k++){
    unsigned short u=tl[k][tid];
    xatt1[((size_t)b*PP + p0+k)*256 + tid] = *(bf16*)&u;
  }
}

// ---- involution: out[C,p] = sum_{i,j} kern[i,j,p] * xatt1[C, shifted] ----
__global__ __launch_bounds__(64) void k_inv(const bf16* xatt1, const float* kern, bf16* inv){
  __shared__ __align__(16) unsigned short xt[196*72];   // rows padded 64->72 (bank spread)
  int tid=threadIdx.x;
  int bx=blockIdx.x, by=blockIdx.y, bz=blockIdx.z;
  int t=bz&7, b=bz>>3;
  int y0=(bx/7)*8, x0=(bx%7)*8, c0=by*64;
  int ty=tid>>3, tx=tid&7;
  for(int e=tid;e<1568;e+=64){
    int row=e>>3, seg=e&7;
    int yy=row/14, xx=row%14;
    int gy=y0+yy-3, gx=x0+xx-3;
    uint4 v={0,0,0,0};
    if(gy>=0&&gy<56&&gx>=0&&gx<56)
      v = *(const uint4*)&xatt1[((size_t)b*PP + t*3136 + gy*56+gx)*256 + c0 + seg*8];
    *(uint4*)&xt[row*72+seg*8]=v;
  }
  float kr[49];
  size_t px=(size_t)t*3136 + (y0+ty)*56 + x0+tx;
  #pragma unroll
  for(int kk=0;kk<49;kk++) kr[kk]=kern[((size_t)b*49+kk)*PP+px];
  __syncthreads();
  for(int sub=0;sub<8;sub++){
    float acc[8];
    #pragma unroll
    for(int e=0;e<8;e++) acc[e]=0;
    for(int i=0;i<7;i++){
      #pragma unroll
      for(int j=0;j<7;j++){
        uint4 u = *(const uint4*)&xt[((ty+i)*14+tx+j)*72 + sub*8];
        float kv = kr[i*7+j];
        acc[0]+=kv*blo(u.x); acc[1]+=kv*bhi(u.x);
        acc[2]+=kv*blo(u.y); acc[3]+=kv*bhi(u.y);
        acc[4]+=kv*blo(u.z); acc[5]+=kv*bhi(u.z);
        acc[6]+=kv*blo(u.w); acc[7]+=kv*bhi(u.w);
      }
    }
    #pragma unroll
    for(int e=0;e<8;e++)
      inv[((size_t)b*256+c0+sub*8+e)*PP+px]=f2b(acc[e]);
  }
}

// ---- out = W_p2 * (bn2(inv) + x_Att) + b_p2  (f32 output) ----
__global__ void k_final(const bf16* inv, const bf16* xatt, const float* wf,
                        const float* sc2, const float* sh2, float* out){
  int p=blockIdx.x*256+threadIdx.x; int o0=blockIdx.y*16; int b=blockIdx.z;
  float acc[16];
  #pragma unroll
  for(int o=0;o<16;o++) acc[o]=wf[oBP2+o0+o];
  const bf16* ip = inv + (size_t)b*256*PP + p;
  const bf16* xp = xatt + (size_t)b*256*PP + p;
  for(int ci=0;ci<256;ci++){
    float v = b2f(ip[(size_t)ci*PP])*sc2[ci]+sh2[ci] + b2f(xp[(size_t)ci*PP]);
    const float* w = wf + oWP2 + ci*64 + o0;
    #pragma unroll
    for(int o=0;o<16;o++) acc[o]+=w[o]*v;
  }
  float* op = out + ((size_t)b*64+o0)*PP + p;
  #pragma unroll
  for(int o=0;o<16;o++) op[(size_t)o*PP]=acc[o];
}

extern "C" void kernel_launch(void* const* d_in, const int* in_sizes, int n_in,
                              void* d_out, int out_size, void* d_ws, size_t ws_size,
                              hipStream_t stream){
  const void* xct_r =d_in[0];
  const void* xwsi_r=d_in[1];
  const void* Wct =d_in[2];
  const void* bct =d_in[3];
  const void* Wwsi=d_in[4];
  const void* bwsi=d_in[5];
  const void* Watt=d_in[6];
  const void* Winv=d_in[7];
  const void* binv=d_in[8];
  const void* Wrr =d_in[9];
  const void* g1  =d_in[10];
  const void* be1 =d_in[11];
  const void* g2  =d_in[12];
  const void* be2 =d_in[13];
  const void* Wp1 =d_in[14];
  const void* Wp2 =d_in[16];
  const void* bp2 =d_in[17];
  float* ws=(float*)d_ws;
  float* x1=ws+X1o; float* pool=ws+POOLo; float* xw1=ws+XW1o;
  float* Wx=ws+WXo; float* WxT=ws+WXTo; float* Wix=ws+WIXo;
  float* att=ws+ATTo; float* kern=ws+KERNo;
  bf16* part=(bf16*)(ws+PARTo);
  bf16* xw3p=(bf16*)(ws+XW3o);
  float* stat=ws+STATo; float* wf=ws+WFo;
  float* Wattf=ws+WATTFo; float* Winvf=ws+WINVFo;
  int* flag=(int*)(ws+FLAGo);
  bf16* bfb=(bf16*)(ws+BF16o);
  bf16* xctb=bfb+bXCT; bf16* xwsib=bfb+bXWSI;
  bf16* xatt=bfb+bXATT; bf16* y1=bfb+bY1; bf16* invb=bfb+bINV; bf16* xatt1=bfb+bXATT1;
  float* sum1=stat; float* sq1=stat+256; float* sum2=stat+512; float* sq2=stat+768;
  float* sc1=stat+1024; float* sh1=stat+1280; float* sc2=stat+1536; float* sh2=stat+1792;

  hipMemsetAsync(stat,0,4096,stream);
  k_detect<<<1,64,0,stream>>>((const unsigned short*)xct_r,flag);
  k_c2b   <<<12544,256,0,stream>>>(xct_r,xctb,3211264,flag);
  k_c2b   <<<18816,256,0,stream>>>(xwsi_r,xwsib,4816896,flag);
  k_c2f   <<<3733,256,0,stream>>>(Watt,Wattf,955500,flag);
  k_c2f   <<<113,256,0,stream>>>(Winv,Winvf,28812,flag);
  k_cvt   <<<461,256,0,stream>>>(Wct,bct,Wwsi,bwsi,Wrr,binv,Wp1,Wp2,bp2,wf,flag);
  k_pool  <<<294,256,0,stream>>>(xwsib,pool);
  k_xw1   <<<294,256,0,stream>>>(pool,wf,xw1);
  k_Wx    <<<813,256,0,stream>>>(Wattf,xw1,Wx);
  k_WxT   <<<1000,256,0,stream>>>(Wx,WxT);
  k_Winvx <<<25,256,0,stream>>>(Winvf,xw1,Wix);
  k_x1    <<<dim3(98,4,2),256,0,stream>>>(xctb,wf,x1);
  k_att   <<<dim3(16,8,16),256,0,stream>>>(x1,WxT,part);    // 2048 blocks, 8/CU
  k_sig   <<<dim3(98,13,2),256,0,stream>>>(part,att);       // consumes part before k_kern/k_rr
  k_kern  <<<dim3(98,2),256,0,stream>>>(x1,Wix,wf,kern);
  k_rr    <<<dim3(28,12,4),128,0,stream>>>(xwsib,wf,xw3p);  // ci-half split, 1344 blocks
  k_xatt  <<<dim3(98,256,2),256,0,stream>>>(xctb,xw3p,att,xatt);
  k_p1    <<<dim3(98,16,2),256,0,stream>>>(xatt,wf,y1);
  k_stats <<<dim3(8,256,2),256,0,stream>>>(y1,sum1,sq1);
  k_finstat<<<1,256,0,stream>>>(sum1,sq1,g1,be1,flag,sc1,sh1);
  k_bn1   <<<dim3(392,2),256,0,stream>>>(y1,sc1,sh1,xatt1);
  k_inv   <<<dim3(49,4,16),64,0,stream>>>(xatt1,kern,invb);
  k_stats <<<dim3(8,256,2),256,0,stream>>>(invb,sum2,sq2);
  k_finstat<<<1,256,0,stream>>>(sum2,sq2,g2,be2,flag,sc2,sh2);
  k_final <<<dim3(98,4,2),256,0,stream>>>(invb,xatt,wf,sc2,sh2,(float*)d_out);
}

// Round 8
// 639.260 us; speedup vs baseline: 1.6022x; 1.2821x over previous
//
#include <hip/hip_runtime.h>
#include <hip/hip_bf16.h>
#include <math.h>

typedef __hip_bfloat16 bf16;
typedef __attribute__((ext_vector_type(8))) short short8v;
typedef __attribute__((ext_vector_type(4))) float f32x4;
#define DEV static __device__ __forceinline__
DEV float b2f(bf16 x){ return __bfloat162float(x); }
DEV bf16  f2b(float x){ return __float2bfloat16(x); }
DEV unsigned short f2u(float x){ bf16 h=f2b(x); return *(unsigned short*)&h; }
DEV float blo(unsigned int w){ return __uint_as_float(w<<16); }
DEV float bhi(unsigned int w){ return __uint_as_float(w&0xffff0000u); }
DEV float ldin(const void* p, long i, int f){
  return f ? ((const float*)p)[i] : b2f(((const bf16*)p)[i]);
}

// problem dims
#define PP 25088            // t*h*w = 8*56*56

// ws layout (float units)
#define X1o    0L           // 2*64*25088
#define POOLo  3211264L     // 2*588*64   [b][m][c]
#define XW1o   3286528L     // 2*588*64   [b][m][c]
#define WXo    3361792L     // 2*13*125*64
#define WXTo   3569792L     // Wf MFMA A-frags: 256000 bf16 (fits old 256000 f region)
#define WIXo   3825792L     // 2*64*49    [b][c][kk]
#define ATTo   3832064L     // 2*13*25088 (post-sigmoid, f32)
#define KERNo  4484352L     // 2*49*25088 f32; head aliased by x1t before k_kern runs
#define XW3o   6942976L     // xw3 partials: 2half*2b*16co*12d*3136 bf16
#define STATo  8147200L     // sums(1024) + scale/shift(1024)
#define FLAGo  8149248L     // dtype flag (int), 16 floats reserved
#define WFo    8149264L     // converted f32 weights (118016)
#define WATTFo 8267280L     // W_att as f32 (955500, pad 955504)
#define WINVFo 9222784L     // W_inv as f32 (28812, pad 28816)
#define BF16o  9251600L     // bf16 region starts here (float idx)
#define X1To   KERNo        // x1t bf16 [b][p][64c]: 3211264 shorts = 1605632 f, fits in KERN
                            // order: k_x1 writes -> k_att reads -> k_kern overwrites
// wf sub-offsets
#define oWCT   0            // [ci][co] 64x64
#define oBCT   4096
#define oWWSI  4160         // [co][ci] (untransposed)
#define oBWSI  8256
#define oWRR   8320         // [(ci*27+tap)*16+co]
#define oBINV  35968
#define oWP1   36032        // [ci][co] 256x256
#define oWP2   101568       // [ci][co] 256x64
#define oBP2   117952
// bf16 sub-offsets (bf16 element units)
#define bXCT   0L           // 3211264
#define bXWSI  3211264L     // 4816896
#define bXATT  8028160L     // 12845056
#define bY1    20873216L    // 12845056
#define bINV   20873216L    // alias: y1 dead after k_bn1
#define bXATT1 33718272L    // 12845056

// ---- input dtype probe ----
__global__ void k_detect(const unsigned short* raw, int* flag){
  int t = threadIdx.x;
  unsigned short u = raw[2*t];
  int e = (u>>7)&0xFF;
  int hit = (e >= 137);
  unsigned long long m = __ballot(hit);
  if(t==0) flag[0] = (__popcll(m) >= 8) ? 1 : 0;   // 1 = inputs are f32
}

// ---- canonicalize inputs ----
__global__ void k_c2b(const void* src, bf16* dst, int n, const int* flag){
  int i = blockIdx.x*256+threadIdx.x; if(i>=n) return;
  int f = flag[0];
  dst[i] = f ? f2b(((const float*)src)[i]) : ((const bf16*)src)[i];
}
__global__ void k_c2f(const void* src, float* dst, int n, const int* flag){
  int i = blockIdx.x*256+threadIdx.x; if(i>=n) return;
  dst[i] = ldin(src, i, flag[0]);
}

// ---- weight convert (+transpose to put out-channel innermost) ----
__global__ void k_cvt(const void* Wct,const void* bct,const void* Wwsi,const void* bwsi,
                      const void* Wrr,const void* binv,const void* Wp1,const void* Wp2,
                      const void* bp2,float* wf,const int* flag){
  int i = blockIdx.x*256 + threadIdx.x;
  int f = flag[0];
  if (i < 4096){ int co=i>>6, ci=i&63; wf[oWCT + ci*64+co] = ldin(Wct,i,f); }
  else if (i < 4160){ wf[i] = ldin(bct,i-4096,f); }
  else if (i < 8256){ wf[i] = ldin(Wwsi,i-4160,f); }
  else if (i < 8320){ wf[i] = ldin(bwsi,i-8256,f); }
  else if (i < 35968){ int l=i-8320; int co=l/1728, r=l%1728, ci=r/27, tp=r%27;
                       wf[oWRR + (ci*27+tp)*16+co] = ldin(Wrr,l,f); }
  else if (i < 36017){ wf[oBINV + (i-35968)] = ldin(binv,i-35968,f); }
  else if (i < 36032){ }
  else if (i < 101568){ int l=i-36032; int co=l>>8, ci=l&255; wf[oWP1 + ci*256+co] = ldin(Wp1,l,f); }
  else if (i < 117952){ int l=i-101568; int o=l>>8, ci=l&255; wf[oWP2 + ci*64+o] = ldin(Wp2,l,f); }
  else if (i < 118016){ int l=i-117952; if(l<64) wf[oBP2 + l] = ldin(bp2,l,f); }
}

// ---- adaptive pool of raw x_WSI ----
__global__ void k_pool(const bf16* xwsi, float* pool){
  int i = blockIdx.x*256+threadIdx.x;            // 75264 = 2*588*64
  int c = i&63; int m=(i>>6)%588; int b=i/37632;
  int d=m/49, r=m%49, ii=r/7, jj=r%7;
  const bf16* src = xwsi + ((size_t)(b*64+c)*12 + d)*3136 + (ii*8)*56 + jj*8;
  float s=0;
  for(int u=0;u<8;u++) for(int v=0;v<8;v++) s += b2f(src[u*56+v]);
  pool[i] = s*(1.f/64.f);
}

// ---- xw1 = W_wsi * pooled + b ----
__global__ void k_xw1(const float* pool, const float* wf, float* xw1){
  int i = blockIdx.x*256+threadIdx.x;
  int c = i&63; int m=(i>>6)%588; int b=i/37632;
  const float* p = pool + (b*588+m)*64;
  const float* w = wf + oWWSI + c*64;
  float s = wf[oBWSI + c];
  for(int ci=0;ci<64;ci++) s += w[ci]*p[ci];
  xw1[i]=s;
}

// ---- Wx[b,o,tap,c] = sum_m W_att[o,m,tap] * xw1[b,c,m] ----
__global__ void k_Wx(const float* Wattf, const float* xw1, float* Wx){
  int i = blockIdx.x*256+threadIdx.x; if(i>=208000) return;
  int c=i&63; int r=i>>6; int tap=r%125; int o=(r/125)%13; int b=r/1625;
  const float* wa = Wattf + (size_t)o*588*125 + tap;
  const float* xp = xw1 + b*588*64 + c;
  float s=0;
  for(int m=0;m<588;m++) s += wa[(size_t)m*125] * xp[m*64];
  Wx[i]=s;
}

// ---- Wf: MFMA A-fragments, [b][tap125][ch][kg][m][8j] bf16, m>=13 zeroed ----
__global__ void k_Wfrag(const float* Wx, unsigned short* Wf){
  int i = blockIdx.x*256+threadIdx.x; if(i>=256000) return;
  int j=i&7; int m=(i>>3)&15; int kg=(i>>7)&3; int ch=(i>>9)&1;
  int r=i>>10; int tap=r%125; int b=r/125;
  int c = ch*32 + kg*8 + j;
  float v = (m<13) ? Wx[((size_t)(b*13+m)*125+tap)*64 + c] : 0.f;
  Wf[i] = f2u(v);
}

// ---- Winvx[b][c][kk] = sum_m W_inv[kk,m] * xw1[b,c,m] ----
__global__ void k_Winvx(const float* Winvf, const float* xw1, float* Wix){
  int i = blockIdx.x*256+threadIdx.x; if(i>=6272) return;
  int kk=i%49; int c=(i/49)&63; int b=i/3136;
  const float* xp = xw1 + b*588*64 + c;
  float s=0;
  for(int m=0;m<588;m++) s += Winvf[kk*588+m] * xp[m*64];
  Wix[i]=s;
}

// ---- x1 = W_ct * x_CT + b ; f32 [b][c][p] AND bf16 channel-last [b][p][c] ----
__global__ void k_x1(const bf16* xct, const float* wf, float* x1, unsigned short* x1t){
  int p = blockIdx.x*256+threadIdx.x;
  int co0 = blockIdx.y*16; int b = blockIdx.z;
  float acc[16];
  #pragma unroll
  for(int o=0;o<16;o++) acc[o]=wf[oBCT+co0+o];
  const bf16* xp = xct + (size_t)b*64*PP + p;
  for(int ci=0;ci<64;ci++){
    float xv = b2f(xp[(size_t)ci*PP]);
    const float* w = wf + oWCT + ci*64 + co0;
    #pragma unroll
    for(int o=0;o<16;o++) acc[o] += w[o]*xv;
  }
  float* out = x1 + ((size_t)b*64+co0)*PP + p;
  #pragma unroll
  for(int o=0;o<16;o++) out[(size_t)o*PP]=acc[o];
  unsigned int pk[8];
  #pragma unroll
  for(int o2=0;o2<8;o2++)
    pk[o2] = (unsigned)f2u(acc[2*o2]) | ((unsigned)f2u(acc[2*o2+1])<<16);
  unsigned short* xo = x1t + ((size_t)(b*PP)+p)*64 + co0;
  *(uint4*)xo     = make_uint4(pk[0],pk[1],pk[2],pk[3]);
  *(uint4*)(xo+8) = make_uint4(pk[4],pk[5],pk[6],pk[7]);
}

// ---- Att = sigmoid(conv5x5x5) via MFMA implicit GEMM ----
// block = (b,t, 8x8 px tile); 4 waves x 16px (2rows x 8cols); K = 5dt x 25tap x 64c
__global__ __launch_bounds__(256) void k_att(const unsigned short* x1t, const unsigned short* Wf,
                                             float* att){
  __shared__ short xt[10368];         // 144 px x 72 bf16 (144B stride: full bank spread)
  int tid=threadIdx.x;
  int tile=blockIdx.x, t=blockIdx.y, b=blockIdx.z;
  int y0=(tile/7)*8, x0=(tile%7)*8;
  int w=tid>>6, l=tid&63;
  int pc=l&7, pr=(l>>3)&1, g=l>>4;
  f32x4 acc0={0,0,0,0}, acc1={0,0,0,0};
  int bbase = ((2*w+pr)*12 + pc)*72 + g*8;
  const unsigned short* Wb = Wf + (size_t)b*128000 + l*8;
  for(int dt=0;dt<5;dt++){
    int ti=t+dt-2;
    if(ti<0||ti>=8) continue;                    // block-uniform
    __syncthreads();
    for(int e=tid;e<1152;e+=256){
      int px=e>>3, q=e&7;
      int row=px/12, col=px-row*12;
      int gy=y0+row-2, gx=x0+col-2;
      uint4 v={0,0,0,0};
      if((unsigned)gy<56u && (unsigned)gx<56u)
        v = *(const uint4*)(x1t + ((size_t)(b*PP) + ti*3136 + gy*56 + gx)*64 + q*8);
      *(uint4*)&xt[px*72 + q*8] = v;
    }
    __syncthreads();
    const unsigned short* Wd = Wb + dt*25600;
    #pragma unroll
    for(int dy=0;dy<5;dy++){
      #pragma unroll
      for(int dx=0;dx<5;dx++){
        int off = bbase + dy*864 + dx*72;
        short8v a0 = *(const short8v*)(Wd + (dy*5+dx)*1024);
        short8v b0 = *(const short8v*)&xt[off];
        acc0 = __builtin_amdgcn_mfma_f32_16x16x32_bf16(a0,b0,acc0,0,0,0);
        short8v a1 = *(const short8v*)(Wd + (dy*5+dx)*1024 + 512);
        short8v b1 = *(const short8v*)&xt[off+32];
        acc1 = __builtin_amdgcn_mfma_f32_16x16x32_bf16(a1,b1,acc1,0,0,0);
      }
    }
  }
  int px=l&15; int epc=px&7, epr=px>>3;
  size_t pbase=(size_t)t*3136+(size_t)(y0+2*w+epr)*56+x0+epc;
  #pragma unroll
  for(int r=0;r<4;r++){
    int o=g*4+r;
    if(o<13){
      float s=acc0[r]+acc1[r];
      att[((size_t)b*13+o)*PP+pbase]=1.f/(1.f+__expf(-s));
    }
  }
}

// ---- kern49 = Winvx * x1 + b_inv ----
__global__ void k_kern(const float* x1, const float* Wix, const float* wf, float* kern){
  int p = blockIdx.x*256+threadIdx.x; int b=blockIdx.y;
  float acc[49];
  #pragma unroll
  for(int kk=0;kk<49;kk++) acc[kk]=wf[oBINV+kk];
  const float* xp = x1 + (size_t)b*64*PP + p;
  for(int c=0;c<64;c++){
    float xv = xp[(size_t)c*PP];
    const float* w = Wix + (b*64+c)*49;
    #pragma unroll
    for(int kk=0;kk<49;kk++) acc[kk]+=w[kk]*xv;
  }
  float* out = kern + (size_t)b*49*PP + p;
  #pragma unroll
  for(int kk=0;kk<49;kk++) out[(size_t)kk*PP]=acc[kk];
}

// ---- xw3 = conv3x3x3(x_WSI, W_rr, pad=1) : ci-half split, bf16 partials ----
__global__ __launch_bounds__(128) void k_rr(const bf16* xwsi, const float* wf, bf16* xw3p){
  __shared__ float xt[16][10][16];
  int tid=threadIdx.x; int bx=blockIdx.x, d=blockIdx.y;
  int b=blockIdx.z>>1, half=blockIdx.z&1;
  int y0=(bx>>2)*8, x0=(bx&3)*14;
  int py=tid>>4, tx=tid&15;
  float acc[16];
  #pragma unroll
  for(int o=0;o<16;o++) acc[o]=0;
  for(int dz=0;dz<3;dz++){
    int di=d+dz-1; if(di<0||di>=12) continue;   // block-uniform
    for(int c0h=0;c0h<2;c0h++){
      int c0 = half*32 + c0h*16;
      __syncthreads();
      #pragma unroll
      for(int c=0;c<16;c++){
        const bf16* src = xwsi + ((size_t)(b*64+c0+c)*12+di)*3136;
        int gy=y0+py-1, gx=x0+tx-1;
        float v=0;
        if(gy>=0&&gy<56&&gx>=0&&gx<56) v=b2f(src[gy*56+gx]);
        xt[c][py][tx]=v;
        if(tid<32){
          int yy2=8+py; int gy2=y0+yy2-1;
          float v2=0;
          if(gy2>=0&&gy2<56&&gx>=0&&gx<56) v2=b2f(src[gy2*56+gx]);
          xt[c][yy2][tx]=v2;
        }
      }
      __syncthreads();
      if(tx<14){
        for(int c=0;c<16;c++){
          #pragma unroll
          for(int dy=0;dy<3;dy++){
            #pragma unroll
            for(int dx=0;dx<3;dx++){
              float xv=xt[c][py+dy][tx+dx];
              const float* w = wf + oWRR + ((c0+c)*27 + dz*9+dy*3+dx)*16;
              #pragma unroll
              for(int o=0;o<16;o++) acc[o]+=w[o]*xv;
            }
          }
        }
      }
    }
  }
  if(tx<14){
    bf16* out = xw3p + (((size_t)(half*2+b)*16)*12 + d)*3136 + (y0+py)*56 + x0+tx;
    #pragma unroll
    for(int o=0;o<16;o++) out[(size_t)o*12*3136]=f2b(acc[o]);
  }
}

// ---- x_Att = x_FS * (1 + Att_FS) ----
__global__ void k_xatt(const bf16* xct, const bf16* xw3p, const float* att, bf16* xatt){
  int p=blockIdx.x*256+threadIdx.x; int ch=blockIdx.y; int b=blockIdx.z;
  float v;
  if(ch<64){
    v = b2f(xct[((size_t)b*64+ch)*PP+p]) * (1.f+att[(size_t)b*13*PP+p]);
  } else {
    int q=ch-64; int co=q/12, dd=q-co*12;       // block-uniform
    int s=p%3136;
    size_t i0=(((size_t)(0+b)*16+co)*12+dd)*3136+s;
    size_t i1=(((size_t)(2+b)*16+co)*12+dd)*3136+s;
    v = (b2f(xw3p[i0])+b2f(xw3p[i1])) * (1.f+att[((size_t)b*13+1+q/16)*PP+p]);
  }
  xatt[((size_t)b*256+ch)*PP+p]=f2b(v);
}

// ---- y1 = W_p1 * x_Att ----
__global__ void k_p1(const bf16* xatt, const float* wf, bf16* y1){
  int p=blockIdx.x*256+threadIdx.x;
  int co0=blockIdx.y*16; int b=blockIdx.z;
  float acc[16];
  #pragma unroll
  for(int o=0;o<16;o++) acc[o]=0;
  const bf16* xp = xatt + (size_t)b*256*PP + p;
  for(int ci=0;ci<256;ci++){
    float xv=b2f(xp[(size_t)ci*PP]);
    const float* w = wf + oWP1 + ci*256 + co0;
    #pragma unroll
    for(int o=0;o<16;o++) acc[o]+=w[o]*xv;
  }
  bf16* out = y1 + ((size_t)b*256+co0)*PP + p;
  #pragma unroll
  for(int o=0;o<16;o++) out[(size_t)o*PP]=f2b(acc[o]);
}

// ---- per-channel sum / sumsq ----
__global__ void k_stats(const bf16* src, float* sum, float* sq){
  __shared__ float rs[256], rq[256];
  int tid=threadIdx.x;
  int chunk=blockIdx.x, ch=blockIdx.y, b=blockIdx.z;
  const bf16* p = src + ((size_t)b*256+ch)*PP + chunk*3136;
  float s=0,q=0;
  for(int i=tid;i<3136;i+=256){ float v=b2f(p[i]); s+=v; q+=v*v; }
  rs[tid]=s; rq[tid]=q; __syncthreads();
  for(int st=128;st>0;st>>=1){ if(tid<st){rs[tid]+=rs[tid+st]; rq[tid]+=rq[tid+st];} __syncthreads(); }
  if(tid==0){ atomicAdd(&sum[ch],rs[0]); atomicAdd(&sq[ch],rq[0]); }
}
__global__ void k_finstat(const float* sum, const float* sq, const void* g, const void* be,
                          const int* flag, float* sc, float* sh){
  int ch=threadIdx.x;
  int f=flag[0];
  float m = sum[ch]*(1.f/50176.f);
  float v = sq[ch]*(1.f/50176.f) - m*m;
  float s = ldin(g,ch,f) * rsqrtf(v+1e-5f);
  sc[ch]=s; sh[ch]=ldin(be,ch,f) - m*s;
}

// ---- xatt1 = relu(bn1(y1)), transposed [b][p][ch] ----
__global__ void k_bn1(const bf16* y1, const float* sc, const float* sh, bf16* xatt1){
  __shared__ unsigned short tl[64][258];
  int tid=threadIdx.x; int p0=blockIdx.x*64; int b=blockIdx.y;
  for(int k=0;k<64;k++){
    int idx=k*256+tid; int ch=idx>>6, pp=idx&63;
    float v=b2f(y1[((size_t)b*256+ch)*PP + p0+pp]);
    v = v*sc[ch]+sh[ch]; v = v>0?v:0;
    bf16 h=f2b(v); tl[pp][ch]=*(unsigned short*)&h;
  }
  __syncthreads();
  for(int k=0;k<64;k++){
    unsigned short u=tl[k][tid];
    xatt1[((size_t)b*PP + p0+k)*256 + tid] = *(bf16*)&u;
  }
}

// ---- involution ----
__global__ __launch_bounds__(64) void k_inv(const bf16* xatt1, const float* kern, bf16* inv){
  __shared__ __align__(16) unsigned short xt[196*72];
  int tid=threadIdx.x;
  int bx=blockIdx.x, by=blockIdx.y, bz=blockIdx.z;
  int t=bz&7, b=bz>>3;
  int y0=(bx/7)*8, x0=(bx%7)*8, c0=by*64;
  int ty=tid>>3, tx=tid&7;
  for(int e=tid;e<1568;e+=64){
    int row=e>>3, seg=e&7;
    int yy=row/14, xx=row%14;
    int gy=y0+yy-3, gx=x0+xx-3;
    uint4 v={0,0,0,0};
    if(gy>=0&&gy<56&&gx>=0&&gx<56)
      v = *(const uint4*)&xatt1[((size_t)b*PP + t*3136 + gy*56+gx)*256 + c0 + seg*8];
    *(uint4*)&xt[row*72+seg*8]=v;
  }
  float kr[49];
  size_t px=(size_t)t*3136 + (y0+ty)*56 + x0+tx;
  #pragma unroll
  for(int kk=0;kk<49;kk++) kr[kk]=kern[((size_t)b*49+kk)*PP+px];
  __syncthreads();
  for(int sub=0;sub<8;sub++){
    float acc[8];
    #pragma unroll
    for(int e=0;e<8;e++) acc[e]=0;
    for(int i=0;i<7;i++){
      #pragma unroll
      for(int j=0;j<7;j++){
        uint4 u = *(const uint4*)&xt[((ty+i)*14+tx+j)*72 + sub*8];
        float kv = kr[i*7+j];
        acc[0]+=kv*blo(u.x); acc[1]+=kv*bhi(u.x);
        acc[2]+=kv*blo(u.y); acc[3]+=kv*bhi(u.y);
        acc[4]+=kv*blo(u.z); acc[5]+=kv*bhi(u.z);
        acc[6]+=kv*blo(u.w); acc[7]+=kv*bhi(u.w);
      }
    }
    #pragma unroll
    for(int e=0;e<8;e++)
      inv[((size_t)b*256+c0+sub*8+e)*PP+px]=f2b(acc[e]);
  }
}

// ---- out = W_p2 * (bn2(inv) + x_Att) + b_p2  (f32 output) ----
__global__ void k_final(const bf16* inv, const bf16* xatt, const float* wf,
                        const float* sc2, const float* sh2, float* out){
  int p=blockIdx.x*256+threadIdx.x; int o0=blockIdx.y*16; int b=blockIdx.z;
  float acc[16];
  #pragma unroll
  for(int o=0;o<16;o++) acc[o]=wf[oBP2+o0+o];
  const bf16* ip = inv + (size_t)b*256*PP + p;
  const bf16* xp = xatt + (size_t)b*256*PP + p;
  for(int ci=0;ci<256;ci++){
    float v = b2f(ip[(size_t)ci*PP])*sc2[ci]+sh2[ci] + b2f(xp[(size_t)ci*PP]);
    const float* w = wf + oWP2 + ci*64 + o0;
    #pragma unroll
    for(int o=0;o<16;o++) acc[o]+=w[o]*v;
  }
  float* op = out + ((size_t)b*64+o0)*PP + p;
  #pragma unroll
  for(int o=0;o<16;o++) op[(size_t)o*PP]=acc[o];
}

extern "C" void kernel_launch(void* const* d_in, const int* in_sizes, int n_in,
                              void* d_out, int out_size, void* d_ws, size_t ws_size,
                              hipStream_t stream){
  const void* xct_r =d_in[0];
  const void* xwsi_r=d_in[1];
  const void* Wct =d_in[2];
  const void* bct =d_in[3];
  const void* Wwsi=d_in[4];
  const void* bwsi=d_in[5];
  const void* Watt=d_in[6];
  const void* Winv=d_in[7];
  const void* binv=d_in[8];
  const void* Wrr =d_in[9];
  const void* g1  =d_in[10];
  const void* be1 =d_in[11];
  const void* g2  =d_in[12];
  const void* be2 =d_in[13];
  const void* Wp1 =d_in[14];
  const void* Wp2 =d_in[16];
  const void* bp2 =d_in[17];
  float* ws=(float*)d_ws;
  float* x1=ws+X1o; float* pool=ws+POOLo; float* xw1=ws+XW1o;
  float* Wx=ws+WXo; float* Wix=ws+WIXo;
  float* att=ws+ATTo; float* kern=ws+KERNo;
  unsigned short* Wf=(unsigned short*)(ws+WXTo);
  unsigned short* x1t=(unsigned short*)(ws+X1To);
  bf16* xw3p=(bf16*)(ws+XW3o);
  float* stat=ws+STATo; float* wf=ws+WFo;
  float* Wattf=ws+WATTFo; float* Winvf=ws+WINVFo;
  int* flag=(int*)(ws+FLAGo);
  bf16* bfb=(bf16*)(ws+BF16o);
  bf16* xctb=bfb+bXCT; bf16* xwsib=bfb+bXWSI;
  bf16* xatt=bfb+bXATT; bf16* y1=bfb+bY1; bf16* invb=bfb+bINV; bf16* xatt1=bfb+bXATT1;
  float* sum1=stat; float* sq1=stat+256; float* sum2=stat+512; float* sq2=stat+768;
  float* sc1=stat+1024; float* sh1=stat+1280; float* sc2=stat+1536; float* sh2=stat+1792;

  hipMemsetAsync(stat,0,4096,stream);
  k_detect<<<1,64,0,stream>>>((const unsigned short*)xct_r,flag);
  k_c2b   <<<12544,256,0,stream>>>(xct_r,xctb,3211264,flag);
  k_c2b   <<<18816,256,0,stream>>>(xwsi_r,xwsib,4816896,flag);
  k_c2f   <<<3733,256,0,stream>>>(Watt,Wattf,955500,flag);
  k_c2f   <<<113,256,0,stream>>>(Winv,Winvf,28812,flag);
  k_cvt   <<<461,256,0,stream>>>(Wct,bct,Wwsi,bwsi,Wrr,binv,Wp1,Wp2,bp2,wf,flag);
  k_pool  <<<294,256,0,stream>>>(xwsib,pool);
  k_xw1   <<<294,256,0,stream>>>(pool,wf,xw1);
  k_Wx    <<<813,256,0,stream>>>(Wattf,xw1,Wx);
  k_Wfrag <<<1000,256,0,stream>>>(Wx,Wf);
  k_Winvx <<<25,256,0,stream>>>(Winvf,xw1,Wix);
  k_x1    <<<dim3(98,4,2),256,0,stream>>>(xctb,wf,x1,x1t);
  k_att   <<<dim3(49,8,2),256,0,stream>>>(x1t,Wf,att);      // MFMA implicit GEMM
  k_kern  <<<dim3(98,2),256,0,stream>>>(x1,Wix,wf,kern);    // overwrites x1t (dead)
  k_rr    <<<dim3(28,12,4),128,0,stream>>>(xwsib,wf,xw3p);
  k_xatt  <<<dim3(98,256,2),256,0,stream>>>(xctb,xw3p,att,xatt);
  k_p1    <<<dim3(98,16,2),256,0,stream>>>(xatt,wf,y1);
  k_stats <<<dim3(8,256,2),256,0,stream>>>(y1,sum1,sq1);
  k_finstat<<<1,256,0,stream>>>(sum1,sq1,g1,be1,flag,sc1,sh1);
  k_bn1   <<<dim3(392,2),256,0,stream>>>(y1,sc1,sh1,xatt1);
  k_inv   <<<dim3(49,4,16),64,0,stream>>>(xatt1,kern,invb);
  k_stats <<<dim3(8,256,2),256,0,stream>>>(invb,sum2,sq2);
  k_finstat<<<1,256,0,stream>>>(sum2,sq2,g2,be2,flag,sc2,sh2);
  k_final <<<dim3(98,4,2),256,0,stream>>>(invb,xatt,wf,sc2,sh2,(float*)d_out);
}

// Round 9
// 520.845 us; speedup vs baseline: 1.9665x; 1.2274x over previous
//
#include <hip/hip_runtime.h>
#include <hip/hip_bf16.h>
#include <math.h>

typedef __hip_bfloat16 bf16;
typedef __attribute__((ext_vector_type(8))) short short8v;
typedef __attribute__((ext_vector_type(4))) float f32x4;
#define DEV static __device__ __forceinline__
DEV float b2f(bf16 x){ return __bfloat162float(x); }
DEV bf16  f2b(float x){ return __float2bfloat16(x); }
DEV unsigned short f2u(float x){ bf16 h=f2b(x); return *(unsigned short*)&h; }
DEV float blo(unsigned int w){ return __uint_as_float(w<<16); }
DEV float bhi(unsigned int w){ return __uint_as_float(w&0xffff0000u); }
DEV float ldin(const void* p, long i, int f){
  return f ? ((const float*)p)[i] : b2f(((const bf16*)p)[i]);
}

// problem dims
#define PP 25088            // t*h*w = 8*56*56

// ws layout (float units)
#define X1o    0L           // 2*64*25088
#define POOLo  3211264L     // 2*588*64   [b][m][c]
#define XW1o   3286528L     // 2*588*64   [b][m][c]
#define WXo    3361792L     // Wx f32 208000; head re-aliased by Wrr2 (13824 f) after k_Wfrag
#define WXTo   3569792L     // Wf MFMA A-frags: 256000 bf16
#define WIXo   3825792L     // 2*64*49    [b][c][kk]
#define ATTo   3832064L     // 2*13*25088 (post-sigmoid, f32)
#define KERNo  4484352L     // 2*49*25088 f32; head aliased by x1t before k_kern runs
#define XW3o   6942976L     // xw3 bf16 [2][16][12][3136] = 1204224 sh
#define STATo  8147200L     // sums(1024) + scale/shift(1024)
#define FLAGo  8149248L     // dtype flag (int), 16 floats reserved
#define WFo    8149264L     // converted f32 weights (118016)
#define WATTFo 8267280L     // W_att as f32 (955500, pad 955504)
#define WINVFo 9222784L     // W_inv as f32 (28812, pad 28816)
#define BF16o  9251600L     // bf16 region starts here (float idx)
#define X1To   KERNo        // x1t bf16 [b][p][64c]: k_x1 writes -> k_att reads -> k_kern overwrites
#define WRR2o  WXo          // Wrr2 A-frags 27648 bf16: written after k_Wfrag consumed Wx
// bf16 sub-offsets (bf16 element units)
#define bXCT   0L           // 3211264
#define bXWSI  3211264L     // 4816896
#define bXATT  8028160L     // 12845056
#define bY1    20873216L    // 12845056
#define bINV   20873216L    // alias: y1 dead after k_bn1
#define bXATT1 33718272L    // 12845056
#define bXWT   bY1          // xwt bf16 [b][d][hw][64] = 4816896 sh; dead before k_p1 writes y1
// wf sub-offsets
#define oWCT   0            // [ci][co] 64x64
#define oBCT   4096
#define oWWSI  4160         // [co][ci] (untransposed)
#define oBWSI  8256
#define oWRR   8320         // [(ci*27+tap)*16+co]
#define oBINV  35968
#define oWP1   36032        // [ci][co] 256x256
#define oWP2   101568       // [ci][co] 256x64
#define oBP2   117952

// ---- input dtype probe ----
__global__ void k_detect(const unsigned short* raw, int* flag){
  int t = threadIdx.x;
  unsigned short u = raw[2*t];
  int e = (u>>7)&0xFF;
  int hit = (e >= 137);
  unsigned long long m = __ballot(hit);
  if(t==0) flag[0] = (__popcll(m) >= 8) ? 1 : 0;   // 1 = inputs are f32
}

// ---- canonicalize inputs ----
__global__ void k_c2b(const void* src, bf16* dst, int n, const int* flag){
  int i = blockIdx.x*256+threadIdx.x; if(i>=n) return;
  int f = flag[0];
  dst[i] = f ? f2b(((const float*)src)[i]) : ((const bf16*)src)[i];
}
__global__ void k_c2f(const void* src, float* dst, int n, const int* flag){
  int i = blockIdx.x*256+threadIdx.x; if(i>=n) return;
  dst[i] = ldin(src, i, flag[0]);
}

// ---- weight convert (+transpose to put out-channel innermost) ----
__global__ void k_cvt(const void* Wct,const void* bct,const void* Wwsi,const void* bwsi,
                      const void* Wrr,const void* binv,const void* Wp1,const void* Wp2,
                      const void* bp2,float* wf,const int* flag){
  int i = blockIdx.x*256 + threadIdx.x;
  int f = flag[0];
  if (i < 4096){ int co=i>>6, ci=i&63; wf[oWCT + ci*64+co] = ldin(Wct,i,f); }
  else if (i < 4160){ wf[i] = ldin(bct,i-4096,f); }
  else if (i < 8256){ wf[i] = ldin(Wwsi,i-4160,f); }
  else if (i < 8320){ wf[i] = ldin(bwsi,i-8256,f); }
  else if (i < 35968){ int l=i-8320; int co=l/1728, r=l%1728, ci=r/27, tp=r%27;
                       wf[oWRR + (ci*27+tp)*16+co] = ldin(Wrr,l,f); }
  else if (i < 36017){ wf[oBINV + (i-35968)] = ldin(binv,i-35968,f); }
  else if (i < 36032){ }
  else if (i < 101568){ int l=i-36032; int co=l>>8, ci=l&255; wf[oWP1 + ci*256+co] = ldin(Wp1,l,f); }
  else if (i < 117952){ int l=i-101568; int o=l>>8, ci=l&255; wf[oWP2 + ci*64+o] = ldin(Wp2,l,f); }
  else if (i < 118016){ int l=i-117952; if(l<64) wf[oBP2 + l] = ldin(bp2,l,f); }
}

// ---- adaptive pool of raw x_WSI ----
__global__ void k_pool(const bf16* xwsi, float* pool){
  int i = blockIdx.x*256+threadIdx.x;            // 75264 = 2*588*64
  int c = i&63; int m=(i>>6)%588; int b=i/37632;
  int d=m/49, r=m%49, ii=r/7, jj=r%7;
  const bf16* src = xwsi + ((size_t)(b*64+c)*12 + d)*3136 + (ii*8)*56 + jj*8;
  float s=0;
  for(int u=0;u<8;u++) for(int v=0;v<8;v++) s += b2f(src[u*56+v]);
  pool[i] = s*(1.f/64.f);
}

// ---- xwt = channel-last x_WSI [b][d][hw][64] (bn1-style LDS transpose) ----
__global__ void k_wsit(const bf16* xwsib, unsigned short* xwt){
  __shared__ unsigned short tl[64*68];
  int tid=threadIdx.x; int p0=blockIdx.x*64; int d=blockIdx.y; int b=blockIdx.z;
  #pragma unroll
  for(int k=0;k<16;k++){
    int idx=k*256+tid; int px=idx&63, c=idx>>6;
    bf16 h = xwsib[((size_t)(b*64+c)*12+d)*3136 + p0+px];
    tl[px*68+c] = *(unsigned short*)&h;
  }
  __syncthreads();
  #pragma unroll
  for(int k=0;k<16;k++){
    int idx=k*256+tid; int px=idx>>6, ch=idx&63;
    xwt[((size_t)(b*12+d)*3136 + p0+px)*64 + ch] = tl[px*68+ch];
  }
}

// ---- xw1 = W_wsi * pooled + b ----
__global__ void k_xw1(const float* pool, const float* wf, float* xw1){
  int i = blockIdx.x*256+threadIdx.x;
  int c = i&63; int m=(i>>6)%588; int b=i/37632;
  const float* p = pool + (b*588+m)*64;
  const float* w = wf + oWWSI + c*64;
  float s = wf[oBWSI + c];
  for(int ci=0;ci<64;ci++) s += w[ci]*p[ci];
  xw1[i]=s;
}

// ---- Wx[b,o,tap,c] = sum_m W_att[o,m,tap] * xw1[b,c,m] ----
__global__ void k_Wx(const float* Wattf, const float* xw1, float* Wx){
  int i = blockIdx.x*256+threadIdx.x; if(i>=208000) return;
  int c=i&63; int r=i>>6; int tap=r%125; int o=(r/125)%13; int b=r/1625;
  const float* wa = Wattf + (size_t)o*588*125 + tap;
  const float* xp = xw1 + b*588*64 + c;
  float s=0;
  for(int m=0;m<588;m++) s += wa[(size_t)m*125] * xp[m*64];
  Wx[i]=s;
}

// ---- Wf: MFMA A-fragments for k_att ----
__global__ void k_Wfrag(const float* Wx, unsigned short* Wf){
  int i = blockIdx.x*256+threadIdx.x; if(i>=256000) return;
  int j=i&7; int m=(i>>3)&15; int kg=(i>>7)&3; int ch=(i>>9)&1;
  int r=i>>10; int tap=r%125; int b=r/125;
  int c = ch*32 + kg*8 + j;
  float v = (m<13) ? Wx[((size_t)(b*13+m)*125+tap)*64 + c] : 0.f;
  Wf[i] = f2u(v);
}

// ---- Wrr2: MFMA A-fragments for k_rr: [td27][kg2][lane64][8j] ----
__global__ void k_rrfrag(const float* wf, unsigned short* Wrr2){
  int i = blockIdx.x*256+threadIdx.x; if(i>=27648) return;
  int j=i&7; int l=(i>>3)&63; int kg=(i>>9)&1; int td=i>>10;
  int m=l&15, g=l>>4;
  int c = kg*32 + g*8 + j;
  Wrr2[i] = f2u(wf[oWRR + (c*27+td)*16 + m]);
}

// ---- Winvx[b][c][kk] = sum_m W_inv[kk,m] * xw1[b,c,m] ----
__global__ void k_Winvx(const float* Winvf, const float* xw1, float* Wix){
  int i = blockIdx.x*256+threadIdx.x; if(i>=6272) return;
  int kk=i%49; int c=(i/49)&63; int b=i/3136;
  const float* xp = xw1 + b*588*64 + c;
  float s=0;
  for(int m=0;m<588;m++) s += Winvf[kk*588+m] * xp[m*64];
  Wix[i]=s;
}

// ---- x1 = W_ct * x_CT + b ; f32 [b][c][p] AND bf16 channel-last [b][p][c] ----
__global__ void k_x1(const bf16* xct, const float* wf, float* x1, unsigned short* x1t){
  int p = blockIdx.x*256+threadIdx.x;
  int co0 = blockIdx.y*16; int b = blockIdx.z;
  float acc[16];
  #pragma unroll
  for(int o=0;o<16;o++) acc[o]=wf[oBCT+co0+o];
  const bf16* xp = xct + (size_t)b*64*PP + p;
  for(int ci=0;ci<64;ci++){
    float xv = b2f(xp[(size_t)ci*PP]);
    const float* w = wf + oWCT + ci*64 + co0;
    #pragma unroll
    for(int o=0;o<16;o++) acc[o] += w[o]*xv;
  }
  float* out = x1 + ((size_t)b*64+co0)*PP + p;
  #pragma unroll
  for(int o=0;o<16;o++) out[(size_t)o*PP]=acc[o];
  unsigned int pk[8];
  #pragma unroll
  for(int o2=0;o2<8;o2++)
    pk[o2] = (unsigned)f2u(acc[2*o2]) | ((unsigned)f2u(acc[2*o2+1])<<16);
  unsigned short* xo = x1t + ((size_t)(b*PP)+p)*64 + co0;
  *(uint4*)xo     = make_uint4(pk[0],pk[1],pk[2],pk[3]);
  *(uint4*)(xo+8) = make_uint4(pk[4],pk[5],pk[6],pk[7]);
}

// ---- Att = sigmoid(conv5x5x5) via MFMA implicit GEMM ----
__global__ __launch_bounds__(256) void k_att(const unsigned short* x1t, const unsigned short* Wf,
                                             float* att){
  __shared__ short xt[10368];         // 144 px x 72 bf16
  int tid=threadIdx.x;
  int tile=blockIdx.x, t=blockIdx.y, b=blockIdx.z;
  int y0=(tile/7)*8, x0=(tile%7)*8;
  int w=tid>>6, l=tid&63;
  int pc=l&7, pr=(l>>3)&1, g=l>>4;
  f32x4 acc0={0,0,0,0}, acc1={0,0,0,0};
  int bbase = ((2*w+pr)*12 + pc)*72 + g*8;
  const unsigned short* Wb = Wf + (size_t)b*128000 + l*8;
  for(int dt=0;dt<5;dt++){
    int ti=t+dt-2;
    if(ti<0||ti>=8) continue;                    // block-uniform
    __syncthreads();
    for(int e=tid;e<1152;e+=256){
      int px=e>>3, q=e&7;
      int row=px/12, col=px-row*12;
      int gy=y0+row-2, gx=x0+col-2;
      uint4 v={0,0,0,0};
      if((unsigned)gy<56u && (unsigned)gx<56u)
        v = *(const uint4*)(x1t + ((size_t)(b*PP) + ti*3136 + gy*56 + gx)*64 + q*8);
      *(uint4*)&xt[px*72 + q*8] = v;
    }
    __syncthreads();
    const unsigned short* Wd = Wb + dt*25600;
    #pragma unroll
    for(int dy=0;dy<5;dy++){
      #pragma unroll
      for(int dx=0;dx<5;dx++){
        int off = bbase + dy*864 + dx*72;
        short8v a0 = *(const short8v*)(Wd + (dy*5+dx)*1024);
        short8v b0 = *(const short8v*)&xt[off];
        acc0 = __builtin_amdgcn_mfma_f32_16x16x32_bf16(a0,b0,acc0,0,0,0);
        short8v a1 = *(const short8v*)(Wd + (dy*5+dx)*1024 + 512);
        short8v b1 = *(const short8v*)&xt[off+32];
        acc1 = __builtin_amdgcn_mfma_f32_16x16x32_bf16(a1,b1,acc1,0,0,0);
      }
    }
  }
  int px=l&15; int epc=px&7, epr=px>>3;
  size_t pbase=(size_t)t*3136+(size_t)(y0+2*w+epr)*56+x0+epc;
  #pragma unroll
  for(int r=0;r<4;r++){
    int o=g*4+r;
    if(o<13){
      float s=acc0[r]+acc1[r];
      att[((size_t)b*13+o)*PP+pbase]=1.f/(1.f+__expf(-s));
    }
  }
}

// ---- kern49 = Winvx * x1 + b_inv ----
__global__ void k_kern(const float* x1, const float* Wix, const float* wf, float* kern){
  int p = blockIdx.x*256+threadIdx.x; int b=blockIdx.y;
  float acc[49];
  #pragma unroll
  for(int kk=0;kk<49;kk++) acc[kk]=wf[oBINV+kk];
  const float* xp = x1 + (size_t)b*64*PP + p;
  for(int c=0;c<64;c++){
    float xv = xp[(size_t)c*PP];
    const float* w = Wix + (b*64+c)*49;
    #pragma unroll
    for(int kk=0;kk<49;kk++) acc[kk]+=w[kk]*xv;
  }
  float* out = kern + (size_t)b*49*PP + p;
  #pragma unroll
  for(int kk=0;kk<49;kk++) out[(size_t)kk*PP]=acc[kk];
}

// ---- xw3 = conv3x3x3 via MFMA implicit GEMM; writes bf16 [b*16+o][12d][hw] ----
__global__ __launch_bounds__(256) void k_rr(const unsigned short* xwt, const unsigned short* Wrr2,
                                            bf16* xw3){
  __shared__ short xt[7200];          // 100 px x 72 bf16
  int tid=threadIdx.x;
  int tile=blockIdx.x, d=blockIdx.y, b=blockIdx.z;
  int y0=(tile/7)*8, x0=(tile%7)*8;
  int w=tid>>6, l=tid&63;
  int pc=l&7, pr=(l>>3)&1, g=l>>4;
  f32x4 acc0={0,0,0,0}, acc1={0,0,0,0};
  int bbase = ((2*w+pr)*10 + pc)*72 + g*8;
  const unsigned short* Wl = Wrr2 + l*8;
  for(int dz=0;dz<3;dz++){
    int di=d+dz-1;
    if(di<0||di>=12) continue;                   // block-uniform
    __syncthreads();
    for(int e=tid;e<800;e+=256){
      int px=e>>3, q=e&7;
      int row=px/10, col=px-row*10;
      int gy=y0+row-1, gx=x0+col-1;
      uint4 v={0,0,0,0};
      if((unsigned)gy<56u && (unsigned)gx<56u)
        v = *(const uint4*)(xwt + ((size_t)(b*12+di)*3136 + gy*56 + gx)*64 + q*8);
      *(uint4*)&xt[px*72 + q*8] = v;
    }
    __syncthreads();
    const unsigned short* Wd = Wl + dz*9216;
    #pragma unroll
    for(int tap=0;tap<9;tap++){
      int dy=tap/3, dx=tap-dy*3;
      int off = bbase + (dy*10+dx)*72;
      short8v a0 = *(const short8v*)(Wd + tap*1024);
      short8v b0 = *(const short8v*)&xt[off];
      acc0 = __builtin_amdgcn_mfma_f32_16x16x32_bf16(a0,b0,acc0,0,0,0);
      short8v a1 = *(const short8v*)(Wd + tap*1024 + 512);
      short8v b1 = *(const short8v*)&xt[off+32];
      acc1 = __builtin_amdgcn_mfma_f32_16x16x32_bf16(a1,b1,acc1,0,0,0);
    }
  }
  int px=l&15; int epc=px&7, epr=px>>3;
  size_t pp=(size_t)(y0+2*w+epr)*56 + x0+epc;
  #pragma unroll
  for(int r=0;r<4;r++){
    int o=g*4+r;
    xw3[((size_t)(b*16+o)*12+d)*3136 + pp] = f2b(acc0[r]+acc1[r]);
  }
}

// ---- x_Att = x_FS * (1 + Att_FS) ----
__global__ void k_xatt(const bf16* xct, const bf16* xw3, const float* att, bf16* xatt){
  int p=blockIdx.x*256+threadIdx.x; int ch=blockIdx.y; int b=blockIdx.z;
  float v;
  if(ch<64){
    v = b2f(xct[((size_t)b*64+ch)*PP+p]) * (1.f+att[(size_t)b*13*PP+p]);
  } else {
    int q=ch-64; int co=q/12, dd=q-co*12;       // block-uniform
    int s=p%3136;
    v = b2f(xw3[((size_t)(b*16+co)*12+dd)*3136+s]) * (1.f+att[((size_t)b*13+1+q/16)*PP+p]);
  }
  xatt[((size_t)b*256+ch)*PP+p]=f2b(v);
}

// ---- y1 = W_p1 * x_Att ----
__global__ void k_p1(const bf16* xatt, const float* wf, bf16* y1){
  int p=blockIdx.x*256+threadIdx.x;
  int co0=blockIdx.y*16; int b=blockIdx.z;
  float acc[16];
  #pragma unroll
  for(int o=0;o<16;o++) acc[o]=0;
  const bf16* xp = xatt + (size_t)b*256*PP + p;
  for(int ci=0;ci<256;ci++){
    float xv=b2f(xp[(size_t)ci*PP]);
    const float* w = wf + oWP1 + ci*256 + co0;
    #pragma unroll
    for(int o=0;o<16;o++) acc[o]+=w[o]*xv;
  }
  bf16* out = y1 + ((size_t)b*256+co0)*PP + p;
  #pragma unroll
  for(int o=0;o<16;o++) out[(size_t)o*PP]=f2b(acc[o]);
}

// ---- per-channel sum / sumsq ----
__global__ void k_stats(const bf16* src, float* sum, float* sq){
  __shared__ float rs[256], rq[256];
  int tid=threadIdx.x;
  int chunk=blockIdx.x, ch=blockIdx.y, b=blockIdx.z;
  const bf16* p = src + ((size_t)b*256+ch)*PP + chunk*3136;
  float s=0,q=0;
  for(int i=tid;i<3136;i+=256){ float v=b2f(p[i]); s+=v; q+=v*v; }
  rs[tid]=s; rq[tid]=q; __syncthreads();
  for(int st=128;st>0;st>>=1){ if(tid<st){rs[tid]+=rs[tid+st]; rq[tid]+=rq[tid+st];} __syncthreads(); }
  if(tid==0){ atomicAdd(&sum[ch],rs[0]); atomicAdd(&sq[ch],rq[0]); }
}
__global__ void k_finstat(const float* sum, const float* sq, const void* g, const void* be,
                          const int* flag, float* sc, float* sh){
  int ch=threadIdx.x;
  int f=flag[0];
  float m = sum[ch]*(1.f/50176.f);
  float v = sq[ch]*(1.f/50176.f) - m*m;
  float s = ldin(g,ch,f) * rsqrtf(v+1e-5f);
  sc[ch]=s; sh[ch]=ldin(be,ch,f) - m*s;
}

// ---- xatt1 = relu(bn1(y1)), transposed [b][p][ch] ----
__global__ void k_bn1(const bf16* y1, const float* sc, const float* sh, bf16* xatt1){
  __shared__ unsigned short tl[64][258];
  int tid=threadIdx.x; int p0=blockIdx.x*64; int b=blockIdx.y;
  for(int k=0;k<64;k++){
    int idx=k*256+tid; int ch=idx>>6, pp=idx&63;
    float v=b2f(y1[((size_t)b*256+ch)*PP + p0+pp]);
    v = v*sc[ch]+sh[ch]; v = v>0?v:0;
    bf16 h=f2b(v); tl[pp][ch]=*(unsigned short*)&h;
  }
  __syncthreads();
  for(int k=0;k<64;k++){
    unsigned short u=tl[k][tid];
    xatt1[((size_t)b*PP + p0+k)*256 + tid] = *(bf16*)&u;
  }
}

// ---- involution ----
__global__ __launch_bounds__(64) void k_inv(const bf16* xatt1, const float* kern, bf16* inv){
  __shared__ __align__(16) unsigned short xt[196*72];
  int tid=threadIdx.x;
  int bx=blockIdx.x, by=blockIdx.y, bz=blockIdx.z;
  int t=bz&7, b=bz>>3;
  int y0=(bx/7)*8, x0=(bx%7)*8, c0=by*64;
  int ty=tid>>3, tx=tid&7;
  for(int e=tid;e<1568;e+=64){
    int row=e>>3, seg=e&7;
    int yy=row/14, xx=row%14;
    int gy=y0+yy-3, gx=x0+xx-3;
    uint4 v={0,0,0,0};
    if(gy>=0&&gy<56&&gx>=0&&gx<56)
      v = *(const uint4*)&xatt1[((size_t)b*PP + t*3136 + gy*56+gx)*256 + c0 + seg*8];
    *(uint4*)&xt[row*72+seg*8]=v;
  }
  float kr[49];
  size_t px=(size_t)t*3136 + (y0+ty)*56 + x0+tx;
  #pragma unroll
  for(int kk=0;kk<49;kk++) kr[kk]=kern[((size_t)b*49+kk)*PP+px];
  __syncthreads();
  for(int sub=0;sub<8;sub++){
    float acc[8];
    #pragma unroll
    for(int e=0;e<8;e++) acc[e]=0;
    for(int i=0;i<7;i++){
      #pragma unroll
      for(int j=0;j<7;j++){
        uint4 u = *(const uint4*)&xt[((ty+i)*14+tx+j)*72 + sub*8];
        float kv = kr[i*7+j];
        acc[0]+=kv*blo(u.x); acc[1]+=kv*bhi(u.x);
        acc[2]+=kv*blo(u.y); acc[3]+=kv*bhi(u.y);
        acc[4]+=kv*blo(u.z); acc[5]+=kv*bhi(u.z);
        acc[6]+=kv*blo(u.w); acc[7]+=kv*bhi(u.w);
      }
    }
    #pragma unroll
    for(int e=0;e<8;e++)
      inv[((size_t)b*256+c0+sub*8+e)*PP+px]=f2b(acc[e]);
  }
}

// ---- out = W_p2 * (bn2(inv) + x_Att) + b_p2  (f32 output) ----
__global__ void k_final(const bf16* inv, const bf16* xatt, const float* wf,
                        const float* sc2, const float* sh2, float* out){
  int p=blockIdx.x*256+threadIdx.x; int o0=blockIdx.y*16; int b=blockIdx.z;
  float acc[16];
  #pragma unroll
  for(int o=0;o<16;o++) acc[o]=wf[oBP2+o0+o];
  const bf16* ip = inv + (size_t)b*256*PP + p;
  const bf16* xp = xatt + (size_t)b*256*PP + p;
  for(int ci=0;ci<256;ci++){
    float v = b2f(ip[(size_t)ci*PP])*sc2[ci]+sh2[ci] + b2f(xp[(size_t)ci*PP]);
    const float* w = wf + oWP2 + ci*64 + o0;
    #pragma unroll
    for(int o=0;o<16;o++) acc[o]+=w[o]*v;
  }
  float* op = out + ((size_t)b*64+o0)*PP + p;
  #pragma unroll
  for(int o=0;o<16;o++) op[(size_t)o*PP]=acc[o];
}

extern "C" void kernel_launch(void* const* d_in, const int* in_sizes, int n_in,
                              void* d_out, int out_size, void* d_ws, size_t ws_size,
                              hipStream_t stream){
  const void* xct_r =d_in[0];
  const void* xwsi_r=d_in[1];
  const void* Wct =d_in[2];
  const void* bct =d_in[3];
  const void* Wwsi=d_in[4];
  const void* bwsi=d_in[5];
  const void* Watt=d_in[6];
  const void* Winv=d_in[7];
  const void* binv=d_in[8];
  const void* Wrr =d_in[9];
  const void* g1  =d_in[10];
  const void* be1 =d_in[11];
  const void* g2  =d_in[12];
  const void* be2 =d_in[13];
  const void* Wp1 =d_in[14];
  const void* Wp2 =d_in[16];
  const void* bp2 =d_in[17];
  float* ws=(float*)d_ws;
  float* x1=ws+X1o; float* pool=ws+POOLo; float* xw1=ws+XW1o;
  float* Wx=ws+WXo; float* Wix=ws+WIXo;
  float* att=ws+ATTo; float* kern=ws+KERNo;
  unsigned short* Wf=(unsigned short*)(ws+WXTo);
  unsigned short* Wrr2=(unsigned short*)(ws+WRR2o);
  unsigned short* x1t=(unsigned short*)(ws+X1To);
  bf16* xw3=(bf16*)(ws+XW3o);
  float* stat=ws+STATo; float* wf=ws+WFo;
  float* Wattf=ws+WATTFo; float* Winvf=ws+WINVFo;
  int* flag=(int*)(ws+FLAGo);
  bf16* bfb=(bf16*)(ws+BF16o);
  bf16* xctb=bfb+bXCT; bf16* xwsib=bfb+bXWSI;
  bf16* xatt=bfb+bXATT; bf16* y1=bfb+bY1; bf16* invb=bfb+bINV; bf16* xatt1=bfb+bXATT1;
  unsigned short* xwt=(unsigned short*)(bfb+bXWT);
  float* sum1=stat; float* sq1=stat+256; float* sum2=stat+512; float* sq2=stat+768;
  float* sc1=stat+1024; float* sh1=stat+1280; float* sc2=stat+1536; float* sh2=stat+1792;

  hipMemsetAsync(stat,0,4096,stream);
  k_detect<<<1,64,0,stream>>>((const unsigned short*)xct_r,flag);
  k_c2b   <<<12544,256,0,stream>>>(xct_r,xctb,3211264,flag);
  k_c2b   <<<18816,256,0,stream>>>(xwsi_r,xwsib,4816896,flag);
  k_c2f   <<<3733,256,0,stream>>>(Watt,Wattf,955500,flag);
  k_c2f   <<<113,256,0,stream>>>(Winv,Winvf,28812,flag);
  k_cvt   <<<461,256,0,stream>>>(Wct,bct,Wwsi,bwsi,Wrr,binv,Wp1,Wp2,bp2,wf,flag);
  k_wsit  <<<dim3(49,12,2),256,0,stream>>>(xwsib,xwt);      // xwt aliases y1 (dead until k_p1)
  k_pool  <<<294,256,0,stream>>>(xwsib,pool);
  k_xw1   <<<294,256,0,stream>>>(pool,wf,xw1);
  k_Wx    <<<813,256,0,stream>>>(Wattf,xw1,Wx);
  k_Wfrag <<<1000,256,0,stream>>>(Wx,Wf);
  k_rrfrag<<<108,256,0,stream>>>(wf,Wrr2);                  // overwrites Wx head (dead)
  k_Winvx <<<25,256,0,stream>>>(Winvf,xw1,Wix);
  k_x1    <<<dim3(98,4,2),256,0,stream>>>(xctb,wf,x1,x1t);
  k_att   <<<dim3(49,8,2),256,0,stream>>>(x1t,Wf,att);      // MFMA implicit GEMM
  k_kern  <<<dim3(98,2),256,0,stream>>>(x1,Wix,wf,kern);    // overwrites x1t (dead)
  k_rr    <<<dim3(49,12,2),256,0,stream>>>(xwt,Wrr2,xw3);   // MFMA implicit GEMM
  k_xatt  <<<dim3(98,256,2),256,0,stream>>>(xctb,xw3,att,xatt);
  k_p1    <<<dim3(98,16,2),256,0,stream>>>(xatt,wf,y1);     // overwrites xwt (dead)
  k_stats <<<dim3(8,256,2),256,0,stream>>>(y1,sum1,sq1);
  k_finstat<<<1,256,0,stream>>>(sum1,sq1,g1,be1,flag,sc1,sh1);
  k_bn1   <<<dim3(392,2),256,0,stream>>>(y1,sc1,sh1,xatt1);
  k_inv   <<<dim3(49,4,16),64,0,stream>>>(xatt1,kern,invb);
  k_stats <<<dim3(8,256,2),256,0,stream>>>(invb,sum2,sq2);
  k_finstat<<<1,256,0,stream>>>(sum2,sq2,g2,be2,flag,sc2,sh2);
  k_final <<<dim3(98,4,2),256,0,stream>>>(invb,xatt,wf,sc2,sh2,(float*)d_out);
}

// Round 10
// 469.859 us; speedup vs baseline: 2.1799x; 1.1085x over previous
//
#include <hip/hip_runtime.h>
#include <hip/hip_bf16.h>
#include <math.h>

typedef __hip_bfloat16 bf16;
typedef __attribute__((ext_vector_type(8))) short short8v;
typedef __attribute__((ext_vector_type(4))) float f32x4;
#define DEV static __device__ __forceinline__
DEV float b2f(bf16 x){ return __bfloat162float(x); }
DEV bf16  f2b(float x){ return __float2bfloat16(x); }
DEV unsigned short f2u(float x){ bf16 h=f2b(x); return *(unsigned short*)&h; }
DEV float blo(unsigned int w){ return __uint_as_float(w<<16); }
DEV float bhi(unsigned int w){ return __uint_as_float(w&0xffff0000u); }
DEV float ldin(const void* p, long i, int f){
  return f ? ((const float*)p)[i] : b2f(((const bf16*)p)[i]);
}

// problem dims
#define PP 25088            // t*h*w = 8*56*56

// ws layout (float units)
#define X1o    0L           // 2*64*25088
#define POOLo  3211264L     // 2*588*64   [b][m][c]
#define XW1o   3286528L     // 2*588*64   [b][m][c]
#define WXo    3361792L     // Wx f32 208000; head re-aliased by Wrr2 (13824 f) after k_Wfrag
#define WXTo   3569792L     // Wf MFMA A-frags: 256000 bf16
#define WIXo   3825792L     // 2*64*49    [b][c][kk]
#define ATTo   3832064L     // 2*13*25088 (post-sigmoid, f32)
#define KERNo  4484352L     // 2*49*25088 f32; head aliased by x1t before k_kern runs
#define XW3o   6942976L     // xw3 bf16 [2][16][12][3136] = 1204224 sh
#define STATo  8147200L     // sums(1024) + scale/shift(1024)
#define FLAGo  8149248L     // dtype flag (int), 16 floats reserved
#define WFo    8149264L     // converted f32 weights (118016)
#define WATTFo 8267280L     // W_att as f32 (955500, pad 955504)
#define WINVFo 9222784L     // W_inv as f32 (28812, pad 28816)
#define BF16o  9251600L     // bf16 region starts here (float idx)
#define X1To   KERNo        // x1t bf16 [b][p][64c]: k_x1 writes -> k_att reads -> k_kern overwrites
#define WRR2o  WXo          // Wrr2 A-frags 27648 bf16: written after k_Wfrag consumed Wx
// bf16 sub-offsets (bf16 element units)
#define bXCT   0L           // 3211264
#define bXWSI  3211264L     // 4816896
#define bXATT  8028160L     // 12845056
#define bY1    20873216L    // 12845056
#define bINV   20873216L    // alias: y1 dead after k_bn1
#define bXATT1 33718272L    // 12845056
#define bXWT   bY1          // xwt bf16 [b][d][hw][64]; dead before k_p1 writes y1
// wf sub-offsets
#define oWCT   0            // [ci][co] 64x64
#define oBCT   4096
#define oWWSI  4160         // [co][ci] (untransposed)
#define oBWSI  8256
#define oWRR   8320         // [(ci*27+tap)*16+co]
#define oBINV  35968
#define oWP1   36032        // [ci][co] 256x256
#define oWP2   101568       // [ci][co] 256x64
#define oBP2   117952

// ---- input dtype probe ----
__global__ void k_detect(const unsigned short* raw, int* flag){
  int t = threadIdx.x;
  unsigned short u = raw[2*t];
  int e = (u>>7)&0xFF;
  int hit = (e >= 137);
  unsigned long long m = __ballot(hit);
  if(t==0) flag[0] = (__popcll(m) >= 8) ? 1 : 0;   // 1 = inputs are f32
}

// ---- canonicalize inputs ----
__global__ void k_c2b(const void* src, bf16* dst, int n, const int* flag){
  int i = blockIdx.x*256+threadIdx.x; if(i>=n) return;
  int f = flag[0];
  dst[i] = f ? f2b(((const float*)src)[i]) : ((const bf16*)src)[i];
}
__global__ void k_c2f(const void* src, float* dst, int n, const int* flag){
  int i = blockIdx.x*256+threadIdx.x; if(i>=n) return;
  dst[i] = ldin(src, i, flag[0]);
}

// ---- weight convert (+transpose to put out-channel innermost) ----
__global__ void k_cvt(const void* Wct,const void* bct,const void* Wwsi,const void* bwsi,
                      const void* Wrr,const void* binv,const void* Wp1,const void* Wp2,
                      const void* bp2,float* wf,const int* flag){
  int i = blockIdx.x*256 + threadIdx.x;
  int f = flag[0];
  if (i < 4096){ int co=i>>6, ci=i&63; wf[oWCT + ci*64+co] = ldin(Wct,i,f); }
  else if (i < 4160){ wf[i] = ldin(bct,i-4096,f); }
  else if (i < 8256){ wf[i] = ldin(Wwsi,i-4160,f); }
  else if (i < 8320){ wf[i] = ldin(bwsi,i-8256,f); }
  else if (i < 35968){ int l=i-8320; int co=l/1728, r=l%1728, ci=r/27, tp=r%27;
                       wf[oWRR + (ci*27+tp)*16+co] = ldin(Wrr,l,f); }
  else if (i < 36017){ wf[oBINV + (i-35968)] = ldin(binv,i-35968,f); }
  else if (i < 36032){ }
  else if (i < 101568){ int l=i-36032; int co=l>>8, ci=l&255; wf[oWP1 + ci*256+co] = ldin(Wp1,l,f); }
  else if (i < 117952){ int l=i-101568; int o=l>>8, ci=l&255; wf[oWP2 + ci*64+o] = ldin(Wp2,l,f); }
  else if (i < 118016){ int l=i-117952; if(l<64) wf[oBP2 + l] = ldin(bp2,l,f); }
}

// ---- adaptive pool of raw x_WSI ----
__global__ void k_pool(const bf16* xwsi, float* pool){
  int i = blockIdx.x*256+threadIdx.x;            // 75264 = 2*588*64
  int c = i&63; int m=(i>>6)%588; int b=i/37632;
  int d=m/49, r=m%49, ii=r/7, jj=r%7;
  const bf16* src = xwsi + ((size_t)(b*64+c)*12 + d)*3136 + (ii*8)*56 + jj*8;
  float s=0;
  for(int u=0;u<8;u++) for(int v=0;v<8;v++) s += b2f(src[u*56+v]);
  pool[i] = s*(1.f/64.f);
}

// ---- xwt = channel-last x_WSI [b][d][hw][64] (bn1-style LDS transpose) ----
__global__ void k_wsit(const bf16* xwsib, unsigned short* xwt){
  __shared__ unsigned short tl[64*68];
  int tid=threadIdx.x; int p0=blockIdx.x*64; int d=blockIdx.y; int b=blockIdx.z;
  #pragma unroll
  for(int k=0;k<16;k++){
    int idx=k*256+tid; int px=idx&63, c=idx>>6;
    bf16 h = xwsib[((size_t)(b*64+c)*12+d)*3136 + p0+px];
    tl[px*68+c] = *(unsigned short*)&h;
  }
  __syncthreads();
  #pragma unroll
  for(int k=0;k<16;k++){
    int idx=k*256+tid; int px=idx>>6, ch=idx&63;
    xwt[((size_t)(b*12+d)*3136 + p0+px)*64 + ch] = tl[px*68+ch];
  }
}

// ---- xw1 = W_wsi * pooled + b ----
__global__ void k_xw1(const float* pool, const float* wf, float* xw1){
  int i = blockIdx.x*256+threadIdx.x;
  int c = i&63; int m=(i>>6)%588; int b=i/37632;
  const float* p = pool + (b*588+m)*64;
  const float* w = wf + oWWSI + c*64;
  float s = wf[oBWSI + c];
  for(int ci=0;ci<64;ci++) s += w[ci]*p[ci];
  xw1[i]=s;
}

// ---- Wx[b,o,tap,c] = sum_m W_att[o,m,tap] * xw1[b,c,m] ----
__global__ void k_Wx(const float* Wattf, const float* xw1, float* Wx){
  int i = blockIdx.x*256+threadIdx.x; if(i>=208000) return;
  int c=i&63; int r=i>>6; int tap=r%125; int o=(r/125)%13; int b=r/1625;
  const float* wa = Wattf + (size_t)o*588*125 + tap;
  const float* xp = xw1 + b*588*64 + c;
  float s=0;
  for(int m=0;m<588;m++) s += wa[(size_t)m*125] * xp[m*64];
  Wx[i]=s;
}

// ---- Wf: MFMA A-fragments for k_att ----
__global__ void k_Wfrag(const float* Wx, unsigned short* Wf){
  int i = blockIdx.x*256+threadIdx.x; if(i>=256000) return;
  int j=i&7; int m=(i>>3)&15; int kg=(i>>7)&3; int ch=(i>>9)&1;
  int r=i>>10; int tap=r%125; int b=r/125;
  int c = ch*32 + kg*8 + j;
  float v = (m<13) ? Wx[((size_t)(b*13+m)*125+tap)*64 + c] : 0.f;
  Wf[i] = f2u(v);
}

// ---- Wrr2: MFMA A-fragments for k_rr: [td27][kg2][lane64][8j] ----
__global__ void k_rrfrag(const float* wf, unsigned short* Wrr2){
  int i = blockIdx.x*256+threadIdx.x; if(i>=27648) return;
  int j=i&7; int l=(i>>3)&63; int kg=(i>>9)&1; int td=i>>10;
  int m=l&15, g=l>>4;
  int c = kg*32 + g*8 + j;
  Wrr2[i] = f2u(wf[oWRR + (c*27+td)*16 + m]);
}

// ---- Winvx[b][c][kk] = sum_m W_inv[kk,m] * xw1[b,c,m] ----
__global__ void k_Winvx(const float* Winvf, const float* xw1, float* Wix){
  int i = blockIdx.x*256+threadIdx.x; if(i>=6272) return;
  int kk=i%49; int c=(i/49)&63; int b=i/3136;
  const float* xp = xw1 + b*588*64 + c;
  float s=0;
  for(int m=0;m<588;m++) s += Winvf[kk*588+m] * xp[m*64];
  Wix[i]=s;
}

// ---- x1 = W_ct * x_CT + b ; f32 [b][c][p] AND bf16 channel-last [b][p][c] ----
__global__ void k_x1(const bf16* xct, const float* wf, float* x1, unsigned short* x1t){
  int p = blockIdx.x*256+threadIdx.x;
  int co0 = blockIdx.y*16; int b = blockIdx.z;
  float acc[16];
  #pragma unroll
  for(int o=0;o<16;o++) acc[o]=wf[oBCT+co0+o];
  const bf16* xp = xct + (size_t)b*64*PP + p;
  for(int ci=0;ci<64;ci++){
    float xv = b2f(xp[(size_t)ci*PP]);
    const float* w = wf + oWCT + ci*64 + co0;
    #pragma unroll
    for(int o=0;o<16;o++) acc[o] += w[o]*xv;
  }
  float* out = x1 + ((size_t)b*64+co0)*PP + p;
  #pragma unroll
  for(int o=0;o<16;o++) out[(size_t)o*PP]=acc[o];
  unsigned int pk[8];
  #pragma unroll
  for(int o2=0;o2<8;o2++)
    pk[o2] = (unsigned)f2u(acc[2*o2]) | ((unsigned)f2u(acc[2*o2+1])<<16);
  unsigned short* xo = x1t + ((size_t)(b*PP)+p)*64 + co0;
  *(uint4*)xo     = make_uint4(pk[0],pk[1],pk[2],pk[3]);
  *(uint4*)(xo+8) = make_uint4(pk[4],pk[5],pk[6],pk[7]);
}

// ---- Att = sigmoid(conv5x5x5) via MFMA implicit GEMM ----
__global__ __launch_bounds__(256) void k_att(const unsigned short* x1t, const unsigned short* Wf,
                                             float* att){
  __shared__ short xt[10368];         // 144 px x 72 bf16
  int tid=threadIdx.x;
  int tile=blockIdx.x, t=blockIdx.y, b=blockIdx.z;
  int y0=(tile/7)*8, x0=(tile%7)*8;
  int w=tid>>6, l=tid&63;
  int pc=l&7, pr=(l>>3)&1, g=l>>4;
  f32x4 acc0={0,0,0,0}, acc1={0,0,0,0};
  int bbase = ((2*w+pr)*12 + pc)*72 + g*8;
  const unsigned short* Wb = Wf + (size_t)b*128000 + l*8;
  for(int dt=0;dt<5;dt++){
    int ti=t+dt-2;
    if(ti<0||ti>=8) continue;                    // block-uniform
    __syncthreads();
    for(int e=tid;e<1152;e+=256){
      int px=e>>3, q=e&7;
      int row=px/12, col=px-row*12;
      int gy=y0+row-2, gx=x0+col-2;
      uint4 v={0,0,0,0};
      if((unsigned)gy<56u && (unsigned)gx<56u)
        v = *(const uint4*)(x1t + ((size_t)(b*PP) + ti*3136 + gy*56 + gx)*64 + q*8);
      *(uint4*)&xt[px*72 + q*8] = v;
    }
    __syncthreads();
    const unsigned short* Wd = Wb + dt*25600;
    #pragma unroll
    for(int dy=0;dy<5;dy++){
      #pragma unroll
      for(int dx=0;dx<5;dx++){
        int off = bbase + dy*864 + dx*72;
        short8v a0 = *(const short8v*)(Wd + (dy*5+dx)*1024);
        short8v b0 = *(const short8v*)&xt[off];
        acc0 = __builtin_amdgcn_mfma_f32_16x16x32_bf16(a0,b0,acc0,0,0,0);
        short8v a1 = *(const short8v*)(Wd + (dy*5+dx)*1024 + 512);
        short8v b1 = *(const short8v*)&xt[off+32];
        acc1 = __builtin_amdgcn_mfma_f32_16x16x32_bf16(a1,b1,acc1,0,0,0);
      }
    }
  }
  int px=l&15; int epc=px&7, epr=px>>3;
  size_t pbase=(size_t)t*3136+(size_t)(y0+2*w+epr)*56+x0+epc;
  #pragma unroll
  for(int r=0;r<4;r++){
    int o=g*4+r;
    if(o<13){
      float s=acc0[r]+acc1[r];
      att[((size_t)b*13+o)*PP+pbase]=1.f/(1.f+__expf(-s));
    }
  }
}

// ---- kern49 = Winvx * x1 + b_inv ----
__global__ void k_kern(const float* x1, const float* Wix, const float* wf, float* kern){
  int p = blockIdx.x*256+threadIdx.x; int b=blockIdx.y;
  float acc[49];
  #pragma unroll
  for(int kk=0;kk<49;kk++) acc[kk]=wf[oBINV+kk];
  const float* xp = x1 + (size_t)b*64*PP + p;
  for(int c=0;c<64;c++){
    float xv = xp[(size_t)c*PP];
    const float* w = Wix + (b*64+c)*49;
    #pragma unroll
    for(int kk=0;kk<49;kk++) acc[kk]+=w[kk]*xv;
  }
  float* out = kern + (size_t)b*49*PP + p;
  #pragma unroll
  for(int kk=0;kk<49;kk++) out[(size_t)kk*PP]=acc[kk];
}

// ---- xw3 = conv3x3x3 via MFMA implicit GEMM; writes bf16 [b*16+o][12d][hw] ----
__global__ __launch_bounds__(256) void k_rr(const unsigned short* xwt, const unsigned short* Wrr2,
                                            bf16* xw3){
  __shared__ short xt[7200];          // 100 px x 72 bf16
  int tid=threadIdx.x;
  int tile=blockIdx.x, d=blockIdx.y, b=blockIdx.z;
  int y0=(tile/7)*8, x0=(tile%7)*8;
  int w=tid>>6, l=tid&63;
  int pc=l&7, pr=(l>>3)&1, g=l>>4;
  f32x4 acc0={0,0,0,0}, acc1={0,0,0,0};
  int bbase = ((2*w+pr)*10 + pc)*72 + g*8;
  const unsigned short* Wl = Wrr2 + l*8;
  for(int dz=0;dz<3;dz++){
    int di=d+dz-1;
    if(di<0||di>=12) continue;                   // block-uniform
    __syncthreads();
    for(int e=tid;e<800;e+=256){
      int px=e>>3, q=e&7;
      int row=px/10, col=px-row*10;
      int gy=y0+row-1, gx=x0+col-1;
      uint4 v={0,0,0,0};
      if((unsigned)gy<56u && (unsigned)gx<56u)
        v = *(const uint4*)(xwt + ((size_t)(b*12+di)*3136 + gy*56 + gx)*64 + q*8);
      *(uint4*)&xt[px*72 + q*8] = v;
    }
    __syncthreads();
    const unsigned short* Wd = Wl + dz*9216;
    #pragma unroll
    for(int tap=0;tap<9;tap++){
      int dy=tap/3, dx=tap-dy*3;
      int off = bbase + (dy*10+dx)*72;
      short8v a0 = *(const short8v*)(Wd + tap*1024);
      short8v b0 = *(const short8v*)&xt[off];
      acc0 = __builtin_amdgcn_mfma_f32_16x16x32_bf16(a0,b0,acc0,0,0,0);
      short8v a1 = *(const short8v*)(Wd + tap*1024 + 512);
      short8v b1 = *(const short8v*)&xt[off+32];
      acc1 = __builtin_amdgcn_mfma_f32_16x16x32_bf16(a1,b1,acc1,0,0,0);
    }
  }
  int px=l&15; int epc=px&7, epr=px>>3;
  size_t pp=(size_t)(y0+2*w+epr)*56 + x0+epc;
  #pragma unroll
  for(int r=0;r<4;r++){
    int o=g*4+r;
    xw3[((size_t)(b*16+o)*12+d)*3136 + pp] = f2b(acc0[r]+acc1[r]);
  }
}

// ---- x_Att = x_FS * (1 + Att_FS) ----
__global__ void k_xatt(const bf16* xct, const bf16* xw3, const float* att, bf16* xatt){
  int p=blockIdx.x*256+threadIdx.x; int ch=blockIdx.y; int b=blockIdx.z;
  float v;
  if(ch<64){
    v = b2f(xct[((size_t)b*64+ch)*PP+p]) * (1.f+att[(size_t)b*13*PP+p]);
  } else {
    int q=ch-64; int co=q/12, dd=q-co*12;       // block-uniform
    int s=p%3136;
    v = b2f(xw3[((size_t)(b*16+co)*12+dd)*3136+s]) * (1.f+att[((size_t)b*13+1+q/16)*PP+p]);
  }
  xatt[((size_t)b*256+ch)*PP+p]=f2b(v);
}

// ---- y1 = W_p1 * x_Att ----
__global__ void k_p1(const bf16* xatt, const float* wf, bf16* y1){
  int p=blockIdx.x*256+threadIdx.x;
  int co0=blockIdx.y*16; int b=blockIdx.z;
  float acc[16];
  #pragma unroll
  for(int o=0;o<16;o++) acc[o]=0;
  const bf16* xp = xatt + (size_t)b*256*PP + p;
  for(int ci=0;ci<256;ci++){
    float xv=b2f(xp[(size_t)ci*PP]);
    const float* w = wf + oWP1 + ci*256 + co0;
    #pragma unroll
    for(int o=0;o<16;o++) acc[o]+=w[o]*xv;
  }
  bf16* out = y1 + ((size_t)b*256+co0)*PP + p;
  #pragma unroll
  for(int o=0;o<16;o++) out[(size_t)o*PP]=f2b(acc[o]);
}

// ---- per-channel sum / sumsq ----
__global__ void k_stats(const bf16* src, float* sum, float* sq){
  __shared__ float rs[256], rq[256];
  int tid=threadIdx.x;
  int chunk=blockIdx.x, ch=blockIdx.y, b=blockIdx.z;
  const bf16* p = src + ((size_t)b*256+ch)*PP + chunk*3136;
  float s=0,q=0;
  for(int i=tid;i<3136;i+=256){ float v=b2f(p[i]); s+=v; q+=v*v; }
  rs[tid]=s; rq[tid]=q; __syncthreads();
  for(int st=128;st>0;st>>=1){ if(tid<st){rs[tid]+=rs[tid+st]; rq[tid]+=rq[tid+st];} __syncthreads(); }
  if(tid==0){ atomicAdd(&sum[ch],rs[0]); atomicAdd(&sq[ch],rq[0]); }
}
__global__ void k_finstat(const float* sum, const float* sq, const void* g, const void* be,
                          const int* flag, float* sc, float* sh){
  int ch=threadIdx.x;
  int f=flag[0];
  float m = sum[ch]*(1.f/50176.f);
  float v = sq[ch]*(1.f/50176.f) - m*m;
  float s = ldin(g,ch,f) * rsqrtf(v+1e-5f);
  sc[ch]=s; sh[ch]=ldin(be,ch,f) - m*s;
}

// ---- xatt1 = relu(bn1(y1)), transposed [b][p][ch] ----
__global__ void k_bn1(const bf16* y1, const float* sc, const float* sh, bf16* xatt1){
  __shared__ unsigned short tl[64][258];
  int tid=threadIdx.x; int p0=blockIdx.x*64; int b=blockIdx.y;
  for(int k=0;k<64;k++){
    int idx=k*256+tid; int ch=idx>>6, pp=idx&63;
    float v=b2f(y1[((size_t)b*256+ch)*PP + p0+pp]);
    v = v*sc[ch]+sh[ch]; v = v>0?v:0;
    bf16 h=f2b(v); tl[pp][ch]=*(unsigned short*)&h;
  }
  __syncthreads();
  for(int k=0;k<64;k++){
    unsigned short u=tl[k][tid];
    xatt1[((size_t)b*PP + p0+k)*256 + tid] = *(bf16*)&u;
  }
}

// ---- involution: 256 thr = 4 waves sharing one LDS tile; wave w handles subs 2w,2w+1 ----
__global__ __launch_bounds__(256) void k_inv(const bf16* xatt1, const float* kern, bf16* inv){
  __shared__ __align__(16) unsigned short xt[196*72];
  int tid=threadIdx.x;
  int bx=blockIdx.x, by=blockIdx.y, bz=blockIdx.z;
  int t=bz&7, b=bz>>3;
  int y0=(bx/7)*8, x0=(bx%7)*8, c0=by*64;
  int w=tid>>6, l=tid&63;
  int ty=l>>3, tx=l&7;
  for(int e=tid;e<1568;e+=256){
    int row=e>>3, seg=e&7;
    int yy=row/14, xx=row%14;
    int gy=y0+yy-3, gx=x0+xx-3;
    uint4 v={0,0,0,0};
    if(gy>=0&&gy<56&&gx>=0&&gx<56)
      v = *(const uint4*)&xatt1[((size_t)b*PP + t*3136 + gy*56+gx)*256 + c0 + seg*8];
    *(uint4*)&xt[row*72+seg*8]=v;
  }
  float kr[49];
  size_t px=(size_t)t*3136 + (y0+ty)*56 + x0+tx;
  #pragma unroll
  for(int kk=0;kk<49;kk++) kr[kk]=kern[((size_t)b*49+kk)*PP+px];
  __syncthreads();
  #pragma unroll
  for(int s=0;s<2;s++){
    int sub=2*w+s;
    float acc[8];
    #pragma unroll
    for(int e=0;e<8;e++) acc[e]=0;
    for(int i=0;i<7;i++){
      #pragma unroll
      for(int j=0;j<7;j++){
        uint4 u = *(const uint4*)&xt[((ty+i)*14+tx+j)*72 + sub*8];
        float kv = kr[i*7+j];
        acc[0]+=kv*blo(u.x); acc[1]+=kv*bhi(u.x);
        acc[2]+=kv*blo(u.y); acc[3]+=kv*bhi(u.y);
        acc[4]+=kv*blo(u.z); acc[5]+=kv*bhi(u.z);
        acc[6]+=kv*blo(u.w); acc[7]+=kv*bhi(u.w);
      }
    }
    #pragma unroll
    for(int e=0;e<8;e++)
      inv[((size_t)b*256+c0+sub*8+e)*PP+px]=f2b(acc[e]);
  }
}

// ---- out = W_p2 * (bn2(inv) + x_Att) + b_p2  (f32 output) ----
__global__ void k_final(const bf16* inv, const bf16* xatt, const float* wf,
                        const float* sc2, const float* sh2, float* out){
  int p=blockIdx.x*256+threadIdx.x; int o0=blockIdx.y*16; int b=blockIdx.z;
  float acc[16];
  #pragma unroll
  for(int o=0;o<16;o++) acc[o]=wf[oBP2+o0+o];
  const bf16* ip = inv + (size_t)b*256*PP + p;
  const bf16* xp = xatt + (size_t)b*256*PP + p;
  for(int ci=0;ci<256;ci++){
    float v = b2f(ip[(size_t)ci*PP])*sc2[ci]+sh2[ci] + b2f(xp[(size_t)ci*PP]);
    const float* w = wf + oWP2 + ci*64 + o0;
    #pragma unroll
    for(int o=0;o<16;o++) acc[o]+=w[o]*v;
  }
  float* op = out + ((size_t)b*64+o0)*PP + p;
  #pragma unroll
  for(int o=0;o<16;o++) op[(size_t)o*PP]=acc[o];
}

extern "C" void kernel_launch(void* const* d_in, const int* in_sizes, int n_in,
                              void* d_out, int out_size, void* d_ws, size_t ws_size,
                              hipStream_t stream){
  const void* xct_r =d_in[0];
  const void* xwsi_r=d_in[1];
  const void* Wct =d_in[2];
  const void* bct =d_in[3];
  const void* Wwsi=d_in[4];
  const void* bwsi=d_in[5];
  const void* Watt=d_in[6];
  const void* Winv=d_in[7];
  const void* binv=d_in[8];
  const void* Wrr =d_in[9];
  const void* g1  =d_in[10];
  const void* be1 =d_in[11];
  const void* g2  =d_in[12];
  const void* be2 =d_in[13];
  const void* Wp1 =d_in[14];
  const void* Wp2 =d_in[16];
  const void* bp2 =d_in[17];
  float* ws=(float*)d_ws;
  float* x1=ws+X1o; float* pool=ws+POOLo; float* xw1=ws+XW1o;
  float* Wx=ws+WXo; float* Wix=ws+WIXo;
  float* att=ws+ATTo; float* kern=ws+KERNo;
  unsigned short* Wf=(unsigned short*)(ws+WXTo);
  unsigned short* Wrr2=(unsigned short*)(ws+WRR2o);
  unsigned short* x1t=(unsigned short*)(ws+X1To);
  bf16* xw3=(bf16*)(ws+XW3o);
  float* stat=ws+STATo; float* wf=ws+WFo;
  float* Wattf=ws+WATTFo; float* Winvf=ws+WINVFo;
  int* flag=(int*)(ws+FLAGo);
  bf16* bfb=(bf16*)(ws+BF16o);
  bf16* xctb=bfb+bXCT; bf16* xwsib=bfb+bXWSI;
  bf16* xatt=bfb+bXATT; bf16* y1=bfb+bY1; bf16* invb=bfb+bINV; bf16* xatt1=bfb+bXATT1;
  unsigned short* xwt=(unsigned short*)(bfb+bXWT);
  float* sum1=stat; float* sq1=stat+256; float* sum2=stat+512; float* sq2=stat+768;
  float* sc1=stat+1024; float* sh1=stat+1280; float* sc2=stat+1536; float* sh2=stat+1792;

  hipMemsetAsync(stat,0,4096,stream);
  k_detect<<<1,64,0,stream>>>((const unsigned short*)xct_r,flag);
  k_c2b   <<<12544,256,0,stream>>>(xct_r,xctb,3211264,flag);
  k_c2b   <<<18816,256,0,stream>>>(xwsi_r,xwsib,4816896,flag);
  k_c2f   <<<3733,256,0,stream>>>(Watt,Wattf,955500,flag);
  k_c2f   <<<113,256,0,stream>>>(Winv,Winvf,28812,flag);
  k_cvt   <<<461,256,0,stream>>>(Wct,bct,Wwsi,bwsi,Wrr,binv,Wp1,Wp2,bp2,wf,flag);
  k_wsit  <<<dim3(49,12,2),256,0,stream>>>(xwsib,xwt);      // xwt aliases y1 (dead until k_p1)
  k_pool  <<<294,256,0,stream>>>(xwsib,pool);
  k_xw1   <<<294,256,0,stream>>>(pool,wf,xw1);
  k_Wx    <<<813,256,0,stream>>>(Wattf,xw1,Wx);
  k_Wfrag <<<1000,256,0,stream>>>(Wx,Wf);
  k_rrfrag<<<108,256,0,stream>>>(wf,Wrr2);                  // overwrites Wx head (dead)
  k_Winvx <<<25,256,0,stream>>>(Winvf,xw1,Wix);
  k_x1    <<<dim3(98,4,2),256,0,stream>>>(xctb,wf,x1,x1t);
  k_att   <<<dim3(49,8,2),256,0,stream>>>(x1t,Wf,att);      // MFMA implicit GEMM
  k_kern  <<<dim3(98,2),256,0,stream>>>(x1,Wix,wf,kern);    // overwrites x1t (dead)
  k_rr    <<<dim3(49,12,2),256,0,stream>>>(xwt,Wrr2,xw3);   // MFMA implicit GEMM
  k_xatt  <<<dim3(98,256,2),256,0,stream>>>(xctb,xw3,att,xatt);
  k_p1    <<<dim3(98,16,2),256,0,stream>>>(xatt,wf,y1);     // overwrites xwt (dead)
  k_stats <<<dim3(8,256,2),256,0,stream>>>(y1,sum1,sq1);
  k_finstat<<<1,256,0,stream>>>(sum1,sq1,g1,be1,flag,sc1,sh1);
  k_bn1   <<<dim3(392,2),256,0,stream>>>(y1,sc1,sh1,xatt1);
  k_inv   <<<dim3(49,4,16),256,0,stream>>>(xatt1,kern,invb);// 4 waves/block share tile
  k_stats <<<dim3(8,256,2),256,0,stream>>>(invb,sum2,sq2);
  k_finstat<<<1,256,0,stream>>>(sum2,sq2,g2,be2,flag,sc2,sh2);
  k_final <<<dim3(98,4,2),256,0,stream>>>(invb,xatt,wf,sc2,sh2,(float*)d_out);
}

// Round 11
// 451.011 us; speedup vs baseline: 2.2710x; 1.0418x over previous
//
#include <hip/hip_runtime.h>
#include <hip/hip_bf16.h>
#include <math.h>

typedef __hip_bfloat16 bf16;
typedef unsigned short us;
typedef __attribute__((ext_vector_type(8))) short short8v;
typedef __attribute__((ext_vector_type(4))) float f32x4;
#define DEV static __device__ __forceinline__
DEV float b2f(bf16 x){ return __bfloat162float(x); }
DEV bf16  f2b(float x){ return __float2bfloat16(x); }
DEV us    f2u(float x){ bf16 h=f2b(x); return *(us*)&h; }
DEV float u2f(us u){ return __uint_as_float(((unsigned)u)<<16); }
DEV float blo(unsigned int w){ return __uint_as_float(w<<16); }
DEV float bhi(unsigned int w){ return __uint_as_float(w&0xffff0000u); }
DEV float ldin(const void* p, long i, int f){
  return f ? ((const float*)p)[i] : b2f(((const bf16*)p)[i]);
}

// problem dims
#define PP 25088            // t*h*w = 8*56*56

// ws layout (float units)
#define X1o    0L           // 2*64*25088
#define POOLo  3211264L
#define XW1o   3286528L
#define WXo    3361792L     // Wx f32 208000; re-aliased by Wrr2 after k_Wfrag
#define WXTo   3569792L     // Wf MFMA A-frags: 256000 bf16
#define WIXo   3825792L
#define ATTo   3832064L     // 2*13*25088 f32
#define KERNo  4484352L     // 2*49*25088 f32; head aliased by x1t before k_kern
#define XW3o   6942976L     // xw3 bf16
#define STATo  8147200L
#define FLAGo  8149248L
#define WFo    8149264L
#define WATTFo 8267280L     // W_att f32; dead after k_Wx -> bias2 (64 f) aliases head
#define WINVFo 9222784L
#define BF16o  9251600L
#define X1To   KERNo
#define WRR2o  WXo
// bf16 sub-offsets (bf16 element units)
#define bXCT   0L           // 3211264
#define bXWSI  3211264L     // 4816896
#define bXATT  8028160L     // xattT [b][p][256] 12845056
#define bY1    20873216L    // y1T [b][p][256] 12845056
#define bINV   20873216L    // invT alias (y1T dead after k_bn1)
#define bXATT1 33718272L    // xatt1 [b][p][256] 12845056
#define bWP1B  46563328L    // Wp1b bf16 raw [co][ci] 65536
#define bWP2B  46628864L    // Wp2b bf16 raw [o][ci] 16384
#define bW2S   46645248L    // W2sb bf16 [o][ci] 16384
#define bXWT   bY1          // xwt; dead before k_p1 writes y1T
// wf sub-offsets
#define oWCT   0
#define oBCT   4096
#define oWWSI  4160
#define oBWSI  8256
#define oWRR   8320
#define oBINV  35968
#define oWP1   36032
#define oWP2   101568       // [ci][co] 256x64
#define oBP2   117952

// ---- input dtype probe ----
__global__ void k_detect(const us* raw, int* flag){
  int t = threadIdx.x;
  us u = raw[2*t];
  int e = (u>>7)&0xFF;
  int hit = (e >= 137);
  unsigned long long m = __ballot(hit);
  if(t==0) flag[0] = (__popcll(m) >= 8) ? 1 : 0;
}

// ---- canonicalize inputs ----
__global__ void k_c2b(const void* src, bf16* dst, int n, const int* flag){
  int i = blockIdx.x*256+threadIdx.x; if(i>=n) return;
  int f = flag[0];
  dst[i] = f ? f2b(((const float*)src)[i]) : ((const bf16*)src)[i];
}
__global__ void k_c2f(const void* src, float* dst, int n, const int* flag){
  int i = blockIdx.x*256+threadIdx.x; if(i>=n) return;
  dst[i] = ldin(src, i, flag[0]);
}

// ---- weight convert ----
__global__ void k_cvt(const void* Wct,const void* bct,const void* Wwsi,const void* bwsi,
                      const void* Wrr,const void* binv,const void* Wp1,const void* Wp2,
                      const void* bp2,float* wf,const int* flag){
  int i = blockIdx.x*256 + threadIdx.x;
  int f = flag[0];
  if (i < 4096){ int co=i>>6, ci=i&63; wf[oWCT + ci*64+co] = ldin(Wct,i,f); }
  else if (i < 4160){ wf[i] = ldin(bct,i-4096,f); }
  else if (i < 8256){ wf[i] = ldin(Wwsi,i-4160,f); }
  else if (i < 8320){ wf[i] = ldin(bwsi,i-8256,f); }
  else if (i < 35968){ int l=i-8320; int co=l/1728, r=l%1728, ci=r/27, tp=r%27;
                       wf[oWRR + (ci*27+tp)*16+co] = ldin(Wrr,l,f); }
  else if (i < 36017){ wf[oBINV + (i-35968)] = ldin(binv,i-35968,f); }
  else if (i < 36032){ }
  else if (i < 101568){ int l=i-36032; int co=l>>8, ci=l&255; wf[oWP1 + ci*256+co] = ldin(Wp1,l,f); }
  else if (i < 117952){ int l=i-101568; int o=l>>8, ci=l&255; wf[oWP2 + ci*64+o] = ldin(Wp2,l,f); }
  else if (i < 118016){ int l=i-117952; if(l<64) wf[oBP2 + l] = ldin(bp2,l,f); }
}

// ---- raw-order bf16 weight copies for GEMM B operands ----
__global__ void k_wb(const void* Wp1, const void* Wp2, us* Wp1b, us* Wp2b, const int* flag){
  int i = blockIdx.x*256+threadIdx.x;
  int f = flag[0];
  if(i<65536) Wp1b[i]=f2u(ldin(Wp1,i,f));
  else if(i<81920) Wp2b[i-65536]=f2u(ldin(Wp2,i-65536,f));
}

// ---- adaptive pool of raw x_WSI ----
__global__ void k_pool(const bf16* xwsi, float* pool){
  int i = blockIdx.x*256+threadIdx.x;
  int c = i&63; int m=(i>>6)%588; int b=i/37632;
  int d=m/49, r=m%49, ii=r/7, jj=r%7;
  const bf16* src = xwsi + ((size_t)(b*64+c)*12 + d)*3136 + (ii*8)*56 + jj*8;
  float s=0;
  for(int u=0;u<8;u++) for(int v=0;v<8;v++) s += b2f(src[u*56+v]);
  pool[i] = s*(1.f/64.f);
}

// ---- xwt = channel-last x_WSI [b][d][hw][64] ----
__global__ void k_wsit(const bf16* xwsib, us* xwt){
  __shared__ us tl[64*68];
  int tid=threadIdx.x; int p0=blockIdx.x*64; int d=blockIdx.y; int b=blockIdx.z;
  #pragma unroll
  for(int k=0;k<16;k++){
    int idx=k*256+tid; int px=idx&63, c=idx>>6;
    bf16 h = xwsib[((size_t)(b*64+c)*12+d)*3136 + p0+px];
    tl[px*68+c] = *(us*)&h;
  }
  __syncthreads();
  #pragma unroll
  for(int k=0;k<16;k++){
    int idx=k*256+tid; int px=idx>>6, ch=idx&63;
    xwt[((size_t)(b*12+d)*3136 + p0+px)*64 + ch] = tl[px*68+ch];
  }
}

// ---- xw1 = W_wsi * pooled + b ----
__global__ void k_xw1(const float* pool, const float* wf, float* xw1){
  int i = blockIdx.x*256+threadIdx.x;
  int c = i&63; int m=(i>>6)%588; int b=i/37632;
  const float* p = pool + (b*588+m)*64;
  const float* w = wf + oWWSI + c*64;
  float s = wf[oBWSI + c];
  for(int ci=0;ci<64;ci++) s += w[ci]*p[ci];
  xw1[i]=s;
}

// ---- Wx[b,o,tap,c] = sum_m W_att[o,m,tap] * xw1[b,c,m] ----
__global__ void k_Wx(const float* Wattf, const float* xw1, float* Wx){
  int i = blockIdx.x*256+threadIdx.x; if(i>=208000) return;
  int c=i&63; int r=i>>6; int tap=r%125; int o=(r/125)%13; int b=r/1625;
  const float* wa = Wattf + (size_t)o*588*125 + tap;
  const float* xp = xw1 + b*588*64 + c;
  float s=0;
  for(int m=0;m<588;m++) s += wa[(size_t)m*125] * xp[m*64];
  Wx[i]=s;
}

// ---- Wf: MFMA A-fragments for k_att ----
__global__ void k_Wfrag(const float* Wx, us* Wf){
  int i = blockIdx.x*256+threadIdx.x; if(i>=256000) return;
  int j=i&7; int m=(i>>3)&15; int kg=(i>>7)&3; int ch=(i>>9)&1;
  int r=i>>10; int tap=r%125; int b=r/125;
  int c = ch*32 + kg*8 + j;
  float v = (m<13) ? Wx[((size_t)(b*13+m)*125+tap)*64 + c] : 0.f;
  Wf[i] = f2u(v);
}

// ---- Wrr2: MFMA A-fragments for k_rr ----
__global__ void k_rrfrag(const float* wf, us* Wrr2){
  int i = blockIdx.x*256+threadIdx.x; if(i>=27648) return;
  int j=i&7; int l=(i>>3)&63; int kg=(i>>9)&1; int td=i>>10;
  int m=l&15, g=l>>4;
  int c = kg*32 + g*8 + j;
  Wrr2[i] = f2u(wf[oWRR + (c*27+td)*16 + m]);
}

// ---- Winvx ----
__global__ void k_Winvx(const float* Winvf, const float* xw1, float* Wix){
  int i = blockIdx.x*256+threadIdx.x; if(i>=6272) return;
  int kk=i%49; int c=(i/49)&63; int b=i/3136;
  const float* xp = xw1 + b*588*64 + c;
  float s=0;
  for(int m=0;m<588;m++) s += Winvf[kk*588+m] * xp[m*64];
  Wix[i]=s;
}

// ---- x1 = W_ct * x_CT + b ; f32 [b][c][p] AND bf16 channel-last [b][p][c] ----
__global__ void k_x1(const bf16* xct, const float* wf, float* x1, us* x1t){
  int p = blockIdx.x*256+threadIdx.x;
  int co0 = blockIdx.y*16; int b = blockIdx.z;
  float acc[16];
  #pragma unroll
  for(int o=0;o<16;o++) acc[o]=wf[oBCT+co0+o];
  const bf16* xp = xct + (size_t)b*64*PP + p;
  for(int ci=0;ci<64;ci++){
    float xv = b2f(xp[(size_t)ci*PP]);
    const float* w = wf + oWCT + ci*64 + co0;
    #pragma unroll
    for(int o=0;o<16;o++) acc[o] += w[o]*xv;
  }
  float* out = x1 + ((size_t)b*64+co0)*PP + p;
  #pragma unroll
  for(int o=0;o<16;o++) out[(size_t)o*PP]=acc[o];
  unsigned int pk[8];
  #pragma unroll
  for(int o2=0;o2<8;o2++)
    pk[o2] = (unsigned)f2u(acc[2*o2]) | ((unsigned)f2u(acc[2*o2+1])<<16);
  us* xo = x1t + ((size_t)(b*PP)+p)*64 + co0;
  *(uint4*)xo     = make_uint4(pk[0],pk[1],pk[2],pk[3]);
  *(uint4*)(xo+8) = make_uint4(pk[4],pk[5],pk[6],pk[7]);
}

// ---- Att = sigmoid(conv5x5x5) via MFMA implicit GEMM ----
__global__ __launch_bounds__(256) void k_att(const us* x1t, const us* Wf, float* att){
  __shared__ short xt[10368];
  int tid=threadIdx.x;
  int tile=blockIdx.x, t=blockIdx.y, b=blockIdx.z;
  int y0=(tile/7)*8, x0=(tile%7)*8;
  int w=tid>>6, l=tid&63;
  int pc=l&7, pr=(l>>3)&1, g=l>>4;
  f32x4 acc0={0,0,0,0}, acc1={0,0,0,0};
  int bbase = ((2*w+pr)*12 + pc)*72 + g*8;
  const us* Wb = Wf + (size_t)b*128000 + l*8;
  for(int dt=0;dt<5;dt++){
    int ti=t+dt-2;
    if(ti<0||ti>=8) continue;
    __syncthreads();
    for(int e=tid;e<1152;e+=256){
      int px=e>>3, q=e&7;
      int row=px/12, col=px-row*12;
      int gy=y0+row-2, gx=x0+col-2;
      uint4 v={0,0,0,0};
      if((unsigned)gy<56u && (unsigned)gx<56u)
        v = *(const uint4*)(x1t + ((size_t)(b*PP) + ti*3136 + gy*56 + gx)*64 + q*8);
      *(uint4*)&xt[px*72 + q*8] = v;
    }
    __syncthreads();
    const us* Wd = Wb + dt*25600;
    #pragma unroll
    for(int dy=0;dy<5;dy++){
      #pragma unroll
      for(int dx=0;dx<5;dx++){
        int off = bbase + dy*864 + dx*72;
        short8v a0 = *(const short8v*)(Wd + (dy*5+dx)*1024);
        short8v b0 = *(const short8v*)&xt[off];
        acc0 = __builtin_amdgcn_mfma_f32_16x16x32_bf16(a0,b0,acc0,0,0,0);
        short8v a1 = *(const short8v*)(Wd + (dy*5+dx)*1024 + 512);
        short8v b1 = *(const short8v*)&xt[off+32];
        acc1 = __builtin_amdgcn_mfma_f32_16x16x32_bf16(a1,b1,acc1,0,0,0);
      }
    }
  }
  int px=l&15; int epc=px&7, epr=px>>3;
  size_t pbase=(size_t)t*3136+(size_t)(y0+2*w+epr)*56+x0+epc;
  #pragma unroll
  for(int r=0;r<4;r++){
    int o=g*4+r;
    if(o<13){
      float s=acc0[r]+acc1[r];
      att[((size_t)b*13+o)*PP+pbase]=1.f/(1.f+__expf(-s));
    }
  }
}

// ---- kern49 = Winvx * x1 + b_inv ----
__global__ void k_kern(const float* x1, const float* Wix, const float* wf, float* kern){
  int p = blockIdx.x*256+threadIdx.x; int b=blockIdx.y;
  float acc[49];
  #pragma unroll
  for(int kk=0;kk<49;kk++) acc[kk]=wf[oBINV+kk];
  const float* xp = x1 + (size_t)b*64*PP + p;
  for(int c=0;c<64;c++){
    float xv = xp[(size_t)c*PP];
    const float* w = Wix + (b*64+c)*49;
    #pragma unroll
    for(int kk=0;kk<49;kk++) acc[kk]+=w[kk]*xv;
  }
  float* out = kern + (size_t)b*49*PP + p;
  #pragma unroll
  for(int kk=0;kk<49;kk++) out[(size_t)kk*PP]=acc[kk];
}

// ---- xw3 = conv3x3x3 via MFMA implicit GEMM ----
__global__ __launch_bounds__(256) void k_rr(const us* xwt, const us* Wrr2, bf16* xw3){
  __shared__ short xt[7200];
  int tid=threadIdx.x;
  int tile=blockIdx.x, d=blockIdx.y, b=blockIdx.z;
  int y0=(tile/7)*8, x0=(tile%7)*8;
  int w=tid>>6, l=tid&63;
  int pc=l&7, pr=(l>>3)&1, g=l>>4;
  f32x4 acc0={0,0,0,0}, acc1={0,0,0,0};
  int bbase = ((2*w+pr)*10 + pc)*72 + g*8;
  const us* Wl = Wrr2 + l*8;
  for(int dz=0;dz<3;dz++){
    int di=d+dz-1;
    if(di<0||di>=12) continue;
    __syncthreads();
    for(int e=tid;e<800;e+=256){
      int px=e>>3, q=e&7;
      int row=px/10, col=px-row*10;
      int gy=y0+row-1, gx=x0+col-1;
      uint4 v={0,0,0,0};
      if((unsigned)gy<56u && (unsigned)gx<56u)
        v = *(const uint4*)(xwt + ((size_t)(b*12+di)*3136 + gy*56 + gx)*64 + q*8);
      *(uint4*)&xt[px*72 + q*8] = v;
    }
    __syncthreads();
    const us* Wd = Wl + dz*9216;
    #pragma unroll
    for(int tap=0;tap<9;tap++){
      int dy=tap/3, dx=tap-dy*3;
      int off = bbase + (dy*10+dx)*72;
      short8v a0 = *(const short8v*)(Wd + tap*1024);
      short8v b0 = *(const short8v*)&xt[off];
      acc0 = __builtin_amdgcn_mfma_f32_16x16x32_bf16(a0,b0,acc0,0,0,0);
      short8v a1 = *(const short8v*)(Wd + tap*1024 + 512);
      short8v b1 = *(const short8v*)&xt[off+32];
      acc1 = __builtin_amdgcn_mfma_f32_16x16x32_bf16(a1,b1,acc1,0,0,0);
    }
  }
  int px=l&15; int epc=px&7, epr=px>>3;
  size_t pp=(size_t)(y0+2*w+epr)*56 + x0+epc;
  #pragma unroll
  for(int r=0;r<4;r++){
    int o=g*4+r;
    xw3[((size_t)(b*16+o)*12+d)*3136 + pp] = f2b(acc0[r]+acc1[r]);
  }
}

// ---- xattT = channel-last x_Att [b][p][256] via LDS transpose ----
__global__ void k_xatt(const bf16* xct, const bf16* xw3, const float* att, us* xattT){
  __shared__ us tl[64*258];
  int tid=threadIdx.x; int p0=blockIdx.x*64; int b=blockIdx.y;
  for(int k=0;k<64;k++){
    int idx=k*256+tid; int ch=idx>>6, pp=idx&63;   // ch uniform per (k,wave)
    int p=p0+pp;
    float v;
    if(ch<64){
      v = b2f(xct[((size_t)b*64+ch)*PP+p]) * (1.f+att[(size_t)b*13*PP+p]);
    } else {
      int q=ch-64; int co=q/12, dd=q-co*12;
      int s=p%3136;
      v = b2f(xw3[((size_t)(b*16+co)*12+dd)*3136+s]) * (1.f+att[((size_t)b*13+1+q/16)*PP+p]);
    }
    tl[pp*258+ch]=f2u(v);
  }
  __syncthreads();
  for(int k=0;k<64;k++)
    xattT[((size_t)b*PP + p0+k)*256 + tid] = tl[k*258+tid];
}

// ---- y1T = x_Att @ W_p1^T (MFMA GEMM, K=256; bias cancels in bn1) ----
__global__ __launch_bounds__(256) void k_p1(const us* xattT, const us* Wp1b, us* y1T){
  int tid=threadIdx.x; int w=tid>>6, l=tid&63;
  int pt=blockIdx.x, b=blockIdx.y;
  int p0 = pt*64 + w*16;
  const us* xa = xattT + ((size_t)b*PP + p0 + (l&15))*256 + ((l>>4)*8);
  const us* wb = Wp1b + (l&15)*256 + ((l>>4)*8);
  f32x4 acc[16];
  #pragma unroll
  for(int n=0;n<16;n++) acc[n]=(f32x4){0,0,0,0};
  for(int kc=0;kc<8;kc++){
    short8v a = *(const short8v*)(xa + kc*32);
    #pragma unroll
    for(int n=0;n<16;n++){
      short8v bf = *(const short8v*)(wb + n*4096 + kc*32);
      acc[n] = __builtin_amdgcn_mfma_f32_16x16x32_bf16(a,bf,acc[n],0,0,0);
    }
  }
  int col=l&15, rowb=(l>>4)*4;
  us* yo = y1T + ((size_t)b*PP + p0)*256;
  #pragma unroll
  for(int n=0;n<16;n++)
    #pragma unroll
    for(int r=0;r<4;r++)
      yo[(size_t)(rowb+r)*256 + n*16 + col] = f2u(acc[n][r]);
}

// ---- per-channel sum/sumsq over channel-last [b][p][256] ----
__global__ void k_stats(const us* src, float* sum, float* sq){
  int tid=threadIdx.x; int pt=blockIdx.x, b=blockIdx.y;
  const us* p = src + ((size_t)b*PP + pt*64)*256 + tid;
  float s=0,q=0;
  #pragma unroll 8
  for(int i=0;i<64;i++){ float v=u2f(p[(size_t)i*256]); s+=v; q+=v*v; }
  atomicAdd(&sum[tid],s); atomicAdd(&sq[tid],q);
}
__global__ void k_finstat(const float* sum, const float* sq, const void* g, const void* be,
                          const int* flag, float* sc, float* sh){
  int ch=threadIdx.x;
  int f=flag[0];
  float m = sum[ch]*(1.f/50176.f);
  float v = sq[ch]*(1.f/50176.f) - m*m;
  float s = ldin(g,ch,f) * rsqrtf(v+1e-5f);
  sc[ch]=s; sh[ch]=ldin(be,ch,f) - m*s;
}

// ---- xatt1 = relu(bn1(y1T)) elementwise (channel-last in, channel-last out) ----
__global__ void k_bn1(const us* y1T, const float* sc, const float* sh, us* xatt1){
  size_t i = ((size_t)blockIdx.x*256+threadIdx.x)*8;
  int ch0 = (int)(i & 255);
  uint4 v = *(const uint4*)(y1T+i);
  const us* up=(const us*)&v;
  us r[8];
  #pragma unroll
  for(int j=0;j<8;j++){
    float x = u2f(up[j]);
    x = x*sc[ch0+j]+sh[ch0+j]; x = x>0.f?x:0.f;
    r[j]=f2u(x);
  }
  *(uint4*)(xatt1+i) = *(const uint4*)r;
}

// ---- involution: 4 waves share tile; writes channel-last invT ----
__global__ __launch_bounds__(256) void k_inv(const bf16* xatt1, const float* kern, us* invT){
  __shared__ __align__(16) us xt[196*72];
  int tid=threadIdx.x;
  int bx=blockIdx.x, by=blockIdx.y, bz=blockIdx.z;
  int t=bz&7, b=bz>>3;
  int y0=(bx/7)*8, x0=(bx%7)*8, c0=by*64;
  int w=tid>>6, l=tid&63;
  int ty=l>>3, tx=l&7;
  for(int e=tid;e<1568;e+=256){
    int row=e>>3, seg=e&7;
    int yy=row/14, xx=row%14;
    int gy=y0+yy-3, gx=x0+xx-3;
    uint4 v={0,0,0,0};
    if(gy>=0&&gy<56&&gx>=0&&gx<56)
      v = *(const uint4*)&xatt1[((size_t)b*PP + t*3136 + gy*56+gx)*256 + c0 + seg*8];
    *(uint4*)&xt[row*72+seg*8]=v;
  }
  float kr[49];
  size_t pxs=(size_t)t*3136 + (y0+ty)*56 + x0+tx;
  #pragma unroll
  for(int kk=0;kk<49;kk++) kr[kk]=kern[((size_t)b*49+kk)*PP+pxs];
  __syncthreads();
  #pragma unroll
  for(int s=0;s<2;s++){
    int sub=2*w+s;
    float acc[8];
    #pragma unroll
    for(int e=0;e<8;e++) acc[e]=0;
    for(int i=0;i<7;i++){
      #pragma unroll
      for(int j=0;j<7;j++){
        uint4 u = *(const uint4*)&xt[((ty+i)*14+tx+j)*72 + sub*8];
        float kv = kr[i*7+j];
        acc[0]+=kv*blo(u.x); acc[1]+=kv*bhi(u.x);
        acc[2]+=kv*blo(u.y); acc[3]+=kv*bhi(u.y);
        acc[4]+=kv*blo(u.z); acc[5]+=kv*bhi(u.z);
        acc[6]+=kv*blo(u.w); acc[7]+=kv*bhi(u.w);
      }
    }
    unsigned pk[4];
    #pragma unroll
    for(int e=0;e<4;e++)
      pk[e] = (unsigned)f2u(acc[2*e]) | ((unsigned)f2u(acc[2*e+1])<<16);
    *(uint4*)&invT[((size_t)b*PP+pxs)*256 + c0 + sub*8] = make_uint4(pk[0],pk[1],pk[2],pk[3]);
  }
}

// ---- W2s = W_p2*diag(sc2) bf16; bias2[o] = b_p2[o] + sum_ci W_p2[o][ci]*sh2[ci] ----
__global__ void k_w2s(const float* wf, const float* sc2, const float* sh2,
                      us* W2sb, float* bias2){
  __shared__ float red[256];
  int o=blockIdx.x, ci=threadIdx.x;
  float wv = wf[oWP2 + ci*64 + o];
  W2sb[o*256+ci] = f2u(wv * sc2[ci]);
  red[ci] = wv * sh2[ci];
  __syncthreads();
  for(int st=128;st>0;st>>=1){ if(ci<st) red[ci]+=red[ci+st]; __syncthreads(); }
  if(ci==0) bias2[o] = wf[oBP2+o] + red[0];
}

// ---- out = W2s@invT + W_p2@xattT + bias2 (MFMA GEMM, f32 out) ----
__global__ __launch_bounds__(256) void k_final(const us* invT, const us* xattT,
                                               const us* W2sb, const us* Wp2b,
                                               const float* bias2, float* out){
  int tid=threadIdx.x; int w=tid>>6, l=tid&63;
  int pt=blockIdx.x, b=blockIdx.y;
  int p0 = pt*64 + w*16;
  size_t abase = ((size_t)b*PP + p0 + (l&15))*256 + ((l>>4)*8);
  int wbase = (l&15)*256 + ((l>>4)*8);
  f32x4 acc[4];
  #pragma unroll
  for(int n=0;n<4;n++) acc[n]=(f32x4){0,0,0,0};
  for(int kc=0;kc<8;kc++){
    short8v ai = *(const short8v*)(invT + abase + kc*32);
    short8v ax = *(const short8v*)(xattT + abase + kc*32);
    #pragma unroll
    for(int n=0;n<4;n++){
      short8v b1 = *(const short8v*)(W2sb + n*4096 + wbase + kc*32);
      acc[n] = __builtin_amdgcn_mfma_f32_16x16x32_bf16(ai,b1,acc[n],0,0,0);
      short8v b2 = *(const short8v*)(Wp2b + n*4096 + wbase + kc*32);
      acc[n] = __builtin_amdgcn_mfma_f32_16x16x32_bf16(ax,b2,acc[n],0,0,0);
    }
  }
  int col=l&15, rowb=(l>>4)*4;
  #pragma unroll
  for(int n=0;n<4;n++){
    float bb = bias2[n*16+col];
    #pragma unroll
    for(int r=0;r<4;r++)
      out[((size_t)b*64 + n*16+col)*PP + p0 + rowb + r] = acc[n][r] + bb;
  }
}

extern "C" void kernel_launch(void* const* d_in, const int* in_sizes, int n_in,
                              void* d_out, int out_size, void* d_ws, size_t ws_size,
                              hipStream_t stream){
  const void* xct_r =d_in[0];
  const void* xwsi_r=d_in[1];
  const void* Wct =d_in[2];
  const void* bct =d_in[3];
  const void* Wwsi=d_in[4];
  const void* bwsi=d_in[5];
  const void* Watt=d_in[6];
  const void* Winv=d_in[7];
  const void* binv=d_in[8];
  const void* Wrr =d_in[9];
  const void* g1  =d_in[10];
  const void* be1 =d_in[11];
  const void* g2  =d_in[12];
  const void* be2 =d_in[13];
  const void* Wp1 =d_in[14];
  const void* Wp2 =d_in[16];
  const void* bp2 =d_in[17];
  float* ws=(float*)d_ws;
  float* x1=ws+X1o; float* pool=ws+POOLo; float* xw1=ws+XW1o;
  float* Wx=ws+WXo; float* Wix=ws+WIXo;
  float* att=ws+ATTo; float* kern=ws+KERNo;
  us* Wf=(us*)(ws+WXTo);
  us* Wrr2=(us*)(ws+WRR2o);
  us* x1t=(us*)(ws+X1To);
  bf16* xw3=(bf16*)(ws+XW3o);
  float* stat=ws+STATo; float* wf=ws+WFo;
  float* Wattf=ws+WATTFo; float* Winvf=ws+WINVFo;
  float* bias2=ws+WATTFo;     // aliases Wattf (dead after k_Wx)
  int* flag=(int*)(ws+FLAGo);
  bf16* bfb=(bf16*)(ws+BF16o);
  bf16* xctb=bfb+bXCT; bf16* xwsib=bfb+bXWSI;
  us* xattT=(us*)(bfb+bXATT); us* y1T=(us*)(bfb+bY1); us* invT=(us*)(bfb+bINV);
  bf16* xatt1=bfb+bXATT1;
  us* Wp1b=(us*)(bfb+bWP1B); us* Wp2b=(us*)(bfb+bWP2B); us* W2sb=(us*)(bfb+bW2S);
  us* xwt=(us*)(bfb+bXWT);
  float* sum1=stat; float* sq1=stat+256; float* sum2=stat+512; float* sq2=stat+768;
  float* sc1=stat+1024; float* sh1=stat+1280; float* sc2=stat+1536; float* sh2=stat+1792;

  hipMemsetAsync(stat,0,4096,stream);
  k_detect<<<1,64,0,stream>>>((const us*)xct_r,flag);
  k_c2b   <<<12544,256,0,stream>>>(xct_r,xctb,3211264,flag);
  k_c2b   <<<18816,256,0,stream>>>(xwsi_r,xwsib,4816896,flag);
  k_c2f   <<<3733,256,0,stream>>>(Watt,Wattf,955500,flag);
  k_c2f   <<<113,256,0,stream>>>(Winv,Winvf,28812,flag);
  k_cvt   <<<461,256,0,stream>>>(Wct,bct,Wwsi,bwsi,Wrr,binv,Wp1,Wp2,bp2,wf,flag);
  k_wb    <<<320,256,0,stream>>>(Wp1,Wp2,Wp1b,Wp2b,flag);
  k_wsit  <<<dim3(49,12,2),256,0,stream>>>(xwsib,xwt);      // xwt aliases y1T (dead until k_p1)
  k_pool  <<<294,256,0,stream>>>(xwsib,pool);
  k_xw1   <<<294,256,0,stream>>>(pool,wf,xw1);
  k_Wx    <<<813,256,0,stream>>>(Wattf,xw1,Wx);
  k_Wfrag <<<1000,256,0,stream>>>(Wx,Wf);
  k_rrfrag<<<108,256,0,stream>>>(wf,Wrr2);                  // overwrites Wx head (dead)
  k_Winvx <<<25,256,0,stream>>>(Winvf,xw1,Wix);
  k_x1    <<<dim3(98,4,2),256,0,stream>>>(xctb,wf,x1,x1t);
  k_att   <<<dim3(49,8,2),256,0,stream>>>(x1t,Wf,att);
  k_kern  <<<dim3(98,2),256,0,stream>>>(x1,Wix,wf,kern);    // overwrites x1t (dead)
  k_rr    <<<dim3(49,12,2),256,0,stream>>>(xwt,Wrr2,xw3);
  k_xatt  <<<dim3(392,2),256,0,stream>>>(xctb,xw3,att,xattT);
  k_p1    <<<dim3(392,2),256,0,stream>>>(xattT,Wp1b,y1T);   // overwrites xwt (dead)
  k_stats <<<dim3(392,2),256,0,stream>>>(y1T,sum1,sq1);
  k_finstat<<<1,256,0,stream>>>(sum1,sq1,g1,be1,flag,sc1,sh1);
  k_bn1   <<<6272,256,0,stream>>>(y1T,sc1,sh1,(us*)xatt1);
  k_inv   <<<dim3(49,4,16),256,0,stream>>>(xatt1,kern,invT);
  k_stats <<<dim3(392,2),256,0,stream>>>(invT,sum2,sq2);
  k_finstat<<<1,256,0,stream>>>(sum2,sq2,g2,be2,flag,sc2,sh2);
  k_w2s   <<<64,256,0,stream>>>(wf,sc2,sh2,W2sb,bias2);
  k_final <<<dim3(392,2),256,0,stream>>>(invT,xattT,W2sb,Wp2b,bias2,(float*)d_out);
}

// Round 12
// 395.419 us; speedup vs baseline: 2.5902x; 1.1406x over previous
//
#include <hip/hip_runtime.h>
#include <hip/hip_bf16.h>
#include <math.h>

typedef __hip_bfloat16 bf16;
typedef unsigned short us;
typedef __attribute__((ext_vector_type(8))) short short8v;
typedef __attribute__((ext_vector_type(4))) float f32x4;
#define DEV static __device__ __forceinline__
DEV float b2f(bf16 x){ return __bfloat162float(x); }
DEV bf16  f2b(float x){ return __float2bfloat16(x); }
DEV us    f2u(float x){ bf16 h=f2b(x); return *(us*)&h; }
DEV float u2f(us u){ return __uint_as_float(((unsigned)u)<<16); }
DEV float blo(unsigned int w){ return __uint_as_float(w<<16); }
DEV float bhi(unsigned int w){ return __uint_as_float(w&0xffff0000u); }
DEV float ldin(const void* p, long i, int f){
  return f ? ((const float*)p)[i] : b2f(((const bf16*)p)[i]);
}

// problem dims
#define PP 25088            // t*h*w = 8*56*56

// ws layout (float units)
#define X1o    0L           // 2*64*25088
#define POOLo  3211264L
#define XW1o   3286528L
#define WXo    3361792L     // Wx f32 208000; re-aliased by Wrr2 after k_Wfrag
#define WXTo   3569792L     // Wf MFMA A-frags: 256000 bf16
#define WIXo   3825792L
#define ATTo   3832064L     // 2*13*25088 f32
#define KERNo  4484352L     // 2*49*25088 f32; head aliased by x1t before k_kern
#define XW3o   6942976L     // xw3 bf16
#define STATo  8147200L
#define FLAGo  8149248L
#define WFo    8149264L
#define WATTFo 8267280L     // W_att f32; dead after k_Wx -> bias2 aliases head
#define WINVFo 9222784L
#define BF16o  9251600L
#define X1To   KERNo
#define WRR2o  WXo
// bf16 sub-offsets (bf16 element units)
#define bXCT   0L           // 3211264
#define bXWSI  3211264L     // 4816896
#define bXATT  8028160L     // xattT [b][p][256] 12845056
#define bY1    20873216L    // y1T [b][p][256] 12845056
#define bINV   20873216L    // invT alias (y1T dead after k_bn1)
#define bXATT1 33718272L    // xatt1 [b][p][256] 12845056
#define bWP1B  46563328L    // Wp1b bf16 raw [co][ci] 65536
#define bWP2B  46628864L    // Wp2b bf16 raw [o][ci] 16384
#define bW2S   46645248L    // W2sb bf16 [o][ci] 16384
#define bXWT   bY1          // xwt; dead before k_p1 writes y1T
// wf sub-offsets
#define oWCT   0
#define oBCT   4096
#define oWWSI  4160
#define oBWSI  8256
#define oWRR   8320
#define oBINV  35968
#define oWP1   36032
#define oWP2   101568       // [ci][co] 256x64
#define oBP2   117952

// ---- input dtype probe ----
__global__ void k_detect(const us* raw, int* flag){
  int t = threadIdx.x;
  us u = raw[2*t];
  int e = (u>>7)&0xFF;
  int hit = (e >= 137);
  unsigned long long m = __ballot(hit);
  if(t==0) flag[0] = (__popcll(m) >= 8) ? 1 : 0;
}

// ---- canonicalize inputs ----
__global__ void k_c2b(const void* src, bf16* dst, int n, const int* flag){
  int i = blockIdx.x*256+threadIdx.x; if(i>=n) return;
  int f = flag[0];
  dst[i] = f ? f2b(((const float*)src)[i]) : ((const bf16*)src)[i];
}
__global__ void k_c2f(const void* src, float* dst, int n, const int* flag){
  int i = blockIdx.x*256+threadIdx.x; if(i>=n) return;
  dst[i] = ldin(src, i, flag[0]);
}

// ---- weight convert ----
__global__ void k_cvt(const void* Wct,const void* bct,const void* Wwsi,const void* bwsi,
                      const void* Wrr,const void* binv,const void* Wp1,const void* Wp2,
                      const void* bp2,float* wf,const int* flag){
  int i = blockIdx.x*256 + threadIdx.x;
  int f = flag[0];
  if (i < 4096){ int co=i>>6, ci=i&63; wf[oWCT + ci*64+co] = ldin(Wct,i,f); }
  else if (i < 4160){ wf[i] = ldin(bct,i-4096,f); }
  else if (i < 8256){ wf[i] = ldin(Wwsi,i-4160,f); }
  else if (i < 8320){ wf[i] = ldin(bwsi,i-8256,f); }
  else if (i < 35968){ int l=i-8320; int co=l/1728, r=l%1728, ci=r/27, tp=r%27;
                       wf[oWRR + (ci*27+tp)*16+co] = ldin(Wrr,l,f); }
  else if (i < 36017){ wf[oBINV + (i-35968)] = ldin(binv,i-35968,f); }
  else if (i < 36032){ }
  else if (i < 101568){ int l=i-36032; int co=l>>8, ci=l&255; wf[oWP1 + ci*256+co] = ldin(Wp1,l,f); }
  else if (i < 117952){ int l=i-101568; int o=l>>8, ci=l&255; wf[oWP2 + ci*64+o] = ldin(Wp2,l,f); }
  else if (i < 118016){ int l=i-117952; if(l<64) wf[oBP2 + l] = ldin(bp2,l,f); }
}

// ---- raw-order bf16 weight copies for GEMM B operands ----
__global__ void k_wb(const void* Wp1, const void* Wp2, us* Wp1b, us* Wp2b, const int* flag){
  int i = blockIdx.x*256+threadIdx.x;
  int f = flag[0];
  if(i<65536) Wp1b[i]=f2u(ldin(Wp1,i,f));
  else if(i<81920) Wp2b[i-65536]=f2u(ldin(Wp2,i-65536,f));
}

// ---- adaptive pool of raw x_WSI ----
__global__ void k_pool(const bf16* xwsi, float* pool){
  int i = blockIdx.x*256+threadIdx.x;
  int c = i&63; int m=(i>>6)%588; int b=i/37632;
  int d=m/49, r=m%49, ii=r/7, jj=r%7;
  const bf16* src = xwsi + ((size_t)(b*64+c)*12 + d)*3136 + (ii*8)*56 + jj*8;
  float s=0;
  for(int u=0;u<8;u++) for(int v=0;v<8;v++) s += b2f(src[u*56+v]);
  pool[i] = s*(1.f/64.f);
}

// ---- xwt = channel-last x_WSI [b][d][hw][64] ----
__global__ void k_wsit(const bf16* xwsib, us* xwt){
  __shared__ us tl[64*68];
  int tid=threadIdx.x; int p0=blockIdx.x*64; int d=blockIdx.y; int b=blockIdx.z;
  #pragma unroll
  for(int k=0;k<16;k++){
    int idx=k*256+tid; int px=idx&63, c=idx>>6;
    bf16 h = xwsib[((size_t)(b*64+c)*12+d)*3136 + p0+px];
    tl[px*68+c] = *(us*)&h;
  }
  __syncthreads();
  #pragma unroll
  for(int k=0;k<16;k++){
    int idx=k*256+tid; int px=idx>>6, ch=idx&63;
    xwt[((size_t)(b*12+d)*3136 + p0+px)*64 + ch] = tl[px*68+ch];
  }
}

// ---- xw1 = W_wsi * pooled + b ----
__global__ void k_xw1(const float* pool, const float* wf, float* xw1){
  int i = blockIdx.x*256+threadIdx.x;
  int c = i&63; int m=(i>>6)%588; int b=i/37632;
  const float* p = pool + (b*588+m)*64;
  const float* w = wf + oWWSI + c*64;
  float s = wf[oBWSI + c];
  for(int ci=0;ci<64;ci++) s += w[ci]*p[ci];
  xw1[i]=s;
}

// ---- Wx[b,o,tap,c] = sum_m W_att[o,m,tap] * xw1[b,c,m] ----
__global__ void k_Wx(const float* Wattf, const float* xw1, float* Wx){
  int i = blockIdx.x*256+threadIdx.x; if(i>=208000) return;
  int c=i&63; int r=i>>6; int tap=r%125; int o=(r/125)%13; int b=r/1625;
  const float* wa = Wattf + (size_t)o*588*125 + tap;
  const float* xp = xw1 + b*588*64 + c;
  float s=0;
  for(int m=0;m<588;m++) s += wa[(size_t)m*125] * xp[m*64];
  Wx[i]=s;
}

// ---- Wf: MFMA A-fragments for k_att ----
__global__ void k_Wfrag(const float* Wx, us* Wf){
  int i = blockIdx.x*256+threadIdx.x; if(i>=256000) return;
  int j=i&7; int m=(i>>3)&15; int kg=(i>>7)&3; int ch=(i>>9)&1;
  int r=i>>10; int tap=r%125; int b=r/125;
  int c = ch*32 + kg*8 + j;
  float v = (m<13) ? Wx[((size_t)(b*13+m)*125+tap)*64 + c] : 0.f;
  Wf[i] = f2u(v);
}

// ---- Wrr2: MFMA A-fragments for k_rr ----
__global__ void k_rrfrag(const float* wf, us* Wrr2){
  int i = blockIdx.x*256+threadIdx.x; if(i>=27648) return;
  int j=i&7; int l=(i>>3)&63; int kg=(i>>9)&1; int td=i>>10;
  int m=l&15, g=l>>4;
  int c = kg*32 + g*8 + j;
  Wrr2[i] = f2u(wf[oWRR + (c*27+td)*16 + m]);
}

// ---- Winvx ----
__global__ void k_Winvx(const float* Winvf, const float* xw1, float* Wix){
  int i = blockIdx.x*256+threadIdx.x; if(i>=6272) return;
  int kk=i%49; int c=(i/49)&63; int b=i/3136;
  const float* xp = xw1 + b*588*64 + c;
  float s=0;
  for(int m=0;m<588;m++) s += Winvf[kk*588+m] * xp[m*64];
  Wix[i]=s;
}

// ---- x1 = W_ct * x_CT + b ; f32 [b][c][p] AND bf16 channel-last [b][p][c] ----
__global__ void k_x1(const bf16* xct, const float* wf, float* x1, us* x1t){
  int p = blockIdx.x*256+threadIdx.x;
  int co0 = blockIdx.y*16; int b = blockIdx.z;
  float acc[16];
  #pragma unroll
  for(int o=0;o<16;o++) acc[o]=wf[oBCT+co0+o];
  const bf16* xp = xct + (size_t)b*64*PP + p;
  for(int ci=0;ci<64;ci++){
    float xv = b2f(xp[(size_t)ci*PP]);
    const float* w = wf + oWCT + ci*64 + co0;
    #pragma unroll
    for(int o=0;o<16;o++) acc[o] += w[o]*xv;
  }
  float* out = x1 + ((size_t)b*64+co0)*PP + p;
  #pragma unroll
  for(int o=0;o<16;o++) out[(size_t)o*PP]=acc[o];
  unsigned int pk[8];
  #pragma unroll
  for(int o2=0;o2<8;o2++)
    pk[o2] = (unsigned)f2u(acc[2*o2]) | ((unsigned)f2u(acc[2*o2+1])<<16);
  us* xo = x1t + ((size_t)(b*PP)+p)*64 + co0;
  *(uint4*)xo     = make_uint4(pk[0],pk[1],pk[2],pk[3]);
  *(uint4*)(xo+8) = make_uint4(pk[4],pk[5],pk[6],pk[7]);
}

// ---- Att = sigmoid(conv5x5x5) via MFMA implicit GEMM ----
__global__ __launch_bounds__(256) void k_att(const us* x1t, const us* Wf, float* att){
  __shared__ short xt[10368];
  int tid=threadIdx.x;
  int tile=blockIdx.x, t=blockIdx.y, b=blockIdx.z;
  int y0=(tile/7)*8, x0=(tile%7)*8;
  int w=tid>>6, l=tid&63;
  int pc=l&7, pr=(l>>3)&1, g=l>>4;
  f32x4 acc0={0,0,0,0}, acc1={0,0,0,0};
  int bbase = ((2*w+pr)*12 + pc)*72 + g*8;
  const us* Wb = Wf + (size_t)b*128000 + l*8;
  for(int dt=0;dt<5;dt++){
    int ti=t+dt-2;
    if(ti<0||ti>=8) continue;
    __syncthreads();
    for(int e=tid;e<1152;e+=256){
      int px=e>>3, q=e&7;
      int row=px/12, col=px-row*12;
      int gy=y0+row-2, gx=x0+col-2;
      uint4 v={0,0,0,0};
      if((unsigned)gy<56u && (unsigned)gx<56u)
        v = *(const uint4*)(x1t + ((size_t)(b*PP) + ti*3136 + gy*56 + gx)*64 + q*8);
      *(uint4*)&xt[px*72 + q*8] = v;
    }
    __syncthreads();
    const us* Wd = Wb + dt*25600;
    #pragma unroll
    for(int dy=0;dy<5;dy++){
      #pragma unroll
      for(int dx=0;dx<5;dx++){
        int off = bbase + dy*864 + dx*72;
        short8v a0 = *(const short8v*)(Wd + (dy*5+dx)*1024);
        short8v b0 = *(const short8v*)&xt[off];
        acc0 = __builtin_amdgcn_mfma_f32_16x16x32_bf16(a0,b0,acc0,0,0,0);
        short8v a1 = *(const short8v*)(Wd + (dy*5+dx)*1024 + 512);
        short8v b1 = *(const short8v*)&xt[off+32];
        acc1 = __builtin_amdgcn_mfma_f32_16x16x32_bf16(a1,b1,acc1,0,0,0);
      }
    }
  }
  int px=l&15; int epc=px&7, epr=px>>3;
  size_t pbase=(size_t)t*3136+(size_t)(y0+2*w+epr)*56+x0+epc;
  #pragma unroll
  for(int r=0;r<4;r++){
    int o=g*4+r;
    if(o<13){
      float s=acc0[r]+acc1[r];
      att[((size_t)b*13+o)*PP+pbase]=1.f/(1.f+__expf(-s));
    }
  }
}

// ---- kern49 = Winvx * x1 + b_inv ----
__global__ void k_kern(const float* x1, const float* Wix, const float* wf, float* kern){
  int p = blockIdx.x*256+threadIdx.x; int b=blockIdx.y;
  float acc[49];
  #pragma unroll
  for(int kk=0;kk<49;kk++) acc[kk]=wf[oBINV+kk];
  const float* xp = x1 + (size_t)b*64*PP + p;
  for(int c=0;c<64;c++){
    float xv = xp[(size_t)c*PP];
    const float* w = Wix + (b*64+c)*49;
    #pragma unroll
    for(int kk=0;kk<49;kk++) acc[kk]+=w[kk]*xv;
  }
  float* out = kern + (size_t)b*49*PP + p;
  #pragma unroll
  for(int kk=0;kk<49;kk++) out[(size_t)kk*PP]=acc[kk];
}

// ---- xw3 = conv3x3x3 via MFMA implicit GEMM ----
__global__ __launch_bounds__(256) void k_rr(const us* xwt, const us* Wrr2, bf16* xw3){
  __shared__ short xt[7200];
  int tid=threadIdx.x;
  int tile=blockIdx.x, d=blockIdx.y, b=blockIdx.z;
  int y0=(tile/7)*8, x0=(tile%7)*8;
  int w=tid>>6, l=tid&63;
  int pc=l&7, pr=(l>>3)&1, g=l>>4;
  f32x4 acc0={0,0,0,0}, acc1={0,0,0,0};
  int bbase = ((2*w+pr)*10 + pc)*72 + g*8;
  const us* Wl = Wrr2 + l*8;
  for(int dz=0;dz<3;dz++){
    int di=d+dz-1;
    if(di<0||di>=12) continue;
    __syncthreads();
    for(int e=tid;e<800;e+=256){
      int px=e>>3, q=e&7;
      int row=px/10, col=px-row*10;
      int gy=y0+row-1, gx=x0+col-1;
      uint4 v={0,0,0,0};
      if((unsigned)gy<56u && (unsigned)gx<56u)
        v = *(const uint4*)(xwt + ((size_t)(b*12+di)*3136 + gy*56 + gx)*64 + q*8);
      *(uint4*)&xt[px*72 + q*8] = v;
    }
    __syncthreads();
    const us* Wd = Wl + dz*9216;
    #pragma unroll
    for(int tap=0;tap<9;tap++){
      int dy=tap/3, dx=tap-dy*3;
      int off = bbase + (dy*10+dx)*72;
      short8v a0 = *(const short8v*)(Wd + tap*1024);
      short8v b0 = *(const short8v*)&xt[off];
      acc0 = __builtin_amdgcn_mfma_f32_16x16x32_bf16(a0,b0,acc0,0,0,0);
      short8v a1 = *(const short8v*)(Wd + tap*1024 + 512);
      short8v b1 = *(const short8v*)&xt[off+32];
      acc1 = __builtin_amdgcn_mfma_f32_16x16x32_bf16(a1,b1,acc1,0,0,0);
    }
  }
  int px=l&15; int epc=px&7, epr=px>>3;
  size_t pp=(size_t)(y0+2*w+epr)*56 + x0+epc;
  #pragma unroll
  for(int r=0;r<4;r++){
    int o=g*4+r;
    xw3[((size_t)(b*16+o)*12+d)*3136 + pp] = f2b(acc0[r]+acc1[r]);
  }
}

// ---- xattT = channel-last x_Att [b][p][256] via LDS transpose ----
__global__ void k_xatt(const bf16* xct, const bf16* xw3, const float* att, us* xattT){
  __shared__ us tl[64*258];
  int tid=threadIdx.x; int p0=blockIdx.x*64; int b=blockIdx.y;
  for(int k=0;k<64;k++){
    int idx=k*256+tid; int ch=idx>>6, pp=idx&63;
    int p=p0+pp;
    float v;
    if(ch<64){
      v = b2f(xct[((size_t)b*64+ch)*PP+p]) * (1.f+att[(size_t)b*13*PP+p]);
    } else {
      int q=ch-64; int co=q/12, dd=q-co*12;
      int s=p%3136;
      v = b2f(xw3[((size_t)(b*16+co)*12+dd)*3136+s]) * (1.f+att[((size_t)b*13+1+q/16)*PP+p]);
    }
    tl[pp*258+ch]=f2u(v);
  }
  __syncthreads();
  for(int k=0;k<64;k++)
    xattT[((size_t)b*PP + p0+k)*256 + tid] = tl[k*258+tid];
}

// ---- y1T = x_Att @ W_p1^T ; LDS-staged weight panel in fragment order ----
// block: 64px x 64co; grid (392, 4 co-quarters, 2 b); LDS 32KB
__global__ __launch_bounds__(256) void k_p1(const us* xattT, const us* Wp1b, us* y1T){
  __shared__ us wt[16384];     // frag[(n*8+kc)*64 + lane][8]
  int tid=threadIdx.x; int w=tid>>6, l=tid&63;
  int pt=blockIdx.x, qtr=blockIdx.y, b=blockIdx.z;
  int co0 = qtr*64;
  #pragma unroll
  for(int it=0;it<8;it++){
    int f = it*256+tid;                 // f < 2048 fragment-groups
    int n=f>>9, kc=(f>>6)&7, lane=f&63;
    int co = co0 + n*16 + (lane&15);
    int ci = (lane>>4)*8 + kc*32;
    uint4 v = *(const uint4*)(Wp1b + (size_t)co*256 + ci);
    *(uint4*)(wt + f*8) = v;            // lane-contiguous: conflict-free
  }
  __syncthreads();
  int p0 = pt*64 + w*16;
  const us* xa = xattT + ((size_t)b*PP + p0 + (l&15))*256 + ((l>>4)*8);
  f32x4 acc[4];
  #pragma unroll
  for(int n=0;n<4;n++) acc[n]=(f32x4){0,0,0,0};
  for(int kc=0;kc<8;kc++){
    short8v a = *(const short8v*)(xa + kc*32);
    #pragma unroll
    for(int n=0;n<4;n++){
      short8v bf = *(const short8v*)(wt + ((n*8+kc)*64 + l)*8);
      acc[n] = __builtin_amdgcn_mfma_f32_16x16x32_bf16(a,bf,acc[n],0,0,0);
    }
  }
  int col=l&15, rowb=(l>>4)*4;
  us* yo = y1T + ((size_t)b*PP + p0)*256 + co0;
  #pragma unroll
  for(int n=0;n<4;n++)
    #pragma unroll
    for(int r=0;r<4;r++)
      yo[(size_t)(rowb+r)*256 + n*16 + col] = f2u(acc[n][r]);
}

// ---- per-channel sum/sumsq over channel-last [b][p][256] ----
__global__ void k_stats(const us* src, float* sum, float* sq){
  int tid=threadIdx.x; int pt=blockIdx.x, b=blockIdx.y;
  const us* p = src + ((size_t)b*PP + pt*64)*256 + tid;
  float s=0,q=0;
  #pragma unroll 8
  for(int i=0;i<64;i++){ float v=u2f(p[(size_t)i*256]); s+=v; q+=v*v; }
  atomicAdd(&sum[tid],s); atomicAdd(&sq[tid],q);
}
__global__ void k_finstat(const float* sum, const float* sq, const void* g, const void* be,
                          const int* flag, float* sc, float* sh){
  int ch=threadIdx.x;
  int f=flag[0];
  float m = sum[ch]*(1.f/50176.f);
  float v = sq[ch]*(1.f/50176.f) - m*m;
  float s = ldin(g,ch,f) * rsqrtf(v+1e-5f);
  sc[ch]=s; sh[ch]=ldin(be,ch,f) - m*s;
}

// ---- xatt1 = relu(bn1(y1T)) elementwise ----
__global__ void k_bn1(const us* y1T, const float* sc, const float* sh, us* xatt1){
  size_t i = ((size_t)blockIdx.x*256+threadIdx.x)*8;
  int ch0 = (int)(i & 255);
  uint4 v = *(const uint4*)(y1T+i);
  const us* up=(const us*)&v;
  us r[8];
  #pragma unroll
  for(int j=0;j<8;j++){
    float x = u2f(up[j]);
    x = x*sc[ch0+j]+sh[ch0+j]; x = x>0.f?x:0.f;
    r[j]=f2u(x);
  }
  *(uint4*)(xatt1+i) = *(const uint4*)r;
}

// ---- involution: 4 waves share tile; writes channel-last invT ----
__global__ __launch_bounds__(256) void k_inv(const bf16* xatt1, const float* kern, us* invT){
  __shared__ __align__(16) us xt[196*72];
  int tid=threadIdx.x;
  int bx=blockIdx.x, by=blockIdx.y, bz=blockIdx.z;
  int t=bz&7, b=bz>>3;
  int y0=(bx/7)*8, x0=(bx%7)*8, c0=by*64;
  int w=tid>>6, l=tid&63;
  int ty=l>>3, tx=l&7;
  for(int e=tid;e<1568;e+=256){
    int row=e>>3, seg=e&7;
    int yy=row/14, xx=row%14;
    int gy=y0+yy-3, gx=x0+xx-3;
    uint4 v={0,0,0,0};
    if(gy>=0&&gy<56&&gx>=0&&gx<56)
      v = *(const uint4*)&xatt1[((size_t)b*PP + t*3136 + gy*56+gx)*256 + c0 + seg*8];
    *(uint4*)&xt[row*72+seg*8]=v;
  }
  float kr[49];
  size_t pxs=(size_t)t*3136 + (y0+ty)*56 + x0+tx;
  #pragma unroll
  for(int kk=0;kk<49;kk++) kr[kk]=kern[((size_t)b*49+kk)*PP+pxs];
  __syncthreads();
  #pragma unroll
  for(int s=0;s<2;s++){
    int sub=2*w+s;
    float acc[8];
    #pragma unroll
    for(int e=0;e<8;e++) acc[e]=0;
    for(int i=0;i<7;i++){
      #pragma unroll
      for(int j=0;j<7;j++){
        uint4 u = *(const uint4*)&xt[((ty+i)*14+tx+j)*72 + sub*8];
        float kv = kr[i*7+j];
        acc[0]+=kv*blo(u.x); acc[1]+=kv*bhi(u.x);
        acc[2]+=kv*blo(u.y); acc[3]+=kv*bhi(u.y);
        acc[4]+=kv*blo(u.z); acc[5]+=kv*bhi(u.z);
        acc[6]+=kv*blo(u.w); acc[7]+=kv*bhi(u.w);
      }
    }
    unsigned pk[4];
    #pragma unroll
    for(int e=0;e<4;e++)
      pk[e] = (unsigned)f2u(acc[2*e]) | ((unsigned)f2u(acc[2*e+1])<<16);
    *(uint4*)&invT[((size_t)b*PP+pxs)*256 + c0 + sub*8] = make_uint4(pk[0],pk[1],pk[2],pk[3]);
  }
}

// ---- W2s = W_p2*diag(sc2) bf16; bias2 = b_p2 + W_p2@sh2 ----
__global__ void k_w2s(const float* wf, const float* sc2, const float* sh2,
                      us* W2sb, float* bias2){
  __shared__ float red[256];
  int o=blockIdx.x, ci=threadIdx.x;
  float wv = wf[oWP2 + ci*64 + o];
  W2sb[o*256+ci] = f2u(wv * sc2[ci]);
  red[ci] = wv * sh2[ci];
  __syncthreads();
  for(int st=128;st>0;st>>=1){ if(ci<st) red[ci]+=red[ci+st]; __syncthreads(); }
  if(ci==0) bias2[o] = wf[oBP2+o] + red[0];
}

// ---- out = W2s@invT + W_p2@xattT + bias2 ; both weight panels LDS-staged ----
__global__ __launch_bounds__(256) void k_final(const us* invT, const us* xattT,
                                               const us* W2sb, const us* Wp2b,
                                               const float* bias2, float* out){
  __shared__ us wt[32768];     // [0:16384) W2s frags, [16384:32768) Wp2 frags
  int tid=threadIdx.x; int w=tid>>6, l=tid&63;
  int pt=blockIdx.x, b=blockIdx.y;
  #pragma unroll
  for(int it=0;it<16;it++){
    int f = it*256+tid;                 // f < 4096
    int which = f>>11;
    int g = f&2047;
    int n=g>>9, kc=(g>>6)&7, lane=g&63;
    int co = n*16 + (lane&15);
    int ci = (lane>>4)*8 + kc*32;
    const us* src = which ? Wp2b : W2sb;
    uint4 v = *(const uint4*)(src + (size_t)co*256 + ci);
    *(uint4*)(wt + f*8) = v;
  }
  __syncthreads();
  int p0 = pt*64 + w*16;
  size_t abase = ((size_t)b*PP + p0 + (l&15))*256 + ((l>>4)*8);
  f32x4 acc[4];
  #pragma unroll
  for(int n=0;n<4;n++) acc[n]=(f32x4){0,0,0,0};
  for(int kc=0;kc<8;kc++){
    short8v ai = *(const short8v*)(invT + abase + kc*32);
    short8v ax = *(const short8v*)(xattT + abase + kc*32);
    #pragma unroll
    for(int n=0;n<4;n++){
      short8v b1 = *(const short8v*)(wt + ((n*8+kc)*64 + l)*8);
      acc[n] = __builtin_amdgcn_mfma_f32_16x16x32_bf16(ai,b1,acc[n],0,0,0);
      short8v b2 = *(const short8v*)(wt + 16384 + ((n*8+kc)*64 + l)*8);
      acc[n] = __builtin_amdgcn_mfma_f32_16x16x32_bf16(ax,b2,acc[n],0,0,0);
    }
  }
  int col=l&15, rowb=(l>>4)*4;
  #pragma unroll
  for(int n=0;n<4;n++){
    float bb = bias2[n*16+col];
    #pragma unroll
    for(int r=0;r<4;r++)
      out[((size_t)b*64 + n*16+col)*PP + p0 + rowb + r] = acc[n][r] + bb;
  }
}

extern "C" void kernel_launch(void* const* d_in, const int* in_sizes, int n_in,
                              void* d_out, int out_size, void* d_ws, size_t ws_size,
                              hipStream_t stream){
  const void* xct_r =d_in[0];
  const void* xwsi_r=d_in[1];
  const void* Wct =d_in[2];
  const void* bct =d_in[3];
  const void* Wwsi=d_in[4];
  const void* bwsi=d_in[5];
  const void* Watt=d_in[6];
  const void* Winv=d_in[7];
  const void* binv=d_in[8];
  const void* Wrr =d_in[9];
  const void* g1  =d_in[10];
  const void* be1 =d_in[11];
  const void* g2  =d_in[12];
  const void* be2 =d_in[13];
  const void* Wp1 =d_in[14];
  const void* Wp2 =d_in[16];
  const void* bp2 =d_in[17];
  float* ws=(float*)d_ws;
  float* x1=ws+X1o; float* pool=ws+POOLo; float* xw1=ws+XW1o;
  float* Wx=ws+WXo; float* Wix=ws+WIXo;
  float* att=ws+ATTo; float* kern=ws+KERNo;
  us* Wf=(us*)(ws+WXTo);
  us* Wrr2=(us*)(ws+WRR2o);
  us* x1t=(us*)(ws+X1To);
  bf16* xw3=(bf16*)(ws+XW3o);
  float* stat=ws+STATo; float* wf=ws+WFo;
  float* Wattf=ws+WATTFo; float* Winvf=ws+WINVFo;
  float* bias2=ws+WATTFo;     // aliases Wattf (dead after k_Wx)
  int* flag=(int*)(ws+FLAGo);
  bf16* bfb=(bf16*)(ws+BF16o);
  bf16* xctb=bfb+bXCT; bf16* xwsib=bfb+bXWSI;
  us* xattT=(us*)(bfb+bXATT); us* y1T=(us*)(bfb+bY1); us* invT=(us*)(bfb+bINV);
  bf16* xatt1=bfb+bXATT1;
  us* Wp1b=(us*)(bfb+bWP1B); us* Wp2b=(us*)(bfb+bWP2B); us* W2sb=(us*)(bfb+bW2S);
  us* xwt=(us*)(bfb+bXWT);
  float* sum1=stat; float* sq1=stat+256; float* sum2=stat+512; float* sq2=stat+768;
  float* sc1=stat+1024; float* sh1=stat+1280; float* sc2=stat+1536; float* sh2=stat+1792;

  hipMemsetAsync(stat,0,4096,stream);
  k_detect<<<1,64,0,stream>>>((const us*)xct_r,flag);
  k_c2b   <<<12544,256,0,stream>>>(xct_r,xctb,3211264,flag);
  k_c2b   <<<18816,256,0,stream>>>(xwsi_r,xwsib,4816896,flag);
  k_c2f   <<<3733,256,0,stream>>>(Watt,Wattf,955500,flag);
  k_c2f   <<<113,256,0,stream>>>(Winv,Winvf,28812,flag);
  k_cvt   <<<461,256,0,stream>>>(Wct,bct,Wwsi,bwsi,Wrr,binv,Wp1,Wp2,bp2,wf,flag);
  k_wb    <<<320,256,0,stream>>>(Wp1,Wp2,Wp1b,Wp2b,flag);
  k_wsit  <<<dim3(49,12,2),256,0,stream>>>(xwsib,xwt);      // xwt aliases y1T (dead until k_p1)
  k_pool  <<<294,256,0,stream>>>(xwsib,pool);
  k_xw1   <<<294,256,0,stream>>>(pool,wf,xw1);
  k_Wx    <<<813,256,0,stream>>>(Wattf,xw1,Wx);
  k_Wfrag <<<1000,256,0,stream>>>(Wx,Wf);
  k_rrfrag<<<108,256,0,stream>>>(wf,Wrr2);                  // overwrites Wx head (dead)
  k_Winvx <<<25,256,0,stream>>>(Winvf,xw1,Wix);
  k_x1    <<<dim3(98,4,2),256,0,stream>>>(xctb,wf,x1,x1t);
  k_att   <<<dim3(49,8,2),256,0,stream>>>(x1t,Wf,att);
  k_kern  <<<dim3(98,2),256,0,stream>>>(x1,Wix,wf,kern);    // overwrites x1t (dead)
  k_rr    <<<dim3(49,12,2),256,0,stream>>>(xwt,Wrr2,xw3);
  k_xatt  <<<dim3(392,2),256,0,stream>>>(xctb,xw3,att,xattT);
  k_p1    <<<dim3(392,4,2),256,0,stream>>>(xattT,Wp1b,y1T); // LDS-staged, co-quarter split
  k_stats <<<dim3(392,2),256,0,stream>>>(y1T,sum1,sq1);
  k_finstat<<<1,256,0,stream>>>(sum1,sq1,g1,be1,flag,sc1,sh1);
  k_bn1   <<<6272,256,0,stream>>>(y1T,sc1,sh1,(us*)xatt1);
  k_inv   <<<dim3(49,4,16),256,0,stream>>>(xatt1,kern,invT);
  k_stats <<<dim3(392,2),256,0,stream>>>(invT,sum2,sq2);
  k_finstat<<<1,256,0,stream>>>(sum2,sq2,g2,be2,flag,sc2,sh2);
  k_w2s   <<<64,256,0,stream>>>(wf,sc2,sh2,W2sb,bias2);
  k_final <<<dim3(392,2),256,0,stream>>>(invT,xattT,W2sb,Wp2b,bias2,(float*)d_out);
}

// Round 13
// 387.523 us; speedup vs baseline: 2.6430x; 1.0204x over previous
//
#include <hip/hip_runtime.h>
#include <hip/hip_bf16.h>
#include <math.h>

typedef __hip_bfloat16 bf16;
typedef unsigned short us;
typedef __attribute__((ext_vector_type(8))) short short8v;
typedef __attribute__((ext_vector_type(4))) float f32x4;
#define DEV static __device__ __forceinline__
DEV float b2f(bf16 x){ return __bfloat162float(x); }
DEV bf16  f2b(float x){ return __float2bfloat16(x); }
DEV us    f2u(float x){ bf16 h=f2b(x); return *(us*)&h; }
DEV float u2f(us u){ return __uint_as_float(((unsigned)u)<<16); }
DEV float blo(unsigned int w){ return __uint_as_float(w<<16); }
DEV float bhi(unsigned int w){ return __uint_as_float(w&0xffff0000u); }
DEV float ldin(const void* p, long i, int f){
  return f ? ((const float*)p)[i] : b2f(((const bf16*)p)[i]);
}

// problem dims
#define PP 25088            // t*h*w = 8*56*56

// ws layout (float units)
#define X1o    0L           // (free)
#define POOLo  3211264L
#define XW1o   3286528L
#define WXo    3361792L     // Wx f32 208000; re-aliased by Wrr2 after k_Wfrag
#define WXTo   3569792L     // Wf MFMA A-frags: 256000 bf16
#define WIXo   3825792L
#define ATTo   3832064L     // 2*13*25088 f32
#define KERNo  4484352L     // 2*49*25088 f32 (no aliases now)
#define XW3o   6942976L     // xw3 bf16
#define STATo  8147200L
#define FLAGo  8149248L
#define WFo    8149264L
#define WATTFo 8267280L     // W_att f32; dead after k_Wx -> bias2 aliases head
#define WINVFo 9222784L
#define BF16o  9251600L
#define WRR2o  WXo
// bf16 sub-offsets (bf16 element units)
#define bXCT   0L           // 3211264
#define bX1T   3211264L     // x1t [b][p][64] 3211264 (in old xwsib slot, 4816896 avail)
#define bXATT  8028160L     // xattT [b][p][256] 12845056
#define bY1    20873216L    // y1T [b][p][256] 12845056 (xwt aliases head until k_p1)
#define bINV   33718272L    // invT [b][p][256] 12845056 (old xatt1 slot, now separate from y1T)
#define bWP1B  46563328L    // Wp1b bf16 raw [co][ci] 65536
#define bWP2B  46628864L    // Wp2b bf16 raw [o][ci] 16384
#define bW2S   46645248L    // W2sb bf16 [o][ci] 16384
#define bXWT   bY1          // xwt [b][d][hw][64]; dead before k_p1 writes y1T
// wf sub-offsets
#define oWCT   0
#define oBCT   4096
#define oWWSI  4160
#define oBWSI  8256
#define oWRR   8320
#define oBINV  35968
#define oWP1   36032
#define oWP2   101568       // [ci][co] 256x64
#define oBP2   117952

// ---- input dtype probe ----
__global__ void k_detect(const us* raw, int* flag){
  int t = threadIdx.x;
  us u = raw[2*t];
  int e = (u>>7)&0xFF;
  int hit = (e >= 137);
  unsigned long long m = __ballot(hit);
  if(t==0) flag[0] = (__popcll(m) >= 8) ? 1 : 0;
}

// ---- canonicalize inputs ----
__global__ void k_c2b(const void* src, bf16* dst, int n, const int* flag){
  int i = blockIdx.x*256+threadIdx.x; if(i>=n) return;
  int f = flag[0];
  dst[i] = f ? f2b(((const float*)src)[i]) : ((const bf16*)src)[i];
}
__global__ void k_c2f(const void* src, float* dst, int n, const int* flag){
  int i = blockIdx.x*256+threadIdx.x; if(i>=n) return;
  dst[i] = ldin(src, i, flag[0]);
}

// ---- weight convert ----
__global__ void k_cvt(const void* Wct,const void* bct,const void* Wwsi,const void* bwsi,
                      const void* Wrr,const void* binv,const void* Wp1,const void* Wp2,
                      const void* bp2,float* wf,const int* flag){
  int i = blockIdx.x*256 + threadIdx.x;
  int f = flag[0];
  if (i < 4096){ int co=i>>6, ci=i&63; wf[oWCT + ci*64+co] = ldin(Wct,i,f); }
  else if (i < 4160){ wf[i] = ldin(bct,i-4096,f); }
  else if (i < 8256){ wf[i] = ldin(Wwsi,i-4160,f); }
  else if (i < 8320){ wf[i] = ldin(bwsi,i-8256,f); }
  else if (i < 35968){ int l=i-8320; int co=l/1728, r=l%1728, ci=r/27, tp=r%27;
                       wf[oWRR + (ci*27+tp)*16+co] = ldin(Wrr,l,f); }
  else if (i < 36017){ wf[oBINV + (i-35968)] = ldin(binv,i-35968,f); }
  else if (i < 36032){ }
  else if (i < 101568){ int l=i-36032; int co=l>>8, ci=l&255; wf[oWP1 + ci*256+co] = ldin(Wp1,l,f); }
  else if (i < 117952){ int l=i-101568; int o=l>>8, ci=l&255; wf[oWP2 + ci*64+o] = ldin(Wp2,l,f); }
  else if (i < 118016){ int l=i-117952; if(l<64) wf[oBP2 + l] = ldin(bp2,l,f); }
}

// ---- raw-order bf16 weight copies for GEMM B operands ----
__global__ void k_wb(const void* Wp1, const void* Wp2, us* Wp1b, us* Wp2b, const int* flag){
  int i = blockIdx.x*256+threadIdx.x;
  int f = flag[0];
  if(i<65536) Wp1b[i]=f2u(ldin(Wp1,i,f));
  else if(i<81920) Wp2b[i-65536]=f2u(ldin(Wp2,i-65536,f));
}

// ---- xwt = channel-last x_WSI [b][d][hw][64] straight from raw input ----
__global__ void k_wsit(const void* xwsi_r, const int* flag, us* xwt){
  __shared__ us tl[64*68];
  int tid=threadIdx.x; int p0=blockIdx.x*64; int d=blockIdx.y; int b=blockIdx.z;
  int f=flag[0];
  #pragma unroll
  for(int k=0;k<16;k++){
    int idx=k*256+tid; int px=idx&63, c=idx>>6;
    float v = ldin(xwsi_r, ((long)(b*64+c)*12+d)*3136 + p0+px, f);
    tl[px*68+c] = f2u(v);
  }
  __syncthreads();
  #pragma unroll
  for(int k=0;k<16;k++){
    int idx=k*256+tid; int px=idx>>6, ch=idx&63;
    xwt[((size_t)(b*12+d)*3136 + p0+px)*64 + ch] = tl[px*68+ch];
  }
}

// ---- adaptive pool over channel-last xwt (lanes = consecutive ch: coalesced) ----
__global__ void k_pool(const us* xwt, float* pool){
  int i = blockIdx.x*256+threadIdx.x;
  int c = i&63; int m=(i>>6)%588; int b=i/37632;
  int d=m/49, r=m%49, ii=r/7, jj=r%7;
  const us* src = xwt + ((size_t)(b*12+d)*3136 + (ii*8)*56 + jj*8)*64 + c;
  float s=0;
  for(int u=0;u<8;u++)
    for(int v=0;v<8;v++) s += u2f(src[(size_t)(u*56+v)*64]);
  pool[i] = s*(1.f/64.f);
}

// ---- xw1 = W_wsi * pooled + b ----
__global__ void k_xw1(const float* pool, const float* wf, float* xw1){
  int i = blockIdx.x*256+threadIdx.x;
  int c = i&63; int m=(i>>6)%588; int b=i/37632;
  const float* p = pool + (b*588+m)*64;
  const float* w = wf + oWWSI + c*64;
  float s = wf[oBWSI + c];
  for(int ci=0;ci<64;ci++) s += w[ci]*p[ci];
  xw1[i]=s;
}

// ---- Wx[b,o,tap,c] = sum_m W_att[o,m,tap] * xw1[b,c,m] ----
__global__ void k_Wx(const float* Wattf, const float* xw1, float* Wx){
  int i = blockIdx.x*256+threadIdx.x; if(i>=208000) return;
  int c=i&63; int r=i>>6; int tap=r%125; int o=(r/125)%13; int b=r/1625;
  const float* wa = Wattf + (size_t)o*588*125 + tap;
  const float* xp = xw1 + b*588*64 + c;
  float s=0;
  for(int m=0;m<588;m++) s += wa[(size_t)m*125] * xp[m*64];
  Wx[i]=s;
}

// ---- Wf: MFMA A-fragments for k_att ----
__global__ void k_Wfrag(const float* Wx, us* Wf){
  int i = blockIdx.x*256+threadIdx.x; if(i>=256000) return;
  int j=i&7; int m=(i>>3)&15; int kg=(i>>7)&3; int ch=(i>>9)&1;
  int r=i>>10; int tap=r%125; int b=r/125;
  int c = ch*32 + kg*8 + j;
  float v = (m<13) ? Wx[((size_t)(b*13+m)*125+tap)*64 + c] : 0.f;
  Wf[i] = f2u(v);
}

// ---- Wrr2: MFMA A-fragments for k_rr ----
__global__ void k_rrfrag(const float* wf, us* Wrr2){
  int i = blockIdx.x*256+threadIdx.x; if(i>=27648) return;
  int j=i&7; int l=(i>>3)&63; int kg=(i>>9)&1; int td=i>>10;
  int m=l&15, g=l>>4;
  int c = kg*32 + g*8 + j;
  Wrr2[i] = f2u(wf[oWRR + (c*27+td)*16 + m]);
}

// ---- Winvx ----
__global__ void k_Winvx(const float* Winvf, const float* xw1, float* Wix){
  int i = blockIdx.x*256+threadIdx.x; if(i>=6272) return;
  int kk=i%49; int c=(i/49)&63; int b=i/3136;
  const float* xp = xw1 + b*588*64 + c;
  float s=0;
  for(int m=0;m<588;m++) s += Winvf[kk*588+m] * xp[m*64];
  Wix[i]=s;
}

// ---- x1t = bf16 channel-last (W_ct * x_CT + b) ----
__global__ void k_x1(const bf16* xct, const float* wf, us* x1t){
  int p = blockIdx.x*256+threadIdx.x;
  int co0 = blockIdx.y*16; int b = blockIdx.z;
  float acc[16];
  #pragma unroll
  for(int o=0;o<16;o++) acc[o]=wf[oBCT+co0+o];
  const bf16* xp = xct + (size_t)b*64*PP + p;
  for(int ci=0;ci<64;ci++){
    float xv = b2f(xp[(size_t)ci*PP]);
    const float* w = wf + oWCT + ci*64 + co0;
    #pragma unroll
    for(int o=0;o<16;o++) acc[o] += w[o]*xv;
  }
  unsigned int pk[8];
  #pragma unroll
  for(int o2=0;o2<8;o2++)
    pk[o2] = (unsigned)f2u(acc[2*o2]) | ((unsigned)f2u(acc[2*o2+1])<<16);
  us* xo = x1t + ((size_t)(b*PP)+p)*64 + co0;
  *(uint4*)xo     = make_uint4(pk[0],pk[1],pk[2],pk[3]);
  *(uint4*)(xo+8) = make_uint4(pk[4],pk[5],pk[6],pk[7]);
}

// ---- Att = sigmoid(conv5x5x5) via MFMA implicit GEMM ----
__global__ __launch_bounds__(256) void k_att(const us* x1t, const us* Wf, float* att){
  __shared__ short xt[10368];
  int tid=threadIdx.x;
  int tile=blockIdx.x, t=blockIdx.y, b=blockIdx.z;
  int y0=(tile/7)*8, x0=(tile%7)*8;
  int w=tid>>6, l=tid&63;
  int pc=l&7, pr=(l>>3)&1, g=l>>4;
  f32x4 acc0={0,0,0,0}, acc1={0,0,0,0};
  int bbase = ((2*w+pr)*12 + pc)*72 + g*8;
  const us* Wb = Wf + (size_t)b*128000 + l*8;
  for(int dt=0;dt<5;dt++){
    int ti=t+dt-2;
    if(ti<0||ti>=8) continue;
    __syncthreads();
    for(int e=tid;e<1152;e+=256){
      int px=e>>3, q=e&7;
      int row=px/12, col=px-row*12;
      int gy=y0+row-2, gx=x0+col-2;
      uint4 v={0,0,0,0};
      if((unsigned)gy<56u && (unsigned)gx<56u)
        v = *(const uint4*)(x1t + ((size_t)(b*PP) + ti*3136 + gy*56 + gx)*64 + q*8);
      *(uint4*)&xt[px*72 + q*8] = v;
    }
    __syncthreads();
    const us* Wd = Wb + dt*25600;
    #pragma unroll
    for(int dy=0;dy<5;dy++){
      #pragma unroll
      for(int dx=0;dx<5;dx++){
        int off = bbase + dy*864 + dx*72;
        short8v a0 = *(const short8v*)(Wd + (dy*5+dx)*1024);
        short8v b0 = *(const short8v*)&xt[off];
        acc0 = __builtin_amdgcn_mfma_f32_16x16x32_bf16(a0,b0,acc0,0,0,0);
        short8v a1 = *(const short8v*)(Wd + (dy*5+dx)*1024 + 512);
        short8v b1 = *(const short8v*)&xt[off+32];
        acc1 = __builtin_amdgcn_mfma_f32_16x16x32_bf16(a1,b1,acc1,0,0,0);
      }
    }
  }
  int px=l&15; int epc=px&7, epr=px>>3;
  size_t pbase=(size_t)t*3136+(size_t)(y0+2*w+epr)*56+x0+epc;
  #pragma unroll
  for(int r=0;r<4;r++){
    int o=g*4+r;
    if(o<13){
      float s=acc0[r]+acc1[r];
      att[((size_t)b*13+o)*PP+pbase]=1.f/(1.f+__expf(-s));
    }
  }
}

// ---- kern49 = Winvx * x1 + b_inv (reads bf16 channel-last x1t) ----
__global__ void k_kern(const us* x1t, const float* Wix, const float* wf, float* kern){
  int p = blockIdx.x*256+threadIdx.x; int b=blockIdx.y;
  float acc[49];
  #pragma unroll
  for(int kk=0;kk<49;kk++) acc[kk]=wf[oBINV+kk];
  const us* xp = x1t + ((size_t)b*PP + p)*64;
  #pragma unroll
  for(int c8=0;c8<8;c8++){
    uint4 v = *(const uint4*)(xp + c8*8);
    const us* vp=(const us*)&v;
    #pragma unroll
    for(int j=0;j<8;j++){
      float xv = u2f(vp[j]);
      const float* w = Wix + (b*64+c8*8+j)*49;
      #pragma unroll
      for(int kk=0;kk<49;kk++) acc[kk]+=w[kk]*xv;
    }
  }
  float* out = kern + (size_t)b*49*PP + p;
  #pragma unroll
  for(int kk=0;kk<49;kk++) out[(size_t)kk*PP]=acc[kk];
}

// ---- xw3 = conv3x3x3 via MFMA implicit GEMM ----
__global__ __launch_bounds__(256) void k_rr(const us* xwt, const us* Wrr2, bf16* xw3){
  __shared__ short xt[7200];
  int tid=threadIdx.x;
  int tile=blockIdx.x, d=blockIdx.y, b=blockIdx.z;
  int y0=(tile/7)*8, x0=(tile%7)*8;
  int w=tid>>6, l=tid&63;
  int pc=l&7, pr=(l>>3)&1, g=l>>4;
  f32x4 acc0={0,0,0,0}, acc1={0,0,0,0};
  int bbase = ((2*w+pr)*10 + pc)*72 + g*8;
  const us* Wl = Wrr2 + l*8;
  for(int dz=0;dz<3;dz++){
    int di=d+dz-1;
    if(di<0||di>=12) continue;
    __syncthreads();
    for(int e=tid;e<800;e+=256){
      int px=e>>3, q=e&7;
      int row=px/10, col=px-row*10;
      int gy=y0+row-1, gx=x0+col-1;
      uint4 v={0,0,0,0};
      if((unsigned)gy<56u && (unsigned)gx<56u)
        v = *(const uint4*)(xwt + ((size_t)(b*12+di)*3136 + gy*56 + gx)*64 + q*8);
      *(uint4*)&xt[px*72 + q*8] = v;
    }
    __syncthreads();
    const us* Wd = Wl + dz*9216;
    #pragma unroll
    for(int tap=0;tap<9;tap++){
      int dy=tap/3, dx=tap-dy*3;
      int off = bbase + (dy*10+dx)*72;
      short8v a0 = *(const short8v*)(Wd + tap*1024);
      short8v b0 = *(const short8v*)&xt[off];
      acc0 = __builtin_amdgcn_mfma_f32_16x16x32_bf16(a0,b0,acc0,0,0,0);
      short8v a1 = *(const short8v*)(Wd + tap*1024 + 512);
      short8v b1 = *(const short8v*)&xt[off+32];
      acc1 = __builtin_amdgcn_mfma_f32_16x16x32_bf16(a1,b1,acc1,0,0,0);
    }
  }
  int px=l&15; int epc=px&7, epr=px>>3;
  size_t pp=(size_t)(y0+2*w+epr)*56 + x0+epc;
  #pragma unroll
  for(int r=0;r<4;r++){
    int o=g*4+r;
    xw3[((size_t)(b*16+o)*12+d)*3136 + pp] = f2b(acc0[r]+acc1[r]);
  }
}

// ---- xattT = channel-last x_Att [b][p][256] via LDS transpose ----
__global__ void k_xatt(const bf16* xct, const bf16* xw3, const float* att, us* xattT){
  __shared__ us tl[64*258];
  int tid=threadIdx.x; int p0=blockIdx.x*64; int b=blockIdx.y;
  for(int k=0;k<64;k++){
    int idx=k*256+tid; int ch=idx>>6, pp=idx&63;
    int p=p0+pp;
    float v;
    if(ch<64){
      v = b2f(xct[((size_t)b*64+ch)*PP+p]) * (1.f+att[(size_t)b*13*PP+p]);
    } else {
      int q=ch-64; int co=q/12, dd=q-co*12;
      int s=p%3136;
      v = b2f(xw3[((size_t)(b*16+co)*12+dd)*3136+s]) * (1.f+att[((size_t)b*13+1+q/16)*PP+p]);
    }
    tl[pp*258+ch]=f2u(v);
  }
  __syncthreads();
  for(int k=0;k<64;k++)
    xattT[((size_t)b*PP + p0+k)*256 + tid] = tl[k*258+tid];
}

// ---- y1T = x_Att @ W_p1^T ; LDS-staged weight panel in fragment order ----
__global__ __launch_bounds__(256) void k_p1(const us* xattT, const us* Wp1b, us* y1T){
  __shared__ us wt[16384];
  int tid=threadIdx.x; int w=tid>>6, l=tid&63;
  int pt=blockIdx.x, qtr=blockIdx.y, b=blockIdx.z;
  int co0 = qtr*64;
  #pragma unroll
  for(int it=0;it<8;it++){
    int f = it*256+tid;
    int n=f>>9, kc=(f>>6)&7, lane=f&63;
    int co = co0 + n*16 + (lane&15);
    int ci = (lane>>4)*8 + kc*32;
    uint4 v = *(const uint4*)(Wp1b + (size_t)co*256 + ci);
    *(uint4*)(wt + f*8) = v;
  }
  __syncthreads();
  int p0 = pt*64 + w*16;
  const us* xa = xattT + ((size_t)b*PP + p0 + (l&15))*256 + ((l>>4)*8);
  f32x4 acc[4];
  #pragma unroll
  for(int n=0;n<4;n++) acc[n]=(f32x4){0,0,0,0};
  for(int kc=0;kc<8;kc++){
    short8v a = *(const short8v*)(xa + kc*32);
    #pragma unroll
    for(int n=0;n<4;n++){
      short8v bf = *(const short8v*)(wt + ((n*8+kc)*64 + l)*8);
      acc[n] = __builtin_amdgcn_mfma_f32_16x16x32_bf16(a,bf,acc[n],0,0,0);
    }
  }
  int col=l&15, rowb=(l>>4)*4;
  us* yo = y1T + ((size_t)b*PP + p0)*256 + co0;
  #pragma unroll
  for(int n=0;n<4;n++)
    #pragma unroll
    for(int r=0;r<4;r++)
      yo[(size_t)(rowb+r)*256 + n*16 + col] = f2u(acc[n][r]);
}

// ---- per-channel sum/sumsq over channel-last [b][p][256] ----
__global__ void k_stats(const us* src, float* sum, float* sq){
  int tid=threadIdx.x; int pt=blockIdx.x, b=blockIdx.y;
  const us* p = src + ((size_t)b*PP + pt*64)*256 + tid;
  float s=0,q=0;
  #pragma unroll 8
  for(int i=0;i<64;i++){ float v=u2f(p[(size_t)i*256]); s+=v; q+=v*v; }
  atomicAdd(&sum[tid],s); atomicAdd(&sq[tid],q);
}
__global__ void k_finstat(const float* sum, const float* sq, const void* g, const void* be,
                          const int* flag, float* sc, float* sh){
  int ch=threadIdx.x;
  int f=flag[0];
  float m = sum[ch]*(1.f/50176.f);
  float v = sq[ch]*(1.f/50176.f) - m*m;
  float s = ldin(g,ch,f) * rsqrtf(v+1e-5f);
  sc[ch]=s; sh[ch]=ldin(be,ch,f) - m*s;
}

// ---- involution with bn1+relu fused into staging; reads y1T, writes invT ----
__global__ __launch_bounds__(256) void k_inv(const us* y1T, const float* sc1, const float* sh1,
                                             const float* kern, us* invT){
  __shared__ __align__(16) us xt[196*72];
  int tid=threadIdx.x;
  int bx=blockIdx.x, by=blockIdx.y, bz=blockIdx.z;
  int t=bz&7, b=bz>>3;
  int y0=(bx/7)*8, x0=(bx%7)*8, c0=by*64;
  int w=tid>>6, l=tid&63;
  int ty=l>>3, tx=l&7;
  // per-thread bn params for its fixed seg = tid&7 (8 channels)
  int segb = c0 + (tid&7)*8;
  float scr[8], shr[8];
  #pragma unroll
  for(int j=0;j<8;j++){ scr[j]=sc1[segb+j]; shr[j]=sh1[segb+j]; }
  for(int e=tid;e<1568;e+=256){
    int row=e>>3, seg=e&7;                       // seg == tid&7
    int yy=row/14, xx=row%14;
    int gy=y0+yy-3, gx=x0+xx-3;
    uint4 o4={0,0,0,0};
    if(gy>=0&&gy<56&&gx>=0&&gx<56){
      uint4 v = *(const uint4*)&y1T[((size_t)b*PP + t*3136 + gy*56+gx)*256 + c0 + seg*8];
      const us* vp=(const us*)&v;
      us r[8];
      #pragma unroll
      for(int j=0;j<8;j++){
        float x = u2f(vp[j]);
        x = x*scr[j]+shr[j]; x = x>0.f?x:0.f;
        r[j]=f2u(x);
      }
      o4 = *(const uint4*)r;
    }
    *(uint4*)&xt[row*72+seg*8]=o4;
  }
  float kr[49];
  size_t pxs=(size_t)t*3136 + (y0+ty)*56 + x0+tx;
  #pragma unroll
  for(int kk=0;kk<49;kk++) kr[kk]=kern[((size_t)b*49+kk)*PP+pxs];
  __syncthreads();
  #pragma unroll
  for(int s=0;s<2;s++){
    int sub=2*w+s;
    float acc[8];
    #pragma unroll
    for(int e=0;e<8;e++) acc[e]=0;
    for(int i=0;i<7;i++){
      #pragma unroll
      for(int j=0;j<7;j++){
        uint4 u = *(const uint4*)&xt[((ty+i)*14+tx+j)*72 + sub*8];
        float kv = kr[i*7+j];
        acc[0]+=kv*blo(u.x); acc[1]+=kv*bhi(u.x);
        acc[2]+=kv*blo(u.y); acc[3]+=kv*bhi(u.y);
        acc[4]+=kv*blo(u.z); acc[5]+=kv*bhi(u.z);
        acc[6]+=kv*blo(u.w); acc[7]+=kv*bhi(u.w);
      }
    }
    unsigned pk[4];
    #pragma unroll
    for(int e=0;e<4;e++)
      pk[e] = (unsigned)f2u(acc[2*e]) | ((unsigned)f2u(acc[2*e+1])<<16);
    *(uint4*)&invT[((size_t)b*PP+pxs)*256 + c0 + sub*8] = make_uint4(pk[0],pk[1],pk[2],pk[3]);
  }
}

// ---- W2s = W_p2*diag(sc2) bf16; bias2 = b_p2 + W_p2@sh2 ----
__global__ void k_w2s(const float* wf, const float* sc2, const float* sh2,
                      us* W2sb, float* bias2){
  __shared__ float red[256];
  int o=blockIdx.x, ci=threadIdx.x;
  float wv = wf[oWP2 + ci*64 + o];
  W2sb[o*256+ci] = f2u(wv * sc2[ci]);
  red[ci] = wv * sh2[ci];
  __syncthreads();
  for(int st=128;st>0;st>>=1){ if(ci<st) red[ci]+=red[ci+st]; __syncthreads(); }
  if(ci==0) bias2[o] = wf[oBP2+o] + red[0];
}

// ---- out = W2s@invT + W_p2@xattT + bias2 ; both weight panels LDS-staged ----
__global__ __launch_bounds__(256) void k_final(const us* invT, const us* xattT,
                                               const us* W2sb, const us* Wp2b,
                                               const float* bias2, float* out){
  __shared__ us wt[32768];
  int tid=threadIdx.x; int w=tid>>6, l=tid&63;
  int pt=blockIdx.x, b=blockIdx.y;
  #pragma unroll
  for(int it=0;it<16;it++){
    int f = it*256+tid;
    int which = f>>11;
    int g = f&2047;
    int n=g>>9, kc=(g>>6)&7, lane=g&63;
    int co = n*16 + (lane&15);
    int ci = (lane>>4)*8 + kc*32;
    const us* src = which ? Wp2b : W2sb;
    uint4 v = *(const uint4*)(src + (size_t)co*256 + ci);
    *(uint4*)(wt + f*8) = v;
  }
  __syncthreads();
  int p0 = pt*64 + w*16;
  size_t abase = ((size_t)b*PP + p0 + (l&15))*256 + ((l>>4)*8);
  f32x4 acc[4];
  #pragma unroll
  for(int n=0;n<4;n++) acc[n]=(f32x4){0,0,0,0};
  for(int kc=0;kc<8;kc++){
    short8v ai = *(const short8v*)(invT + abase + kc*32);
    short8v ax = *(const short8v*)(xattT + abase + kc*32);
    #pragma unroll
    for(int n=0;n<4;n++){
      short8v b1 = *(const short8v*)(wt + ((n*8+kc)*64 + l)*8);
      acc[n] = __builtin_amdgcn_mfma_f32_16x16x32_bf16(ai,b1,acc[n],0,0,0);
      short8v b2 = *(const short8v*)(wt + 16384 + ((n*8+kc)*64 + l)*8);
      acc[n] = __builtin_amdgcn_mfma_f32_16x16x32_bf16(ax,b2,acc[n],0,0,0);
    }
  }
  int col=l&15, rowb=(l>>4)*4;
  #pragma unroll
  for(int n=0;n<4;n++){
    float bb = bias2[n*16+col];
    #pragma unroll
    for(int r=0;r<4;r++)
      out[((size_t)b*64 + n*16+col)*PP + p0 + rowb + r] = acc[n][r] + bb;
  }
}

extern "C" void kernel_launch(void* const* d_in, const int* in_sizes, int n_in,
                              void* d_out, int out_size, void* d_ws, size_t ws_size,
                              hipStream_t stream){
  const void* xct_r =d_in[0];
  const void* xwsi_r=d_in[1];
  const void* Wct =d_in[2];
  const void* bct =d_in[3];
  const void* Wwsi=d_in[4];
  const void* bwsi=d_in[5];
  const void* Watt=d_in[6];
  const void* Winv=d_in[7];
  const void* binv=d_in[8];
  const void* Wrr =d_in[9];
  const void* g1  =d_in[10];
  const void* be1 =d_in[11];
  const void* g2  =d_in[12];
  const void* be2 =d_in[13];
  const void* Wp1 =d_in[14];
  const void* Wp2 =d_in[16];
  const void* bp2 =d_in[17];
  float* ws=(float*)d_ws;
  float* pool=ws+POOLo; float* xw1=ws+XW1o;
  float* Wx=ws+WXo; float* Wix=ws+WIXo;
  float* att=ws+ATTo; float* kern=ws+KERNo;
  us* Wf=(us*)(ws+WXTo);
  us* Wrr2=(us*)(ws+WRR2o);
  bf16* xw3=(bf16*)(ws+XW3o);
  float* stat=ws+STATo; float* wf=ws+WFo;
  float* Wattf=ws+WATTFo; float* Winvf=ws+WINVFo;
  float* bias2=ws+WATTFo;     // aliases Wattf (dead after k_Wx)
  int* flag=(int*)(ws+FLAGo);
  bf16* bfb=(bf16*)(ws+BF16o);
  bf16* xctb=bfb+bXCT;
  us* x1t=(us*)(bfb+bX1T);
  us* xattT=(us*)(bfb+bXATT); us* y1T=(us*)(bfb+bY1); us* invT=(us*)(bfb+bINV);
  us* Wp1b=(us*)(bfb+bWP1B); us* Wp2b=(us*)(bfb+bWP2B); us* W2sb=(us*)(bfb+bW2S);
  us* xwt=(us*)(bfb+bXWT);
  float* sum1=stat; float* sq1=stat+256; float* sum2=stat+512; float* sq2=stat+768;
  float* sc1=stat+1024; float* sh1=stat+1280; float* sc2=stat+1536; float* sh2=stat+1792;

  hipMemsetAsync(stat,0,4096,stream);
  k_detect<<<1,64,0,stream>>>((const us*)xct_r,flag);
  k_c2b   <<<12544,256,0,stream>>>(xct_r,xctb,3211264,flag);
  k_c2f   <<<3733,256,0,stream>>>(Watt,Wattf,955500,flag);
  k_c2f   <<<113,256,0,stream>>>(Winv,Winvf,28812,flag);
  k_cvt   <<<461,256,0,stream>>>(Wct,bct,Wwsi,bwsi,Wrr,binv,Wp1,Wp2,bp2,wf,flag);
  k_wb    <<<320,256,0,stream>>>(Wp1,Wp2,Wp1b,Wp2b,flag);
  k_wsit  <<<dim3(49,12,2),256,0,stream>>>(xwsi_r,flag,xwt); // xwt aliases y1T head (dead until k_p1)
  k_pool  <<<294,256,0,stream>>>(xwt,pool);
  k_xw1   <<<294,256,0,stream>>>(pool,wf,xw1);
  k_Wx    <<<813,256,0,stream>>>(Wattf,xw1,Wx);
  k_Wfrag <<<1000,256,0,stream>>>(Wx,Wf);
  k_rrfrag<<<108,256,0,stream>>>(wf,Wrr2);                   // overwrites Wx head (dead)
  k_Winvx <<<25,256,0,stream>>>(Winvf,xw1,Wix);
  k_x1    <<<dim3(98,4,2),256,0,stream>>>(xctb,wf,x1t);
  k_att   <<<dim3(49,8,2),256,0,stream>>>(x1t,Wf,att);
  k_kern  <<<dim3(98,2),256,0,stream>>>(x1t,Wix,wf,kern);
  k_rr    <<<dim3(49,12,2),256,0,stream>>>(xwt,Wrr2,xw3);
  k_xatt  <<<dim3(392,2),256,0,stream>>>(xctb,xw3,att,xattT);
  k_p1    <<<dim3(392,4,2),256,0,stream>>>(xattT,Wp1b,y1T);  // overwrites xwt (dead)
  k_stats <<<dim3(392,2),256,0,stream>>>(y1T,sum1,sq1);
  k_finstat<<<1,256,0,stream>>>(sum1,sq1,g1,be1,flag,sc1,sh1);
  k_inv   <<<dim3(49,4,16),256,0,stream>>>(y1T,sc1,sh1,kern,invT); // bn1 fused into staging
  k_stats <<<dim3(392,2),256,0,stream>>>(invT,sum2,sq2);
  k_finstat<<<1,256,0,stream>>>(sum2,sq2,g2,be2,flag,sc2,sh2);
  k_w2s   <<<64,256,0,stream>>>(wf,sc2,sh2,W2sb,bias2);
  k_final <<<dim3(392,2),256,0,stream>>>(invT,xattT,W2sb,Wp2b,bias2,(float*)d_out);
}

// Round 14
// 386.192 us; speedup vs baseline: 2.6521x; 1.0034x over previous
//
#include <hip/hip_runtime.h>
#include <hip/hip_bf16.h>
#include <hip/hip_fp16.h>
#include <math.h>

typedef __hip_bfloat16 bf16;
typedef unsigned short us;
typedef __attribute__((ext_vector_type(8))) short short8v;
typedef __attribute__((ext_vector_type(4))) float f32x4;
#define DEV static __device__ __forceinline__
DEV float b2f(bf16 x){ return __bfloat162float(x); }
DEV bf16  f2b(float x){ return __float2bfloat16(x); }
DEV us    f2u(float x){ bf16 h=f2b(x); return *(us*)&h; }
DEV float u2f(us u){ return __uint_as_float(((unsigned)u)<<16); }
DEV us    f2h(float x){ __half h=__float2half(x); return *(us*)&h; }
DEV float hlo(unsigned int w){ return __half2float(__ushort_as_half((us)(w&0xffff))); }
DEV float hhi(unsigned int w){ return __half2float(__ushort_as_half((us)(w>>16))); }
DEV float ldin(const void* p, long i, int f){
  return f ? ((const float*)p)[i] : b2f(((const bf16*)p)[i]);
}

// problem dims
#define PP 25088            // t*h*w = 8*56*56

// ws layout (float units)
#define POOLo  3211264L
#define XW1o   3286528L
#define WXo    3361792L     // Wx f32 208000; re-aliased by Wrr2 after k_Wfrag
#define WXTo   3569792L     // Wf MFMA A-frags: 256000 bf16
#define WIXo   3825792L
#define ATTo   3832064L     // 2*13*25088 f32
#define KERNo  4484352L     // 2*49*25088 f32
#define XW3o   6942976L     // xw3 bf16
#define STATo  8147200L
#define FLAGo  8149248L
#define WFo    8149264L
#define WATTFo 8267280L     // W_att f32; dead after k_Wx -> bias2 aliases head
#define WINVFo 9222784L
#define BF16o  9251600L
#define WRR2o  WXo
// bf16 sub-offsets (bf16 element units)
#define bX1T   3211264L     // x1t [b][p][64] 3211264
#define bXATT  8028160L     // xattT [b][p][256] 12845056
#define bY1    20873216L    // y1T [b][p][256] 12845056 (xwt aliases head until k_p1)
#define bINV   33718272L    // invT [b][p][256] 12845056
#define bWP1B  46563328L    // Wp1b bf16 raw [co][ci] 65536
#define bWP2B  46628864L    // Wp2b bf16 raw [o][ci] 16384
#define bW2S   46645248L    // W2sb bf16 [o][ci] 16384
#define bXWT   bY1          // xwt [b][d][hw][64]; dead before k_p1 writes y1T
// wf sub-offsets
#define oWCT   0
#define oBCT   4096
#define oWWSI  4160
#define oBWSI  8256
#define oWRR   8320
#define oBINV  35968
#define oWP1   36032
#define oWP2   101568       // [ci][co] 256x64
#define oBP2   117952

// ---- input dtype probe ----
__global__ void k_detect(const us* raw, int* flag){
  int t = threadIdx.x;
  us u = raw[2*t];
  int e = (u>>7)&0xFF;
  int hit = (e >= 137);
  unsigned long long m = __ballot(hit);
  if(t==0) flag[0] = (__popcll(m) >= 8) ? 1 : 0;
}

// ---- canonicalize small inputs ----
__global__ void k_c2f(const void* src, float* dst, int n, const int* flag){
  int i = blockIdx.x*256+threadIdx.x; if(i>=n) return;
  dst[i] = ldin(src, i, flag[0]);
}

// ---- weight convert ----
__global__ void k_cvt(const void* Wct,const void* bct,const void* Wwsi,const void* bwsi,
                      const void* Wrr,const void* binv,const void* Wp1,const void* Wp2,
                      const void* bp2,float* wf,const int* flag){
  int i = blockIdx.x*256 + threadIdx.x;
  int f = flag[0];
  if (i < 4096){ int co=i>>6, ci=i&63; wf[oWCT + ci*64+co] = ldin(Wct,i,f); }
  else if (i < 4160){ wf[i] = ldin(bct,i-4096,f); }
  else if (i < 8256){ wf[i] = ldin(Wwsi,i-4160,f); }
  else if (i < 8320){ wf[i] = ldin(bwsi,i-8256,f); }
  else if (i < 35968){ int l=i-8320; int co=l/1728, r=l%1728, ci=r/27, tp=r%27;
                       wf[oWRR + (ci*27+tp)*16+co] = ldin(Wrr,l,f); }
  else if (i < 36017){ wf[oBINV + (i-35968)] = ldin(binv,i-35968,f); }
  else if (i < 36032){ }
  else if (i < 101568){ int l=i-36032; int co=l>>8, ci=l&255; wf[oWP1 + ci*256+co] = ldin(Wp1,l,f); }
  else if (i < 117952){ int l=i-101568; int o=l>>8, ci=l&255; wf[oWP2 + ci*64+o] = ldin(Wp2,l,f); }
  else if (i < 118016){ int l=i-117952; if(l<64) wf[oBP2 + l] = ldin(bp2,l,f); }
}

// ---- raw-order bf16 weight copies for GEMM B operands ----
__global__ void k_wb(const void* Wp1, const void* Wp2, us* Wp1b, us* Wp2b, const int* flag){
  int i = blockIdx.x*256+threadIdx.x;
  int f = flag[0];
  if(i<65536) Wp1b[i]=f2u(ldin(Wp1,i,f));
  else if(i<81920) Wp2b[i-65536]=f2u(ldin(Wp2,i-65536,f));
}

// ---- xwt = channel-last x_WSI [b][d][hw][64] straight from raw input ----
__global__ void k_wsit(const void* xwsi_r, const int* flag, us* xwt){
  __shared__ us tl[64*68];
  int tid=threadIdx.x; int p0=blockIdx.x*64; int d=blockIdx.y; int b=blockIdx.z;
  int f=flag[0];
  #pragma unroll
  for(int k=0;k<16;k++){
    int idx=k*256+tid; int px=idx&63, c=idx>>6;
    float v = ldin(xwsi_r, ((long)(b*64+c)*12+d)*3136 + p0+px, f);
    tl[px*68+c] = f2u(v);
  }
  __syncthreads();
  #pragma unroll
  for(int k=0;k<16;k++){
    int idx=k*256+tid; int px=idx>>6, ch=idx&63;
    xwt[((size_t)(b*12+d)*3136 + p0+px)*64 + ch] = tl[px*68+ch];
  }
}

// ---- adaptive pool over channel-last xwt ----
__global__ void k_pool(const us* xwt, float* pool){
  int i = blockIdx.x*256+threadIdx.x;
  int c = i&63; int m=(i>>6)%588; int b=i/37632;
  int d=m/49, r=m%49, ii=r/7, jj=r%7;
  const us* src = xwt + ((size_t)(b*12+d)*3136 + (ii*8)*56 + jj*8)*64 + c;
  float s=0;
  for(int u=0;u<8;u++)
    for(int v=0;v<8;v++) s += u2f(src[(size_t)(u*56+v)*64]);
  pool[i] = s*(1.f/64.f);
}

// ---- xw1 = W_wsi * pooled + b ----
__global__ void k_xw1(const float* pool, const float* wf, float* xw1){
  int i = blockIdx.x*256+threadIdx.x;
  int c = i&63; int m=(i>>6)%588; int b=i/37632;
  const float* p = pool + (b*588+m)*64;
  const float* w = wf + oWWSI + c*64;
  float s = wf[oBWSI + c];
  for(int ci=0;ci<64;ci++) s += w[ci]*p[ci];
  xw1[i]=s;
}

// ---- Wx[b,o,tap,c] = sum_m W_att[o,m,tap] * xw1[b,c,m] ----
__global__ void k_Wx(const float* Wattf, const float* xw1, float* Wx){
  int i = blockIdx.x*256+threadIdx.x; if(i>=208000) return;
  int c=i&63; int r=i>>6; int tap=r%125; int o=(r/125)%13; int b=r/1625;
  const float* wa = Wattf + (size_t)o*588*125 + tap;
  const float* xp = xw1 + b*588*64 + c;
  float s=0;
  for(int m=0;m<588;m++) s += wa[(size_t)m*125] * xp[m*64];
  Wx[i]=s;
}

// ---- Wf: MFMA A-fragments for k_att ----
__global__ void k_Wfrag(const float* Wx, us* Wf){
  int i = blockIdx.x*256+threadIdx.x; if(i>=256000) return;
  int j=i&7; int m=(i>>3)&15; int kg=(i>>7)&3; int ch=(i>>9)&1;
  int r=i>>10; int tap=r%125; int b=r/125;
  int c = ch*32 + kg*8 + j;
  float v = (m<13) ? Wx[((size_t)(b*13+m)*125+tap)*64 + c] : 0.f;
  Wf[i] = f2u(v);
}

// ---- Wrr2: MFMA A-fragments for k_rr ----
__global__ void k_rrfrag(const float* wf, us* Wrr2){
  int i = blockIdx.x*256+threadIdx.x; if(i>=27648) return;
  int j=i&7; int l=(i>>3)&63; int kg=(i>>9)&1; int td=i>>10;
  int m=l&15, g=l>>4;
  int c = kg*32 + g*8 + j;
  Wrr2[i] = f2u(wf[oWRR + (c*27+td)*16 + m]);
}

// ---- Winvx ----
__global__ void k_Winvx(const float* Winvf, const float* xw1, float* Wix){
  int i = blockIdx.x*256+threadIdx.x; if(i>=6272) return;
  int kk=i%49; int c=(i/49)&63; int b=i/3136;
  const float* xp = xw1 + b*588*64 + c;
  float s=0;
  for(int m=0;m<588;m++) s += Winvf[kk*588+m] * xp[m*64];
  Wix[i]=s;
}

// ---- x1t = bf16 channel-last (W_ct * x_CT + b), reads raw input ----
__global__ void k_x1(const void* xct_r, const int* flag, const float* wf, us* x1t){
  int p = blockIdx.x*256+threadIdx.x;
  int co0 = blockIdx.y*16; int b = blockIdx.z;
  float acc[16];
  #pragma unroll
  for(int o=0;o<16;o++) acc[o]=wf[oBCT+co0+o];
  int f=flag[0];
  if(f){
    const float* xp = (const float*)xct_r + (size_t)b*64*PP + p;
    for(int ci=0;ci<64;ci++){
      float xv = xp[(size_t)ci*PP];
      const float* w = wf + oWCT + ci*64 + co0;
      #pragma unroll
      for(int o=0;o<16;o++) acc[o] += w[o]*xv;
    }
  } else {
    const bf16* xp = (const bf16*)xct_r + (size_t)b*64*PP + p;
    for(int ci=0;ci<64;ci++){
      float xv = b2f(xp[(size_t)ci*PP]);
      const float* w = wf + oWCT + ci*64 + co0;
      #pragma unroll
      for(int o=0;o<16;o++) acc[o] += w[o]*xv;
    }
  }
  unsigned int pk[8];
  #pragma unroll
  for(int o2=0;o2<8;o2++)
    pk[o2] = (unsigned)f2u(acc[2*o2]) | ((unsigned)f2u(acc[2*o2+1])<<16);
  us* xo = x1t + ((size_t)(b*PP)+p)*64 + co0;
  *(uint4*)xo     = make_uint4(pk[0],pk[1],pk[2],pk[3]);
  *(uint4*)(xo+8) = make_uint4(pk[4],pk[5],pk[6],pk[7]);
}

// ---- Att = sigmoid(conv5x5x5) via MFMA implicit GEMM ----
__global__ __launch_bounds__(256) void k_att(const us* x1t, const us* Wf, float* att){
  __shared__ short xt[10368];
  int tid=threadIdx.x;
  int tile=blockIdx.x, t=blockIdx.y, b=blockIdx.z;
  int y0=(tile/7)*8, x0=(tile%7)*8;
  int w=tid>>6, l=tid&63;
  int pc=l&7, pr=(l>>3)&1, g=l>>4;
  f32x4 acc0={0,0,0,0}, acc1={0,0,0,0};
  int bbase = ((2*w+pr)*12 + pc)*72 + g*8;
  const us* Wb = Wf + (size_t)b*128000 + l*8;
  for(int dt=0;dt<5;dt++){
    int ti=t+dt-2;
    if(ti<0||ti>=8) continue;
    __syncthreads();
    for(int e=tid;e<1152;e+=256){
      int px=e>>3, q=e&7;
      int row=px/12, col=px-row*12;
      int gy=y0+row-2, gx=x0+col-2;
      uint4 v={0,0,0,0};
      if((unsigned)gy<56u && (unsigned)gx<56u)
        v = *(const uint4*)(x1t + ((size_t)(b*PP) + ti*3136 + gy*56 + gx)*64 + q*8);
      *(uint4*)&xt[px*72 + q*8] = v;
    }
    __syncthreads();
    const us* Wd = Wb + dt*25600;
    #pragma unroll
    for(int dy=0;dy<5;dy++){
      #pragma unroll
      for(int dx=0;dx<5;dx++){
        int off = bbase + dy*864 + dx*72;
        short8v a0 = *(const short8v*)(Wd + (dy*5+dx)*1024);
        short8v b0 = *(const short8v*)&xt[off];
        acc0 = __builtin_amdgcn_mfma_f32_16x16x32_bf16(a0,b0,acc0,0,0,0);
        short8v a1 = *(const short8v*)(Wd + (dy*5+dx)*1024 + 512);
        short8v b1 = *(const short8v*)&xt[off+32];
        acc1 = __builtin_amdgcn_mfma_f32_16x16x32_bf16(a1,b1,acc1,0,0,0);
      }
    }
  }
  int px=l&15; int epc=px&7, epr=px>>3;
  size_t pbase=(size_t)t*3136+(size_t)(y0+2*w+epr)*56+x0+epc;
  #pragma unroll
  for(int r=0;r<4;r++){
    int o=g*4+r;
    if(o<13){
      float s=acc0[r]+acc1[r];
      att[((size_t)b*13+o)*PP+pbase]=1.f/(1.f+__expf(-s));
    }
  }
}

// ---- kern49 = Winvx * x1 + b_inv ----
__global__ void k_kern(const us* x1t, const float* Wix, const float* wf, float* kern){
  int p = blockIdx.x*256+threadIdx.x; int b=blockIdx.y;
  float acc[49];
  #pragma unroll
  for(int kk=0;kk<49;kk++) acc[kk]=wf[oBINV+kk];
  const us* xp = x1t + ((size_t)b*PP + p)*64;
  #pragma unroll
  for(int c8=0;c8<8;c8++){
    uint4 v = *(const uint4*)(xp + c8*8);
    const us* vp=(const us*)&v;
    #pragma unroll
    for(int j=0;j<8;j++){
      float xv = u2f(vp[j]);
      const float* w = Wix + (b*64+c8*8+j)*49;
      #pragma unroll
      for(int kk=0;kk<49;kk++) acc[kk]+=w[kk]*xv;
    }
  }
  float* out = kern + (size_t)b*49*PP + p;
  #pragma unroll
  for(int kk=0;kk<49;kk++) out[(size_t)kk*PP]=acc[kk];
}

// ---- xw3 = conv3x3x3 via MFMA implicit GEMM ----
__global__ __launch_bounds__(256) void k_rr(const us* xwt, const us* Wrr2, bf16* xw3){
  __shared__ short xt[7200];
  int tid=threadIdx.x;
  int tile=blockIdx.x, d=blockIdx.y, b=blockIdx.z;
  int y0=(tile/7)*8, x0=(tile%7)*8;
  int w=tid>>6, l=tid&63;
  int pc=l&7, pr=(l>>3)&1, g=l>>4;
  f32x4 acc0={0,0,0,0}, acc1={0,0,0,0};
  int bbase = ((2*w+pr)*10 + pc)*72 + g*8;
  const us* Wl = Wrr2 + l*8;
  for(int dz=0;dz<3;dz++){
    int di=d+dz-1;
    if(di<0||di>=12) continue;
    __syncthreads();
    for(int e=tid;e<800;e+=256){
      int px=e>>3, q=e&7;
      int row=px/10, col=px-row*10;
      int gy=y0+row-1, gx=x0+col-1;
      uint4 v={0,0,0,0};
      if((unsigned)gy<56u && (unsigned)gx<56u)
        v = *(const uint4*)(xwt + ((size_t)(b*12+di)*3136 + gy*56 + gx)*64 + q*8);
      *(uint4*)&xt[px*72 + q*8] = v;
    }
    __syncthreads();
    const us* Wd = Wl + dz*9216;
    #pragma unroll
    for(int tap=0;tap<9;tap++){
      int dy=tap/3, dx=tap-dy*3;
      int off = bbase + (dy*10+dx)*72;
      short8v a0 = *(const short8v*)(Wd + tap*1024);
      short8v b0 = *(const short8v*)&xt[off];
      acc0 = __builtin_amdgcn_mfma_f32_16x16x32_bf16(a0,b0,acc0,0,0,0);
      short8v a1 = *(const short8v*)(Wd + tap*1024 + 512);
      short8v b1 = *(const short8v*)&xt[off+32];
      acc1 = __builtin_amdgcn_mfma_f32_16x16x32_bf16(a1,b1,acc1,0,0,0);
    }
  }
  int px=l&15; int epc=px&7, epr=px>>3;
  size_t pp=(size_t)(y0+2*w+epr)*56 + x0+epc;
  #pragma unroll
  for(int r=0;r<4;r++){
    int o=g*4+r;
    xw3[((size_t)(b*16+o)*12+d)*3136 + pp] = f2b(acc0[r]+acc1[r]);
  }
}

// ---- xattT = channel-last x_Att [b][p][256] (reads raw xct) ----
__global__ void k_xatt(const void* xct_r, const int* flag, const bf16* xw3,
                       const float* att, us* xattT){
  __shared__ us tl[64*258];
  int tid=threadIdx.x; int p0=blockIdx.x*64; int b=blockIdx.y;
  int f=flag[0];
  for(int k=0;k<64;k++){
    int idx=k*256+tid; int ch=idx>>6, pp=idx&63;
    int p=p0+pp;
    float v;
    if(ch<64){
      long ix = (long)(b*64+ch)*PP+p;
      float xv;
      if(f) xv = ((const float*)xct_r)[ix]; else xv = b2f(((const bf16*)xct_r)[ix]);
      v = xv * (1.f+att[(size_t)b*13*PP+p]);
    } else {
      int q=ch-64; int co=q/12, dd=q-co*12;
      int s=p%3136;
      v = b2f(xw3[((size_t)(b*16+co)*12+dd)*3136+s]) * (1.f+att[((size_t)b*13+1+q/16)*PP+p]);
    }
    tl[pp*258+ch]=f2u(v);
  }
  __syncthreads();
  for(int k=0;k<64;k++)
    xattT[((size_t)b*PP + p0+k)*256 + tid] = tl[k*258+tid];
}

// ---- y1T = x_Att @ W_p1^T ; LDS-staged weight panel in fragment order ----
__global__ __launch_bounds__(256) void k_p1(const us* xattT, const us* Wp1b, us* y1T){
  __shared__ us wt[16384];
  int tid=threadIdx.x; int w=tid>>6, l=tid&63;
  int pt=blockIdx.x, qtr=blockIdx.y, b=blockIdx.z;
  int co0 = qtr*64;
  #pragma unroll
  for(int it=0;it<8;it++){
    int f = it*256+tid;
    int n=f>>9, kc=(f>>6)&7, lane=f&63;
    int co = co0 + n*16 + (lane&15);
    int ci = (lane>>4)*8 + kc*32;
    uint4 v = *(const uint4*)(Wp1b + (size_t)co*256 + ci);
    *(uint4*)(wt + f*8) = v;
  }
  __syncthreads();
  int p0 = pt*64 + w*16;
  const us* xa = xattT + ((size_t)b*PP + p0 + (l&15))*256 + ((l>>4)*8);
  f32x4 acc[4];
  #pragma unroll
  for(int n=0;n<4;n++) acc[n]=(f32x4){0,0,0,0};
  for(int kc=0;kc<8;kc++){
    short8v a = *(const short8v*)(xa + kc*32);
    #pragma unroll
    for(int n=0;n<4;n++){
      short8v bf = *(const short8v*)(wt + ((n*8+kc)*64 + l)*8);
      acc[n] = __builtin_amdgcn_mfma_f32_16x16x32_bf16(a,bf,acc[n],0,0,0);
    }
  }
  int col=l&15, rowb=(l>>4)*4;
  us* yo = y1T + ((size_t)b*PP + p0)*256 + co0;
  #pragma unroll
  for(int n=0;n<4;n++)
    #pragma unroll
    for(int r=0;r<4;r++)
      yo[(size_t)(rowb+r)*256 + n*16 + col] = f2u(acc[n][r]);
}

// ---- per-channel sum/sumsq over channel-last [b][p][256] ----
__global__ void k_stats(const us* src, float* sum, float* sq){
  int tid=threadIdx.x; int pt=blockIdx.x, b=blockIdx.y;
  const us* p = src + ((size_t)b*PP + pt*64)*256 + tid;
  float s=0,q=0;
  #pragma unroll 8
  for(int i=0;i<64;i++){ float v=u2f(p[(size_t)i*256]); s+=v; q+=v*v; }
  atomicAdd(&sum[tid],s); atomicAdd(&sq[tid],q);
}
__global__ void k_finstat(const float* sum, const float* sq, const void* g, const void* be,
                          const int* flag, float* sc, float* sh){
  int ch=threadIdx.x;
  int f=flag[0];
  float m = sum[ch]*(1.f/50176.f);
  float v = sq[ch]*(1.f/50176.f) - m*m;
  float s = ldin(g,ch,f) * rsqrtf(v+1e-5f);
  sc[ch]=s; sh[ch]=ldin(be,ch,f) - m*s;
}

// ---- involution, bn1+relu fused into staging; fp16 tile (targets v_fma_mix) ----
__global__ __launch_bounds__(256) void k_inv(const us* y1T, const float* sc1, const float* sh1,
                                             const float* kern, us* invT){
  __shared__ __align__(16) us xt[196*72];   // fp16 elements
  int tid=threadIdx.x;
  int bx=blockIdx.x, by=blockIdx.y, bz=blockIdx.z;
  int t=bz&7, b=bz>>3;
  int y0=(bx/7)*8, x0=(bx%7)*8, c0=by*64;
  int w=tid>>6, l=tid&63;
  int ty=l>>3, tx=l&7;
  int segb = c0 + (tid&7)*8;
  float scr[8], shr[8];
  #pragma unroll
  for(int j=0;j<8;j++){ scr[j]=sc1[segb+j]; shr[j]=sh1[segb+j]; }
  for(int e=tid;e<1568;e+=256){
    int row=e>>3, seg=e&7;                       // seg == tid&7
    int yy=row/14, xx=row%14;
    int gy=y0+yy-3, gx=x0+xx-3;
    uint4 o4={0,0,0,0};
    if(gy>=0&&gy<56&&gx>=0&&gx<56){
      uint4 v = *(const uint4*)&y1T[((size_t)b*PP + t*3136 + gy*56+gx)*256 + c0 + seg*8];
      const us* vp=(const us*)&v;
      us r[8];
      #pragma unroll
      for(int j=0;j<8;j++){
        float x = u2f(vp[j]);
        x = x*scr[j]+shr[j]; x = x>0.f?x:0.f;
        r[j]=f2h(x);                             // fp16 tile
      }
      o4 = *(const uint4*)r;
    }
    *(uint4*)&xt[row*72+seg*8]=o4;
  }
  float kr[49];
  size_t pxs=(size_t)t*3136 + (y0+ty)*56 + x0+tx;
  #pragma unroll
  for(int kk=0;kk<49;kk++) kr[kk]=kern[((size_t)b*49+kk)*PP+pxs];
  __syncthreads();
  #pragma unroll
  for(int s=0;s<2;s++){
    int sub=2*w+s;
    float acc[8];
    #pragma unroll
    for(int e=0;e<8;e++) acc[e]=0;
    for(int i=0;i<7;i++){
      #pragma unroll
      for(int j=0;j<7;j++){
        uint4 u = *(const uint4*)&xt[((ty+i)*14+tx+j)*72 + sub*8];
        float kv = kr[i*7+j];
        acc[0]+=hlo(u.x)*kv; acc[1]+=hhi(u.x)*kv;   // -> v_fma_mix_f32
        acc[2]+=hlo(u.y)*kv; acc[3]+=hhi(u.y)*kv;
        acc[4]+=hlo(u.z)*kv; acc[5]+=hhi(u.z)*kv;
        acc[6]+=hlo(u.w)*kv; acc[7]+=hhi(u.w)*kv;
      }
    }
    unsigned pk[4];
    #pragma unroll
    for(int e=0;e<4;e++)
      pk[e] = (unsigned)f2u(acc[2*e]) | ((unsigned)f2u(acc[2*e+1])<<16);
    *(uint4*)&invT[((size_t)b*PP+pxs)*256 + c0 + sub*8] = make_uint4(pk[0],pk[1],pk[2],pk[3]);
  }
}

// ---- W2s = W_p2*diag(sc2) bf16; bias2 = b_p2 + W_p2@sh2 ----
__global__ void k_w2s(const float* wf, const float* sc2, const float* sh2,
                      us* W2sb, float* bias2){
  __shared__ float red[256];
  int o=blockIdx.x, ci=threadIdx.x;
  float wv = wf[oWP2 + ci*64 + o];
  W2sb[o*256+ci] = f2u(wv * sc2[ci]);
  red[ci] = wv * sh2[ci];
  __syncthreads();
  for(int st=128;st>0;st>>=1){ if(ci<st) red[ci]+=red[ci+st]; __syncthreads(); }
  if(ci==0) bias2[o] = wf[oBP2+o] + red[0];
}

// ---- out = W2s@invT + W_p2@xattT + bias2 ; both weight panels LDS-staged ----
__global__ __launch_bounds__(256) void k_final(const us* invT, const us* xattT,
                                               const us* W2sb, const us* Wp2b,
                                               const float* bias2, float* out){
  __shared__ us wt[32768];
  int tid=threadIdx.x; int w=tid>>6, l=tid&63;
  int pt=blockIdx.x, b=blockIdx.y;
  #pragma unroll
  for(int it=0;it<16;it++){
    int f = it*256+tid;
    int which = f>>11;
    int g = f&2047;
    int n=g>>9, kc=(g>>6)&7, lane=g&63;
    int co = n*16 + (lane&15);
    int ci = (lane>>4)*8 + kc*32;
    const us* src = which ? Wp2b : W2sb;
    uint4 v = *(const uint4*)(src + (size_t)co*256 + ci);
    *(uint4*)(wt + f*8) = v;
  }
  __syncthreads();
  int p0 = pt*64 + w*16;
  size_t abase = ((size_t)b*PP + p0 + (l&15))*256 + ((l>>4)*8);
  f32x4 acc[4];
  #pragma unroll
  for(int n=0;n<4;n++) acc[n]=(f32x4){0,0,0,0};
  for(int kc=0;kc<8;kc++){
    short8v ai = *(const short8v*)(invT + abase + kc*32);
    short8v ax = *(const short8v*)(xattT + abase + kc*32);
    #pragma unroll
    for(int n=0;n<4;n++){
      short8v b1 = *(const short8v*)(wt + ((n*8+kc)*64 + l)*8);
      acc[n] = __builtin_amdgcn_mfma_f32_16x16x32_bf16(ai,b1,acc[n],0,0,0);
      short8v b2 = *(const short8v*)(wt + 16384 + ((n*8+kc)*64 + l)*8);
      acc[n] = __builtin_amdgcn_mfma_f32_16x16x32_bf16(ax,b2,acc[n],0,0,0);
    }
  }
  int col=l&15, rowb=(l>>4)*4;
  #pragma unroll
  for(int n=0;n<4;n++){
    float bb = bias2[n*16+col];
    #pragma unroll
    for(int r=0;r<4;r++)
      out[((size_t)b*64 + n*16+col)*PP + p0 + rowb + r] = acc[n][r] + bb;
  }
}

extern "C" void kernel_launch(void* const* d_in, const int* in_sizes, int n_in,
                              void* d_out, int out_size, void* d_ws, size_t ws_size,
                              hipStream_t stream){
  const void* xct_r =d_in[0];
  const void* xwsi_r=d_in[1];
  const void* Wct =d_in[2];
  const void* bct =d_in[3];
  const void* Wwsi=d_in[4];
  const void* bwsi=d_in[5];
  const void* Watt=d_in[6];
  const void* Winv=d_in[7];
  const void* binv=d_in[8];
  const void* Wrr =d_in[9];
  const void* g1  =d_in[10];
  const void* be1 =d_in[11];
  const void* g2  =d_in[12];
  const void* be2 =d_in[13];
  const void* Wp1 =d_in[14];
  const void* Wp2 =d_in[16];
  const void* bp2 =d_in[17];
  float* ws=(float*)d_ws;
  float* pool=ws+POOLo; float* xw1=ws+XW1o;
  float* Wx=ws+WXo; float* Wix=ws+WIXo;
  float* att=ws+ATTo; float* kern=ws+KERNo;
  us* Wf=(us*)(ws+WXTo);
  us* Wrr2=(us*)(ws+WRR2o);
  bf16* xw3=(bf16*)(ws+XW3o);
  float* stat=ws+STATo; float* wf=ws+WFo;
  float* Wattf=ws+WATTFo; float* Winvf=ws+WINVFo;
  float* bias2=ws+WATTFo;     // aliases Wattf (dead after k_Wx)
  int* flag=(int*)(ws+FLAGo);
  bf16* bfb=(bf16*)(ws+BF16o);
  us* x1t=(us*)(bfb+bX1T);
  us* xattT=(us*)(bfb+bXATT); us* y1T=(us*)(bfb+bY1); us* invT=(us*)(bfb+bINV);
  us* Wp1b=(us*)(bfb+bWP1B); us* Wp2b=(us*)(bfb+bWP2B); us* W2sb=(us*)(bfb+bW2S);
  us* xwt=(us*)(bfb+bXWT);
  float* sum1=stat; float* sq1=stat+256; float* sum2=stat+512; float* sq2=stat+768;
  float* sc1=stat+1024; float* sh1=stat+1280; float* sc2=stat+1536; float* sh2=stat+1792;

  hipMemsetAsync(stat,0,4096,stream);
  k_detect<<<1,64,0,stream>>>((const us*)xct_r,flag);
  k_c2f   <<<3733,256,0,stream>>>(Watt,Wattf,955500,flag);
  k_c2f   <<<113,256,0,stream>>>(Winv,Winvf,28812,flag);
  k_cvt   <<<461,256,0,stream>>>(Wct,bct,Wwsi,bwsi,Wrr,binv,Wp1,Wp2,bp2,wf,flag);
  k_wb    <<<320,256,0,stream>>>(Wp1,Wp2,Wp1b,Wp2b,flag);
  k_wsit  <<<dim3(49,12,2),256,0,stream>>>(xwsi_r,flag,xwt); // xwt aliases y1T head (dead until k_p1)
  k_pool  <<<294,256,0,stream>>>(xwt,pool);
  k_xw1   <<<294,256,0,stream>>>(pool,wf,xw1);
  k_Wx    <<<813,256,0,stream>>>(Wattf,xw1,Wx);
  k_Wfrag <<<1000,256,0,stream>>>(Wx,Wf);
  k_rrfrag<<<108,256,0,stream>>>(wf,Wrr2);                   // overwrites Wx head (dead)
  k_Winvx <<<25,256,0,stream>>>(Winvf,xw1,Wix);
  k_x1    <<<dim3(98,4,2),256,0,stream>>>(xct_r,flag,wf,x1t);
  k_att   <<<dim3(49,8,2),256,0,stream>>>(x1t,Wf,att);
  k_kern  <<<dim3(98,2),256,0,stream>>>(x1t,Wix,wf,kern);
  k_rr    <<<dim3(49,12,2),256,0,stream>>>(xwt,Wrr2,xw3);
  k_xatt  <<<dim3(392,2),256,0,stream>>>(xct_r,flag,xw3,att,xattT);
  k_p1    <<<dim3(392,4,2),256,0,stream>>>(xattT,Wp1b,y1T);  // overwrites xwt (dead)
  k_stats <<<dim3(392,2),256,0,stream>>>(y1T,sum1,sq1);
  k_finstat<<<1,256,0,stream>>>(sum1,sq1,g1,be1,flag,sc1,sh1);
  k_inv   <<<dim3(49,4,16),256,0,stream>>>(y1T,sc1,sh1,kern,invT); // fp16 tile + fma_mix
  k_stats <<<dim3(392,2),256,0,stream>>>(invT,sum2,sq2);
  k_finstat<<<1,256,0,stream>>>(sum2,sq2,g2,be2,flag,sc2,sh2);
  k_w2s   <<<64,256,0,stream>>>(wf,sc2,sh2,W2sb,bias2);
  k_final <<<dim3(392,2),256,0,stream>>>(invT,xattT,W2sb,Wp2b,bias2,(float*)d_out);
}